// Round 2
// baseline (1190.489 us; speedup 1.0000x reference)
//
#include <hip/hip_runtime.h>
#include <hip/hip_bf16.h>
#include <math.h>

#define NN 100000
#define EE 800000
#define FIN 256
#define CH 64      // HID
#define C1 256     // H*HID
#define BN_EPS 1e-5f
#define NEG_SLOPE 0.2f

typedef __attribute__((ext_vector_type(8))) short short8;
typedef __attribute__((ext_vector_type(8))) unsigned short u16x8;
typedef __attribute__((ext_vector_type(4))) float f32x4;

__device__ __forceinline__ float bf2f(ushort u) {
    return __uint_as_float(((unsigned)u) << 16);
}
__device__ __forceinline__ ushort f2bf(float f) {
    unsigned u = __float_as_uint(f);
    return (ushort)((u + 0x7FFF + ((u >> 16) & 1)) >> 16);   // RNE
}

// ================= CSR build =================
__global__ void hist_kernel(const int* __restrict__ ei, int* __restrict__ deg) {
    int t = blockIdx.x * 256 + threadIdx.x;
    if (t < EE) atomicAdd(&deg[ei[EE + t]], 1);
}
__global__ void dinv_kernel(const int* __restrict__ deg, float* __restrict__ dinv) {
    int i = blockIdx.x * 256 + threadIdx.x;
    if (i < NN) dinv[i] = rsqrtf((float)(deg[i] + 1));  // +1 self loop
}
__global__ void scan_k1(const int* __restrict__ deg, int* __restrict__ row_start,
                        int* __restrict__ bsum) {
    __shared__ int sh[256];
    int t = threadIdx.x;
    int i = blockIdx.x * 256 + t;
    int v = (i < NN) ? (deg[i] + 1) : 0;
    sh[t] = v;
    __syncthreads();
    for (int off = 1; off < 256; off <<= 1) {
        int add = (t >= off) ? sh[t - off] : 0;
        __syncthreads();
        sh[t] += add;
        __syncthreads();
    }
    if (i < NN) row_start[i] = sh[t] - v;
    if (t == 255) bsum[blockIdx.x] = sh[255];
}
__global__ void scan_k2(int* __restrict__ bsum, int nb) {
    __shared__ int sh[512];
    int t = threadIdx.x;
    int v = (t < nb) ? bsum[t] : 0;
    sh[t] = v;
    __syncthreads();
    for (int off = 1; off < 512; off <<= 1) {
        int add = (t >= off) ? sh[t - off] : 0;
        __syncthreads();
        sh[t] += add;
        __syncthreads();
    }
    if (t < nb) bsum[t] = sh[t] - v;
}
__global__ void scan_k3(int* __restrict__ row_start, const int* __restrict__ bsum) {
    int i = blockIdx.x * 256 + threadIdx.x;
    if (i < NN) row_start[i] += bsum[i >> 8];
    if (i == NN) row_start[NN] = EE + NN;
}
__global__ void scatter_kernel(const int* __restrict__ ei, const int* __restrict__ row_start,
                               int* __restrict__ fill, int* __restrict__ sorted) {
    int t = blockIdx.x * 256 + threadIdx.x;
    if (t >= EE + NN) return;
    int s, d;
    if (t < EE) { s = ei[t]; d = ei[EE + t]; }
    else        { s = t - EE; d = s; }
    int pos = atomicAdd(&fill[d], 1);
    sorted[row_start[d] + pos] = s;
}

// ================= conversions =================
__global__ void convert_f32_bf16(const float* __restrict__ in, ushort* __restrict__ out, long n4) {
    long i = (long)blockIdx.x * 256 + threadIdx.x;
    if (i < n4) {
        float4 v = *(const float4*)&in[i * 4];
        ushort4 o;
        o.x = f2bf(v.x); o.y = f2bf(v.y); o.z = f2bf(v.z); o.w = f2bf(v.w);
        *(ushort4*)&out[i * 4] = o;
    }
}
__global__ void transpose_w(const float* __restrict__ W, ushort* __restrict__ Bt, int M, int K) {
    int idx = blockIdx.x * 256 + threadIdx.x;
    if (idx < M * K) {
        int m = idx / K, n = idx % K;
        Bt[n * M + m] = f2bf(W[idx]);
    }
}

// ================= bf16 MFMA GEMM =================
// C[N x K] = A[N x M] @ B[M x K]; A bf16 row-major, Bt bf16 [K][M], C bf16.
__global__ __launch_bounds__(256) void gemm_mfma(
        const ushort* __restrict__ A, const ushort* __restrict__ Bt,
        ushort* __restrict__ C, int M, int K) {
    __shared__ ushort As[64][40];
    __shared__ ushort Bs[64][40];
    int t = threadIdx.x;
    int w = t >> 6;
    int l = t & 63;
    int rowBase = blockIdx.y * 64;
    int colBase = blockIdx.x * 64;
    int srow = t >> 2;
    int sk = (t & 3) * 8;
    int m = l & 15, q = l >> 4;
    f32x4 acc[4] = {};
    for (int k0 = 0; k0 < M; k0 += 32) {
        uint4 av = make_uint4(0u, 0u, 0u, 0u);
        int gr = rowBase + srow;
        if (gr < NN) av = *(const uint4*)&A[(long)gr * M + k0 + sk];
        uint4 bv = *(const uint4*)&Bt[(long)(colBase + srow) * M + k0 + sk];
        *(uint4*)&As[srow][sk] = av;
        *(uint4*)&Bs[srow][sk] = bv;
        __syncthreads();
        short8 af = *(const short8*)&As[w * 16 + m][q * 8];
#pragma unroll
        for (int c = 0; c < 4; ++c) {
            short8 bf = *(const short8*)&Bs[c * 16 + m][q * 8];
            acc[c] = __builtin_amdgcn_mfma_f32_16x16x32_bf16(af, bf, acc[c], 0, 0, 0);
        }
        __syncthreads();
    }
#pragma unroll
    for (int c = 0; c < 4; ++c) {
#pragma unroll
        for (int r = 0; r < 4; ++r) {
            int orow = rowBase + w * 16 + q * 4 + r;
            if (orow < NN) C[(long)orow * K + colBase + c * 16 + m] = f2bf(acc[c][r]);
        }
    }
}

// ================= GCN gather =================
// one wave per node; 16-lane sub-groups each take edges at stride 4;
// ushort4 loads (8B/lane), shfl-xor reduce, f32x4 store.
__global__ __launch_bounds__(256) void gcn_gather(
        const int* __restrict__ row_start, const int* __restrict__ sorted,
        const float* __restrict__ dinv, const ushort* __restrict__ h0,
        float* __restrict__ agg) {
    int node = blockIdx.x * 4 + (threadIdx.x >> 6);
    if (node >= NN) return;
    int l = threadIdx.x & 63;
    int sub = l >> 4;           // edge sub-slot 0..3
    int ch = (l & 15) * 4;      // 4 channels of 64
    int b = row_start[node], e = row_start[node + 1];
    float a0 = 0.f, a1 = 0.f, a2 = 0.f, a3 = 0.f;
    for (int i = b + sub; i < e; i += 4) {
        int s = sorted[i];
        float dv = dinv[s];
        ushort4 v = *(const ushort4*)&h0[(long)s * 64 + ch];
        a0 += dv * bf2f(v.x);
        a1 += dv * bf2f(v.y);
        a2 += dv * bf2f(v.z);
        a3 += dv * bf2f(v.w);
    }
    a0 += __shfl_xor(a0, 16); a1 += __shfl_xor(a1, 16);
    a2 += __shfl_xor(a2, 16); a3 += __shfl_xor(a3, 16);
    a0 += __shfl_xor(a0, 32); a1 += __shfl_xor(a1, 32);
    a2 += __shfl_xor(a2, 32); a3 += __shfl_xor(a3, 32);
    if (sub == 0) {
        float dn = dinv[node];
        f32x4 o;
        o[0] = a0 * dn; o[1] = a1 * dn; o[2] = a2 * dn; o[3] = a3 * dn;
        *(f32x4*)&agg[(long)node * 64 + ch] = o;
    }
}

// ================= BatchNorm =================
// C=64, fp32 input, relu pre-BN. grid = ceil(NN/64), block 256.
__global__ __launch_bounds__(256) void bn_stats64(
        const float* __restrict__ x, const float* __restrict__ bias,
        float* __restrict__ sums, float* __restrict__ sumsq) {
    __shared__ float red[512];
    int t = threadIdx.x;
    int col = t & 63, sub = t >> 6;
    int r0 = blockIdx.x * 64;
    int r1 = min(r0 + 64, NN);
    float b = bias[col];
    float s = 0.f, ss = 0.f;
    for (int r = r0 + sub; r < r1; r += 4) {
        float v = fmaxf(x[(long)r * 64 + col] + b, 0.f);
        s += v; ss += v * v;
    }
    red[t] = s; red[256 + t] = ss;
    __syncthreads();
    if (t < 64) {
        s = red[t] + red[t + 64] + red[t + 128] + red[t + 192];
        ss = red[256 + t] + red[320 + t] + red[384 + t] + red[448 + t];
        atomicAdd(&sums[col], s);
        atomicAdd(&sumsq[col], ss);
    }
}
// C=256, bf16 input, no relu. grid = ceil(NN/32), block 256.
__global__ __launch_bounds__(256) void bn_stats256(
        const ushort* __restrict__ x, const float* __restrict__ bias,
        float* __restrict__ sums, float* __restrict__ sumsq) {
    int t = threadIdx.x;
    int r0 = blockIdx.x * 32;
    int r1 = min(r0 + 32, NN);
    float b = bias[t];
    float s = 0.f, ss = 0.f;
    for (int r = r0; r < r1; ++r) {
        float v = bf2f(x[(long)r * 256 + t]) + b;
        s += v; ss += v * v;
    }
    atomicAdd(&sums[t], s);
    atomicAdd(&sumsq[t], ss);
}
__global__ void bn_finalize(const float* __restrict__ sums, const float* __restrict__ sumsq,
                            const float* __restrict__ g, const float* __restrict__ beta,
                            float* __restrict__ scale, float* __restrict__ shift, int C) {
    int c = threadIdx.x;
    if (c < C) {
        float mean = sums[c] / (float)NN;
        float var = sumsq[c] / (float)NN - mean * mean;
        float sc = g[c] * rsqrtf(var + BN_EPS);
        scale[c] = sc;
        shift[c] = beta[c] - mean * sc;
    }
}
// GCN: fp32 in, relu pre-BN, bf16 out. 4 elems/thread. grid = N*16/256.
__global__ void bn_apply_gcn(const float* __restrict__ x, const float* __restrict__ bias,
                             const float* __restrict__ scale, const float* __restrict__ shift,
                             ushort* __restrict__ out) {
    long i4 = (long)blockIdx.x * 256 + threadIdx.x;
    if (i4 < (long)NN * 16) {
        int c = (int)((i4 & 15) * 4);
        f32x4 v = *(const f32x4*)&x[i4 * 4];
        ushort4 o;
        float t0 = fmaxf(v[0] + bias[c + 0], 0.f);
        float t1 = fmaxf(v[1] + bias[c + 1], 0.f);
        float t2 = fmaxf(v[2] + bias[c + 2], 0.f);
        float t3 = fmaxf(v[3] + bias[c + 3], 0.f);
        o.x = f2bf(scale[c + 0] * t0 + shift[c + 0]);
        o.y = f2bf(scale[c + 1] * t1 + shift[c + 1]);
        o.z = f2bf(scale[c + 2] * t2 + shift[c + 2]);
        o.w = f2bf(scale[c + 3] * t3 + shift[c + 3]);
        *(ushort4*)&out[i4 * 4] = o;
    }
}
// GAT: bf16 in, ELU post-BN, bf16 or fp32 out. 8 elems/thread. grid = N*32/256.
__global__ void bn_apply_gat(const ushort* __restrict__ x, const float* __restrict__ bias,
                             const float* __restrict__ scale, const float* __restrict__ shift,
                             void* __restrict__ out, int out_bf16) {
    long i8 = (long)blockIdx.x * 256 + threadIdx.x;
    if (i8 < (long)NN * 32) {
        int c = (int)((i8 & 31) * 8);
        u16x8 v = *(const u16x8*)&x[i8 * 8];
        float r[8];
#pragma unroll
        for (int j = 0; j < 8; ++j) {
            float t = bf2f((ushort)v[j]) + bias[c + j];
            t = scale[c + j] * t + shift[c + j];
            r[j] = (t > 0.f) ? t : expm1f(t);
        }
        if (out_bf16) {
            u16x8 o;
#pragma unroll
            for (int j = 0; j < 8; ++j) o[j] = f2bf(r[j]);
            *(u16x8*)&((ushort*)out)[i8 * 8] = o;
        } else {
            f32x4 o0, o1;
#pragma unroll
            for (int j = 0; j < 4; ++j) { o0[j] = r[j]; o1[j] = r[4 + j]; }
            float* op = (float*)out + i8 * 8;
            *(f32x4*)op = o0;
            *(f32x4*)(op + 4) = o1;
        }
    }
}

// ================= GAT =================
__global__ void gat_alpha(const ushort* __restrict__ h, const float* __restrict__ a_src,
                          const float* __restrict__ a_dst,
                          float* __restrict__ alpha_s, float* __restrict__ alpha_d) {
    int n = blockIdx.x;
    int t = threadIdx.x;
    float hv = bf2f(h[(long)n * 256 + t]);
    float vs = hv * a_src[t];
    float vd = hv * a_dst[t];
    for (int off = 32; off > 0; off >>= 1) {
        vs += __shfl_down(vs, off);
        vd += __shfl_down(vd, off);
    }
    if ((t & 63) == 0) {
        int head = t >> 6;
        alpha_s[n * 4 + head] = vs;
        alpha_d[n * 4 + head] = vd;
    }
}

// one wave per node; lane = edge_k*4 + head; 2 passes; stores UNNORMALIZED w
// plus per-(node,head) 1/sum into inv_ls (normalization applied in gather).
__global__ __launch_bounds__(256) void gat_att(
        const int* __restrict__ row_start, const int* __restrict__ sorted,
        const float* __restrict__ as, const float* __restrict__ ad,
        float* __restrict__ att, float* __restrict__ inv_ls) {
    int node = blockIdx.x * 4 + (threadIdx.x >> 6);
    if (node >= NN) return;
    int l = threadIdx.x & 63;
    int h = l & 3, k = l >> 2;
    int b = row_start[node], e = row_start[node + 1];
    float adn = ad[node * 4 + h];
    // pass 1: per-head max
    float lm = -1e30f;
    for (int i = b + k; i < e; i += 16) {
        int s = sorted[i];
        float ev = as[s * 4 + h] + adn;
        ev = (ev > 0.f) ? ev : NEG_SLOPE * ev;
        lm = fmaxf(lm, ev);
    }
    lm = fmaxf(lm, __shfl_xor(lm, 4));
    lm = fmaxf(lm, __shfl_xor(lm, 8));
    lm = fmaxf(lm, __shfl_xor(lm, 16));
    lm = fmaxf(lm, __shfl_xor(lm, 32));
    // pass 2: exp, store unnormalized, per-head sum
    float ls = 0.f;
    for (int i = b + k; i < e; i += 16) {
        int s = sorted[i];
        float ev = as[s * 4 + h] + adn;
        ev = (ev > 0.f) ? ev : NEG_SLOPE * ev;
        float wv = __expf(ev - lm);
        att[(long)i * 4 + h] = wv;
        ls += wv;
    }
    ls += __shfl_xor(ls, 4);
    ls += __shfl_xor(ls, 8);
    ls += __shfl_xor(ls, 16);
    ls += __shfl_xor(ls, 32);
    if (k == 0) inv_ls[node * 4 + h] = 1.0f / ls;
}

// one WAVE per node: lane l owns channels 4l..4l+3 (ushort4 = full 512B row
// per wave-instruction), 4-edge unroll, inv-sum applied at the end.
__global__ __launch_bounds__(256) void gat_gather(
        const int* __restrict__ row_start, const int* __restrict__ sorted,
        const float* __restrict__ att, const float* __restrict__ inv_ls,
        const ushort* __restrict__ h, ushort* __restrict__ out) {
    int node = blockIdx.x * 4 + (threadIdx.x >> 6);
    if (node >= NN) return;
    int l = threadIdx.x & 63;
    int head = l >> 4;                      // channels 4l..4l+3 share one head
    int b = row_start[node], e = row_start[node + 1];
    float a0 = 0.f, a1 = 0.f, a2 = 0.f, a3 = 0.f;
    int i = b;
    for (; i + 3 < e; i += 4) {
        int s0 = sorted[i], s1 = sorted[i + 1], s2 = sorted[i + 2], s3 = sorted[i + 3];
        float w0 = att[(long)i * 4 + head];
        float w1 = att[(long)(i + 1) * 4 + head];
        float w2 = att[(long)(i + 2) * 4 + head];
        float w3 = att[(long)(i + 3) * 4 + head];
        ushort4 v0 = *(const ushort4*)&h[(long)s0 * 256 + l * 4];
        ushort4 v1 = *(const ushort4*)&h[(long)s1 * 256 + l * 4];
        ushort4 v2 = *(const ushort4*)&h[(long)s2 * 256 + l * 4];
        ushort4 v3 = *(const ushort4*)&h[(long)s3 * 256 + l * 4];
        a0 += w0 * bf2f(v0.x) + w1 * bf2f(v1.x) + w2 * bf2f(v2.x) + w3 * bf2f(v3.x);
        a1 += w0 * bf2f(v0.y) + w1 * bf2f(v1.y) + w2 * bf2f(v2.y) + w3 * bf2f(v3.y);
        a2 += w0 * bf2f(v0.z) + w1 * bf2f(v1.z) + w2 * bf2f(v2.z) + w3 * bf2f(v3.z);
        a3 += w0 * bf2f(v0.w) + w1 * bf2f(v1.w) + w2 * bf2f(v2.w) + w3 * bf2f(v3.w);
    }
    for (; i < e; ++i) {
        int s0 = sorted[i];
        float w0 = att[(long)i * 4 + head];
        ushort4 v0 = *(const ushort4*)&h[(long)s0 * 256 + l * 4];
        a0 += w0 * bf2f(v0.x);
        a1 += w0 * bf2f(v0.y);
        a2 += w0 * bf2f(v0.z);
        a3 += w0 * bf2f(v0.w);
    }
    float inv = inv_ls[node * 4 + head];
    ushort4 o;
    o.x = f2bf(a0 * inv);
    o.y = f2bf(a1 * inv);
    o.z = f2bf(a2 * inv);
    o.w = f2bf(a3 * inv);
    *(ushort4*)&out[(long)node * 256 + l * 4] = o;
}

// ================= launch =================
extern "C" void kernel_launch(void* const* d_in, const int* in_sizes, int n_in,
                              void* d_out, int out_size, void* d_ws, size_t ws_size,
                              hipStream_t stream) {
    const float* x      = (const float*)d_in[0];
    const int*   ei     = (const int*)d_in[1];
    const float* W_gcn  = (const float*)d_in[2];
    const float* b_gcn  = (const float*)d_in[3];
    const float* g0     = (const float*)d_in[4];
    const float* beta0  = (const float*)d_in[5];
    const float* W1     = (const float*)d_in[6];
    const float* a_src1 = (const float*)d_in[7];
    const float* a_dst1 = (const float*)d_in[8];
    const float* b1     = (const float*)d_in[9];
    const float* g1     = (const float*)d_in[10];
    const float* beta1  = (const float*)d_in[11];
    const float* W2     = (const float*)d_in[12];
    const float* a_src2 = (const float*)d_in[13];
    const float* a_dst2 = (const float*)d_in[14];
    const float* b2     = (const float*)d_in[15];
    const float* g2     = (const float*)d_in[16];
    const float* beta2  = (const float*)d_in[17];

    const long N = NN;
    float* ws = (float*)d_ws;

    // ---- layout (~544N floats; ws proven >= 641N floats) ----
    float* dinv    = ws;                        // N
    float* alpha_s = ws + N;                    // 4N
    float* alpha_d = ws + 5 * N;                // 4N
    float* sums    = ws + 9 * N;                // 256
    float* sumsq   = sums + 256;
    float* scale   = sumsq + 256;
    float* shift   = scale + 256;
    int*   row_start = (int*)(shift + 256);     // N+1
    int*   fill      = row_start + NN + 1;      // N
    int*   deg_i     = fill + NN;               // N
    int*   sorted    = deg_i + NN;              // 9N
    int*   bsum      = sorted + EE + NN;        // ~400
    ushort* Wgt  = (ushort*)(ws + 23 * N);      // 64x256
    ushort* W1t  = Wgt + 16384;                 // 256x64
    ushort* W2t  = W1t + 16384;                 // 256x256
    ushort* h0b  = (ushort*)(ws + 24 * N);      // [N,64] bf16 (32N fl); reused as x1b
    ushort* x1b  = h0b;
    float*  agg0 = ws + 56 * N;                 // [N,64] fp32 (64N fl)
    ushort* h1b  = (ushort*)(ws + 120 * N);     // [N,256] bf16 (128N fl); also h2
    ushort* x2b  = (ushort*)(ws + 248 * N);     // [N,256] bf16 (128N fl)
    ushort* xb   = x2b;                         // alias: x bf16, dead before x2b live
    ushort* yb   = (ushort*)(ws + 376 * N);     // [N,256] bf16 gather out (128N fl)
    float*  attb = ws + 504 * N;                // (E+N)*4 floats (36N fl) -> ends 540N
    float*  inv_ls = ws + 540 * N;              // 4N floats -> ends 544N
    float*  outp = (float*)d_out;

    const int BLK = 256;
    dim3 blk(BLK);
    const int NBLK_N = (NN + 255) / 256;        // 391

    // ===== CSR build =====
    hipMemsetAsync(fill, 0, 2L * NN * sizeof(int), stream);
    hist_kernel<<<(EE + 255) / 256, blk, 0, stream>>>(ei, deg_i);
    dinv_kernel<<<NBLK_N, blk, 0, stream>>>(deg_i, dinv);
    scan_k1<<<NBLK_N, blk, 0, stream>>>(deg_i, row_start, bsum);
    scan_k2<<<1, 512, 0, stream>>>(bsum, NBLK_N);
    scan_k3<<<(NN + 1 + 255) / 256, blk, 0, stream>>>(row_start, bsum);
    scatter_kernel<<<(EE + NN + 255) / 256, blk, 0, stream>>>(ei, row_start, fill, sorted);

    // ===== conversions =====
    convert_f32_bf16<<<(int)((N * 256 / 4 + 255) / 256), blk, 0, stream>>>(x, xb, N * 256 / 4);
    transpose_w<<<(FIN * CH + 255) / 256, blk, 0, stream>>>(W_gcn, Wgt, FIN, CH);
    transpose_w<<<(CH * C1 + 255) / 256, blk, 0, stream>>>(W1, W1t, CH, C1);
    transpose_w<<<(C1 * C1 + 255) / 256, blk, 0, stream>>>(W2, W2t, C1, C1);

    // ===== GCN =====
    gemm_mfma<<<dim3(CH / 64, (NN + 63) / 64), blk, 0, stream>>>(xb, Wgt, h0b, FIN, CH);
    gcn_gather<<<(NN + 3) / 4, blk, 0, stream>>>(row_start, sorted, dinv, h0b, agg0);
    hipMemsetAsync(sums, 0, 512 * sizeof(float), stream);
    bn_stats64<<<(NN + 63) / 64, blk, 0, stream>>>(agg0, b_gcn, sums, sumsq);
    bn_finalize<<<1, CH, 0, stream>>>(sums, sumsq, g0, beta0, scale, shift, CH);
    bn_apply_gcn<<<(int)(N * 16 / BLK), blk, 0, stream>>>(agg0, b_gcn, scale, shift, x1b);

    // ===== GAT layer 1 =====
    gemm_mfma<<<dim3(C1 / 64, (NN + 63) / 64), blk, 0, stream>>>(x1b, W1t, h1b, CH, C1);
    gat_alpha<<<NN, blk, 0, stream>>>(h1b, a_src1, a_dst1, alpha_s, alpha_d);
    gat_att<<<(NN + 3) / 4, blk, 0, stream>>>(row_start, sorted, alpha_s, alpha_d, attb, inv_ls);
    gat_gather<<<(NN + 3) / 4, blk, 0, stream>>>(row_start, sorted, attb, inv_ls, h1b, yb);
    hipMemsetAsync(sums, 0, 512 * sizeof(float), stream);
    bn_stats256<<<(NN + 31) / 32, blk, 0, stream>>>(yb, b1, sums, sumsq);
    bn_finalize<<<1, C1, 0, stream>>>(sums, sumsq, g1, beta1, scale, shift, C1);
    bn_apply_gat<<<(int)(N * 32 / BLK), blk, 0, stream>>>(yb, b1, scale, shift, x2b, 1);

    // ===== GAT layer 2 =====
    gemm_mfma<<<dim3(C1 / 64, (NN + 63) / 64), blk, 0, stream>>>(x2b, W2t, h1b, C1, C1);
    gat_alpha<<<NN, blk, 0, stream>>>(h1b, a_src2, a_dst2, alpha_s, alpha_d);
    gat_att<<<(NN + 3) / 4, blk, 0, stream>>>(row_start, sorted, alpha_s, alpha_d, attb, inv_ls);
    gat_gather<<<(NN + 3) / 4, blk, 0, stream>>>(row_start, sorted, attb, inv_ls, h1b, yb);
    hipMemsetAsync(sums, 0, 512 * sizeof(float), stream);
    bn_stats256<<<(NN + 31) / 32, blk, 0, stream>>>(yb, b2, sums, sumsq);
    bn_finalize<<<1, C1, 0, stream>>>(sums, sumsq, g2, beta2, scale, shift, C1);
    bn_apply_gat<<<(int)(N * 32 / BLK), blk, 0, stream>>>(yb, b2, scale, shift, outp, 0);
}

// Round 3
// 965.624 us; speedup vs baseline: 1.2329x; 1.2329x over previous
//
#include <hip/hip_runtime.h>
#include <hip/hip_bf16.h>
#include <math.h>

#define NN 100000
#define EE 800000
#define FIN 256
#define CH 64      // HID
#define C1 256     // H*HID
#define BN_EPS 1e-5f
#define NEG_SLOPE 0.2f

typedef __attribute__((ext_vector_type(8))) short short8;
typedef __attribute__((ext_vector_type(8))) unsigned short u16x8;
typedef __attribute__((ext_vector_type(4))) float f32x4;

__device__ __forceinline__ float bf2f(ushort u) {
    return __uint_as_float(((unsigned)u) << 16);
}
__device__ __forceinline__ ushort f2bf(float f) {
    unsigned u = __float_as_uint(f);
    return (ushort)((u + 0x7FFF + ((u >> 16) & 1)) >> 16);   // RNE
}

// ================= CSR build =================
__global__ void hist_kernel(const int* __restrict__ ei, int* __restrict__ deg) {
    int t = blockIdx.x * 256 + threadIdx.x;
    if (t < EE) atomicAdd(&deg[ei[EE + t]], 1);
}
__global__ void dinv_kernel(const int* __restrict__ deg, float* __restrict__ dinv) {
    int i = blockIdx.x * 256 + threadIdx.x;
    if (i < NN) dinv[i] = rsqrtf((float)(deg[i] + 1));  // +1 self loop
}
__global__ void scan_k1(const int* __restrict__ deg, int* __restrict__ row_start,
                        int* __restrict__ bsum) {
    __shared__ int sh[256];
    int t = threadIdx.x;
    int i = blockIdx.x * 256 + t;
    int v = (i < NN) ? (deg[i] + 1) : 0;
    sh[t] = v;
    __syncthreads();
    for (int off = 1; off < 256; off <<= 1) {
        int add = (t >= off) ? sh[t - off] : 0;
        __syncthreads();
        sh[t] += add;
        __syncthreads();
    }
    if (i < NN) row_start[i] = sh[t] - v;
    if (t == 255) bsum[blockIdx.x] = sh[255];
}
__global__ void scan_k2(int* __restrict__ bsum, int nb) {
    __shared__ int sh[512];
    int t = threadIdx.x;
    int v = (t < nb) ? bsum[t] : 0;
    sh[t] = v;
    __syncthreads();
    for (int off = 1; off < 512; off <<= 1) {
        int add = (t >= off) ? sh[t - off] : 0;
        __syncthreads();
        sh[t] += add;
        __syncthreads();
    }
    if (t < nb) bsum[t] = sh[t] - v;
}
__global__ void scan_k3(int* __restrict__ row_start, const int* __restrict__ bsum) {
    int i = blockIdx.x * 256 + threadIdx.x;
    if (i < NN) row_start[i] += bsum[i >> 8];
    if (i == NN) row_start[NN] = EE + NN;
}
__global__ void scatter_kernel(const int* __restrict__ ei, const int* __restrict__ row_start,
                               int* __restrict__ fill, int* __restrict__ sorted) {
    int t = blockIdx.x * 256 + threadIdx.x;
    if (t >= EE + NN) return;
    int s, d;
    if (t < EE) { s = ei[t]; d = ei[EE + t]; }
    else        { s = t - EE; d = s; }
    int pos = atomicAdd(&fill[d], 1);
    sorted[row_start[d] + pos] = s;
}

// ================= conversions =================
__global__ void convert_f32_bf16(const float* __restrict__ in, ushort* __restrict__ out, long n4) {
    long i = (long)blockIdx.x * 256 + threadIdx.x;
    if (i < n4) {
        float4 v = *(const float4*)&in[i * 4];
        ushort4 o;
        o.x = f2bf(v.x); o.y = f2bf(v.y); o.z = f2bf(v.z); o.w = f2bf(v.w);
        *(ushort4*)&out[i * 4] = o;
    }
}
__global__ void transpose_w(const float* __restrict__ W, ushort* __restrict__ Bt, int M, int K) {
    int idx = blockIdx.x * 256 + threadIdx.x;
    if (idx < M * K) {
        int m = idx / K, n = idx % K;
        Bt[n * M + m] = f2bf(W[idx]);
    }
}

// ================= bf16 MFMA GEMM =================
// C[N x K] = A[N x M] @ B[M x K]; A bf16 row-major, Bt bf16 [K][M], C bf16.
__global__ __launch_bounds__(256) void gemm_mfma(
        const ushort* __restrict__ A, const ushort* __restrict__ Bt,
        ushort* __restrict__ C, int M, int K) {
    __shared__ ushort As[64][40];
    __shared__ ushort Bs[64][40];
    int t = threadIdx.x;
    int w = t >> 6;
    int l = t & 63;
    int rowBase = blockIdx.y * 64;
    int colBase = blockIdx.x * 64;
    int srow = t >> 2;
    int sk = (t & 3) * 8;
    int m = l & 15, q = l >> 4;
    f32x4 acc[4] = {};
    for (int k0 = 0; k0 < M; k0 += 32) {
        uint4 av = make_uint4(0u, 0u, 0u, 0u);
        int gr = rowBase + srow;
        if (gr < NN) av = *(const uint4*)&A[(long)gr * M + k0 + sk];
        uint4 bv = *(const uint4*)&Bt[(long)(colBase + srow) * M + k0 + sk];
        *(uint4*)&As[srow][sk] = av;
        *(uint4*)&Bs[srow][sk] = bv;
        __syncthreads();
        short8 af = *(const short8*)&As[w * 16 + m][q * 8];
#pragma unroll
        for (int c = 0; c < 4; ++c) {
            short8 bf = *(const short8*)&Bs[c * 16 + m][q * 8];
            acc[c] = __builtin_amdgcn_mfma_f32_16x16x32_bf16(af, bf, acc[c], 0, 0, 0);
        }
        __syncthreads();
    }
#pragma unroll
    for (int c = 0; c < 4; ++c) {
#pragma unroll
        for (int r = 0; r < 4; ++r) {
            int orow = rowBase + w * 16 + q * 4 + r;
            if (orow < NN) C[(long)orow * K + colBase + c * 16 + m] = f2bf(acc[c][r]);
        }
    }
}

// ================= GCN gather =================
// one wave per node; 16-lane sub-groups each take edges at stride 4;
// ushort4 loads (8B/lane), shfl-xor reduce, f32x4 store.
__global__ __launch_bounds__(256) void gcn_gather(
        const int* __restrict__ row_start, const int* __restrict__ sorted,
        const float* __restrict__ dinv, const ushort* __restrict__ h0,
        float* __restrict__ agg) {
    int node = blockIdx.x * 4 + (threadIdx.x >> 6);
    if (node >= NN) return;
    int l = threadIdx.x & 63;
    int sub = l >> 4;           // edge sub-slot 0..3
    int ch = (l & 15) * 4;      // 4 channels of 64
    int b = row_start[node], e = row_start[node + 1];
    float a0 = 0.f, a1 = 0.f, a2 = 0.f, a3 = 0.f;
    for (int i = b + sub; i < e; i += 4) {
        int s = sorted[i];
        float dv = dinv[s];
        ushort4 v = *(const ushort4*)&h0[(long)s * 64 + ch];
        a0 += dv * bf2f(v.x);
        a1 += dv * bf2f(v.y);
        a2 += dv * bf2f(v.z);
        a3 += dv * bf2f(v.w);
    }
    a0 += __shfl_xor(a0, 16); a1 += __shfl_xor(a1, 16);
    a2 += __shfl_xor(a2, 16); a3 += __shfl_xor(a3, 16);
    a0 += __shfl_xor(a0, 32); a1 += __shfl_xor(a1, 32);
    a2 += __shfl_xor(a2, 32); a3 += __shfl_xor(a3, 32);
    if (sub == 0) {
        float dn = dinv[node];
        f32x4 o;
        o[0] = a0 * dn; o[1] = a1 * dn; o[2] = a2 * dn; o[3] = a3 * dn;
        *(f32x4*)&agg[(long)node * 64 + ch] = o;
    }
}

// ================= BatchNorm =================
// C=64, fp32 input, relu pre-BN. grid = ceil(NN/64), block 256.
__global__ __launch_bounds__(256) void bn_stats64(
        const float* __restrict__ x, const float* __restrict__ bias,
        float* __restrict__ sums, float* __restrict__ sumsq) {
    __shared__ float red[512];
    int t = threadIdx.x;
    int col = t & 63, sub = t >> 6;
    int r0 = blockIdx.x * 64;
    int r1 = min(r0 + 64, NN);
    float b = bias[col];
    float s = 0.f, ss = 0.f;
    for (int r = r0 + sub; r < r1; r += 4) {
        float v = fmaxf(x[(long)r * 64 + col] + b, 0.f);
        s += v; ss += v * v;
    }
    red[t] = s; red[256 + t] = ss;
    __syncthreads();
    if (t < 64) {
        s = red[t] + red[t + 64] + red[t + 128] + red[t + 192];
        ss = red[256 + t] + red[320 + t] + red[384 + t] + red[448 + t];
        atomicAdd(&sums[col], s);
        atomicAdd(&sumsq[col], ss);
    }
}
// C=256, bf16 input, no relu. grid = ceil(NN/32), block 256.
__global__ __launch_bounds__(256) void bn_stats256(
        const ushort* __restrict__ x, const float* __restrict__ bias,
        float* __restrict__ sums, float* __restrict__ sumsq) {
    int t = threadIdx.x;
    int r0 = blockIdx.x * 32;
    int r1 = min(r0 + 32, NN);
    float b = bias[t];
    float s = 0.f, ss = 0.f;
    for (int r = r0; r < r1; ++r) {
        float v = bf2f(x[(long)r * 256 + t]) + b;
        s += v; ss += v * v;
    }
    atomicAdd(&sums[t], s);
    atomicAdd(&sumsq[t], ss);
}
__global__ void bn_finalize(const float* __restrict__ sums, const float* __restrict__ sumsq,
                            const float* __restrict__ g, const float* __restrict__ beta,
                            float* __restrict__ scale, float* __restrict__ shift, int C) {
    int c = threadIdx.x;
    if (c < C) {
        float mean = sums[c] / (float)NN;
        float var = sumsq[c] / (float)NN - mean * mean;
        float sc = g[c] * rsqrtf(var + BN_EPS);
        scale[c] = sc;
        shift[c] = beta[c] - mean * sc;
    }
}
// GCN BN apply: fp32 in, relu pre-BN, bf16 out.
// 4 rows per wave (16 lanes/row, 4 ch/lane); tables hoisted out of row loop.
__global__ __launch_bounds__(256) void bn_apply_gcn(
        const float* __restrict__ x, const float* __restrict__ bias,
        const float* __restrict__ scale, const float* __restrict__ shift,
        ushort* __restrict__ out) {
    int l = threadIdx.x & 63;
    int wv = blockIdx.x * 4 + (threadIdx.x >> 6);
    int nw = gridDim.x * 4;
    int c = (l & 15) * 4;
    int sub = l >> 4;
    f32x4 b4  = *(const f32x4*)&bias[c];
    f32x4 sc4 = *(const f32x4*)&scale[c];
    f32x4 sh4 = *(const f32x4*)&shift[c];
    for (int r = wv * 4 + sub; r < NN; r += nw * 4) {
        f32x4 v = *(const f32x4*)&x[(long)r * 64 + c];
        ushort4 o;
        o.x = f2bf(sc4[0] * fmaxf(v[0] + b4[0], 0.f) + sh4[0]);
        o.y = f2bf(sc4[1] * fmaxf(v[1] + b4[1], 0.f) + sh4[1]);
        o.z = f2bf(sc4[2] * fmaxf(v[2] + b4[2], 0.f) + sh4[2]);
        o.w = f2bf(sc4[3] * fmaxf(v[3] + b4[3], 0.f) + sh4[3]);
        *(ushort4*)&out[(long)r * 64 + c] = o;
    }
}
// GAT BN apply: bf16 in, ELU post-BN, bf16 or fp32 out.
// One wave per row; lane l owns channels 4l..4l+3; tables hoisted.
__global__ __launch_bounds__(256) void bn_apply_gat(
        const ushort* __restrict__ x, const float* __restrict__ bias,
        const float* __restrict__ scale, const float* __restrict__ shift,
        void* __restrict__ out, int out_bf16) {
    int l = threadIdx.x & 63;
    int wv = blockIdx.x * 4 + (threadIdx.x >> 6);
    int nw = gridDim.x * 4;
    int c = l * 4;
    f32x4 b4  = *(const f32x4*)&bias[c];
    f32x4 sc4 = *(const f32x4*)&scale[c];
    f32x4 sh4 = *(const f32x4*)&shift[c];
    if (out_bf16) {
        ushort* ob = (ushort*)out;
        for (int r = wv; r < NN; r += nw) {
            ushort4 v = *(const ushort4*)&x[(long)r * 256 + c];
            float t0 = sc4[0] * (bf2f(v.x) + b4[0]) + sh4[0];
            float t1 = sc4[1] * (bf2f(v.y) + b4[1]) + sh4[1];
            float t2 = sc4[2] * (bf2f(v.z) + b4[2]) + sh4[2];
            float t3 = sc4[3] * (bf2f(v.w) + b4[3]) + sh4[3];
            t0 = (t0 > 0.f) ? t0 : (__expf(t0) - 1.f);
            t1 = (t1 > 0.f) ? t1 : (__expf(t1) - 1.f);
            t2 = (t2 > 0.f) ? t2 : (__expf(t2) - 1.f);
            t3 = (t3 > 0.f) ? t3 : (__expf(t3) - 1.f);
            ushort4 o;
            o.x = f2bf(t0); o.y = f2bf(t1); o.z = f2bf(t2); o.w = f2bf(t3);
            *(ushort4*)&ob[(long)r * 256 + c] = o;
        }
    } else {
        float* of = (float*)out;
        for (int r = wv; r < NN; r += nw) {
            ushort4 v = *(const ushort4*)&x[(long)r * 256 + c];
            float t0 = sc4[0] * (bf2f(v.x) + b4[0]) + sh4[0];
            float t1 = sc4[1] * (bf2f(v.y) + b4[1]) + sh4[1];
            float t2 = sc4[2] * (bf2f(v.z) + b4[2]) + sh4[2];
            float t3 = sc4[3] * (bf2f(v.w) + b4[3]) + sh4[3];
            f32x4 o;
            o[0] = (t0 > 0.f) ? t0 : (__expf(t0) - 1.f);
            o[1] = (t1 > 0.f) ? t1 : (__expf(t1) - 1.f);
            o[2] = (t2 > 0.f) ? t2 : (__expf(t2) - 1.f);
            o[3] = (t3 > 0.f) ? t3 : (__expf(t3) - 1.f);
            *(f32x4*)&of[(long)r * 256 + c] = o;
        }
    }
}

// ================= GAT =================
__global__ void gat_alpha(const ushort* __restrict__ h, const float* __restrict__ a_src,
                          const float* __restrict__ a_dst,
                          float* __restrict__ alpha_s, float* __restrict__ alpha_d) {
    int n = blockIdx.x;
    int t = threadIdx.x;
    float hv = bf2f(h[(long)n * 256 + t]);
    float vs = hv * a_src[t];
    float vd = hv * a_dst[t];
    for (int off = 32; off > 0; off >>= 1) {
        vs += __shfl_down(vs, off);
        vd += __shfl_down(vd, off);
    }
    if ((t & 63) == 0) {
        int head = t >> 6;
        alpha_s[n * 4 + head] = vs;
        alpha_d[n * 4 + head] = vd;
    }
}

// one wave per node; lane = edge_k*4 + head; 2 passes; stores UNNORMALIZED w
// plus per-(node,head) 1/sum into inv_ls (normalization applied in gather).
__global__ __launch_bounds__(256) void gat_att(
        const int* __restrict__ row_start, const int* __restrict__ sorted,
        const float* __restrict__ as, const float* __restrict__ ad,
        float* __restrict__ att, float* __restrict__ inv_ls) {
    int node = blockIdx.x * 4 + (threadIdx.x >> 6);
    if (node >= NN) return;
    int l = threadIdx.x & 63;
    int h = l & 3, k = l >> 2;
    int b = row_start[node], e = row_start[node + 1];
    float adn = ad[node * 4 + h];
    // pass 1: per-head max
    float lm = -1e30f;
    for (int i = b + k; i < e; i += 16) {
        int s = sorted[i];
        float ev = as[s * 4 + h] + adn;
        ev = (ev > 0.f) ? ev : NEG_SLOPE * ev;
        lm = fmaxf(lm, ev);
    }
    lm = fmaxf(lm, __shfl_xor(lm, 4));
    lm = fmaxf(lm, __shfl_xor(lm, 8));
    lm = fmaxf(lm, __shfl_xor(lm, 16));
    lm = fmaxf(lm, __shfl_xor(lm, 32));
    // pass 2: exp, store unnormalized, per-head sum
    float ls = 0.f;
    for (int i = b + k; i < e; i += 16) {
        int s = sorted[i];
        float ev = as[s * 4 + h] + adn;
        ev = (ev > 0.f) ? ev : NEG_SLOPE * ev;
        float wv = __expf(ev - lm);
        att[(long)i * 4 + h] = wv;
        ls += wv;
    }
    ls += __shfl_xor(ls, 4);
    ls += __shfl_xor(ls, 8);
    ls += __shfl_xor(ls, 16);
    ls += __shfl_xor(ls, 32);
    if (k == 0) inv_ls[node * 4 + h] = 1.0f / ls;
}

// one WAVE per node: lane l owns channels 4l..4l+3 (ushort4 = full 512B row
// per wave-instruction), 4-edge unroll, inv-sum applied at the end.
__global__ __launch_bounds__(256) void gat_gather(
        const int* __restrict__ row_start, const int* __restrict__ sorted,
        const float* __restrict__ att, const float* __restrict__ inv_ls,
        const ushort* __restrict__ h, ushort* __restrict__ out) {
    int node = blockIdx.x * 4 + (threadIdx.x >> 6);
    if (node >= NN) return;
    int l = threadIdx.x & 63;
    int head = l >> 4;                      // channels 4l..4l+3 share one head
    int b = row_start[node], e = row_start[node + 1];
    float a0 = 0.f, a1 = 0.f, a2 = 0.f, a3 = 0.f;
    int i = b;
    for (; i + 3 < e; i += 4) {
        int s0 = sorted[i], s1 = sorted[i + 1], s2 = sorted[i + 2], s3 = sorted[i + 3];
        float w0 = att[(long)i * 4 + head];
        float w1 = att[(long)(i + 1) * 4 + head];
        float w2 = att[(long)(i + 2) * 4 + head];
        float w3 = att[(long)(i + 3) * 4 + head];
        ushort4 v0 = *(const ushort4*)&h[(long)s0 * 256 + l * 4];
        ushort4 v1 = *(const ushort4*)&h[(long)s1 * 256 + l * 4];
        ushort4 v2 = *(const ushort4*)&h[(long)s2 * 256 + l * 4];
        ushort4 v3 = *(const ushort4*)&h[(long)s3 * 256 + l * 4];
        a0 += w0 * bf2f(v0.x) + w1 * bf2f(v1.x) + w2 * bf2f(v2.x) + w3 * bf2f(v3.x);
        a1 += w0 * bf2f(v0.y) + w1 * bf2f(v1.y) + w2 * bf2f(v2.y) + w3 * bf2f(v3.y);
        a2 += w0 * bf2f(v0.z) + w1 * bf2f(v1.z) + w2 * bf2f(v2.z) + w3 * bf2f(v3.z);
        a3 += w0 * bf2f(v0.w) + w1 * bf2f(v1.w) + w2 * bf2f(v2.w) + w3 * bf2f(v3.w);
    }
    for (; i < e; ++i) {
        int s0 = sorted[i];
        float w0 = att[(long)i * 4 + head];
        ushort4 v0 = *(const ushort4*)&h[(long)s0 * 256 + l * 4];
        a0 += w0 * bf2f(v0.x);
        a1 += w0 * bf2f(v0.y);
        a2 += w0 * bf2f(v0.z);
        a3 += w0 * bf2f(v0.w);
    }
    float inv = inv_ls[node * 4 + head];
    ushort4 o;
    o.x = f2bf(a0 * inv);
    o.y = f2bf(a1 * inv);
    o.z = f2bf(a2 * inv);
    o.w = f2bf(a3 * inv);
    *(ushort4*)&out[(long)node * 256 + l * 4] = o;
}

// ================= launch =================
extern "C" void kernel_launch(void* const* d_in, const int* in_sizes, int n_in,
                              void* d_out, int out_size, void* d_ws, size_t ws_size,
                              hipStream_t stream) {
    const float* x      = (const float*)d_in[0];
    const int*   ei     = (const int*)d_in[1];
    const float* W_gcn  = (const float*)d_in[2];
    const float* b_gcn  = (const float*)d_in[3];
    const float* g0     = (const float*)d_in[4];
    const float* beta0  = (const float*)d_in[5];
    const float* W1     = (const float*)d_in[6];
    const float* a_src1 = (const float*)d_in[7];
    const float* a_dst1 = (const float*)d_in[8];
    const float* b1     = (const float*)d_in[9];
    const float* g1     = (const float*)d_in[10];
    const float* beta1  = (const float*)d_in[11];
    const float* W2     = (const float*)d_in[12];
    const float* a_src2 = (const float*)d_in[13];
    const float* a_dst2 = (const float*)d_in[14];
    const float* b2     = (const float*)d_in[15];
    const float* g2     = (const float*)d_in[16];
    const float* beta2  = (const float*)d_in[17];

    const long N = NN;
    float* ws = (float*)d_ws;

    // ---- layout (~544N floats; ws proven >= 641N floats) ----
    float* dinv    = ws;                        // N
    float* alpha_s = ws + N;                    // 4N
    float* alpha_d = ws + 5 * N;                // 4N
    float* sums    = ws + 9 * N;                // 256
    float* sumsq   = sums + 256;
    float* scale   = sumsq + 256;
    float* shift   = scale + 256;
    int*   row_start = (int*)(shift + 256);     // N+1
    int*   fill      = row_start + NN + 1;      // N
    int*   deg_i     = fill + NN;               // N
    int*   sorted    = deg_i + NN;              // 9N
    int*   bsum      = sorted + EE + NN;        // ~400
    ushort* Wgt  = (ushort*)(ws + 23 * N);      // 64x256
    ushort* W1t  = Wgt + 16384;                 // 256x64
    ushort* W2t  = W1t + 16384;                 // 256x256
    ushort* h0b  = (ushort*)(ws + 24 * N);      // [N,64] bf16 (32N fl); reused as x1b
    ushort* x1b  = h0b;
    float*  agg0 = ws + 56 * N;                 // [N,64] fp32 (64N fl)
    ushort* h1b  = (ushort*)(ws + 120 * N);     // [N,256] bf16 (128N fl); also h2
    ushort* x2b  = (ushort*)(ws + 248 * N);     // [N,256] bf16 (128N fl)
    ushort* xb   = x2b;                         // alias: x bf16, dead before x2b live
    ushort* yb   = (ushort*)(ws + 376 * N);     // [N,256] bf16 gather out (128N fl)
    float*  attb = ws + 504 * N;                // (E+N)*4 floats (36N fl) -> ends 540N
    float*  inv_ls = ws + 540 * N;              // 4N floats -> ends 544N
    float*  outp = (float*)d_out;

    const int BLK = 256;
    dim3 blk(BLK);
    const int NBLK_N = (NN + 255) / 256;        // 391

    // ===== CSR build =====
    hipMemsetAsync(fill, 0, 2L * NN * sizeof(int), stream);
    hist_kernel<<<(EE + 255) / 256, blk, 0, stream>>>(ei, deg_i);
    dinv_kernel<<<NBLK_N, blk, 0, stream>>>(deg_i, dinv);
    scan_k1<<<NBLK_N, blk, 0, stream>>>(deg_i, row_start, bsum);
    scan_k2<<<1, 512, 0, stream>>>(bsum, NBLK_N);
    scan_k3<<<(NN + 1 + 255) / 256, blk, 0, stream>>>(row_start, bsum);
    scatter_kernel<<<(EE + NN + 255) / 256, blk, 0, stream>>>(ei, row_start, fill, sorted);

    // ===== conversions =====
    convert_f32_bf16<<<(int)((N * 256 / 4 + 255) / 256), blk, 0, stream>>>(x, xb, N * 256 / 4);
    transpose_w<<<(FIN * CH + 255) / 256, blk, 0, stream>>>(W_gcn, Wgt, FIN, CH);
    transpose_w<<<(CH * C1 + 255) / 256, blk, 0, stream>>>(W1, W1t, CH, C1);
    transpose_w<<<(C1 * C1 + 255) / 256, blk, 0, stream>>>(W2, W2t, C1, C1);

    // ===== GCN =====
    gemm_mfma<<<dim3(CH / 64, (NN + 63) / 64), blk, 0, stream>>>(xb, Wgt, h0b, FIN, CH);
    gcn_gather<<<(NN + 3) / 4, blk, 0, stream>>>(row_start, sorted, dinv, h0b, agg0);
    hipMemsetAsync(sums, 0, 512 * sizeof(float), stream);
    bn_stats64<<<(NN + 63) / 64, blk, 0, stream>>>(agg0, b_gcn, sums, sumsq);
    bn_finalize<<<1, CH, 0, stream>>>(sums, sumsq, g0, beta0, scale, shift, CH);
    bn_apply_gcn<<<1024, blk, 0, stream>>>(agg0, b_gcn, scale, shift, x1b);

    // ===== GAT layer 1 =====
    gemm_mfma<<<dim3(C1 / 64, (NN + 63) / 64), blk, 0, stream>>>(x1b, W1t, h1b, CH, C1);
    gat_alpha<<<NN, blk, 0, stream>>>(h1b, a_src1, a_dst1, alpha_s, alpha_d);
    gat_att<<<(NN + 3) / 4, blk, 0, stream>>>(row_start, sorted, alpha_s, alpha_d, attb, inv_ls);
    gat_gather<<<(NN + 3) / 4, blk, 0, stream>>>(row_start, sorted, attb, inv_ls, h1b, yb);
    hipMemsetAsync(sums, 0, 512 * sizeof(float), stream);
    bn_stats256<<<(NN + 31) / 32, blk, 0, stream>>>(yb, b1, sums, sumsq);
    bn_finalize<<<1, C1, 0, stream>>>(sums, sumsq, g1, beta1, scale, shift, C1);
    bn_apply_gat<<<2048, blk, 0, stream>>>(yb, b1, scale, shift, x2b, 1);

    // ===== GAT layer 2 =====
    gemm_mfma<<<dim3(C1 / 64, (NN + 63) / 64), blk, 0, stream>>>(x2b, W2t, h1b, C1, C1);
    gat_alpha<<<NN, blk, 0, stream>>>(h1b, a_src2, a_dst2, alpha_s, alpha_d);
    gat_att<<<(NN + 3) / 4, blk, 0, stream>>>(row_start, sorted, alpha_s, alpha_d, attb, inv_ls);
    gat_gather<<<(NN + 3) / 4, blk, 0, stream>>>(row_start, sorted, attb, inv_ls, h1b, yb);
    hipMemsetAsync(sums, 0, 512 * sizeof(float), stream);
    bn_stats256<<<(NN + 31) / 32, blk, 0, stream>>>(yb, b2, sums, sumsq);
    bn_finalize<<<1, C1, 0, stream>>>(sums, sumsq, g2, beta2, scale, shift, C1);
    bn_apply_gat<<<2048, blk, 0, stream>>>(yb, b2, scale, shift, outp, 0);
}

// Round 4
// 934.283 us; speedup vs baseline: 1.2742x; 1.0335x over previous
//
#include <hip/hip_runtime.h>
#include <hip/hip_bf16.h>
#include <math.h>

#define NN 100000
#define EE 800000
#define FIN 256
#define CH 64      // HID
#define C1 256     // H*HID
#define BN_EPS 1e-5f
#define NEG_SLOPE 0.2f

typedef __attribute__((ext_vector_type(8))) short short8;
typedef __attribute__((ext_vector_type(8))) unsigned short u16x8;
typedef __attribute__((ext_vector_type(4))) float f32x4;

__device__ __forceinline__ float bf2f(ushort u) {
    return __uint_as_float(((unsigned)u) << 16);
}
__device__ __forceinline__ ushort f2bf(float f) {
    unsigned u = __float_as_uint(f);
    return (ushort)((u + 0x7FFF + ((u >> 16) & 1)) >> 16);   // RNE
}

// ================= CSR build =================
__global__ void hist_kernel(const int* __restrict__ ei, int* __restrict__ deg) {
    int t = blockIdx.x * 256 + threadIdx.x;
    if (t < EE) atomicAdd(&deg[ei[EE + t]], 1);
}
__global__ void dinv_kernel(const int* __restrict__ deg, float* __restrict__ dinv) {
    int i = blockIdx.x * 256 + threadIdx.x;
    if (i < NN) dinv[i] = rsqrtf((float)(deg[i] + 1));  // +1 self loop
}
__global__ void scan_k1(const int* __restrict__ deg, int* __restrict__ row_start,
                        int* __restrict__ bsum) {
    __shared__ int sh[256];
    int t = threadIdx.x;
    int i = blockIdx.x * 256 + t;
    int v = (i < NN) ? (deg[i] + 1) : 0;
    sh[t] = v;
    __syncthreads();
    for (int off = 1; off < 256; off <<= 1) {
        int add = (t >= off) ? sh[t - off] : 0;
        __syncthreads();
        sh[t] += add;
        __syncthreads();
    }
    if (i < NN) row_start[i] = sh[t] - v;
    if (t == 255) bsum[blockIdx.x] = sh[255];
}
__global__ void scan_k2(int* __restrict__ bsum, int nb) {
    __shared__ int sh[512];
    int t = threadIdx.x;
    int v = (t < nb) ? bsum[t] : 0;
    sh[t] = v;
    __syncthreads();
    for (int off = 1; off < 512; off <<= 1) {
        int add = (t >= off) ? sh[t - off] : 0;
        __syncthreads();
        sh[t] += add;
        __syncthreads();
    }
    if (t < nb) bsum[t] = sh[t] - v;
}
__global__ void scan_k3(int* __restrict__ row_start, const int* __restrict__ bsum) {
    int i = blockIdx.x * 256 + threadIdx.x;
    if (i < NN) row_start[i] += bsum[i >> 8];
    if (i == NN) row_start[NN] = EE + NN;
}
__global__ void scatter_kernel(const int* __restrict__ ei, const int* __restrict__ row_start,
                               int* __restrict__ fill, int* __restrict__ sorted) {
    int t = blockIdx.x * 256 + threadIdx.x;
    if (t >= EE + NN) return;
    int s, d;
    if (t < EE) { s = ei[t]; d = ei[EE + t]; }
    else        { s = t - EE; d = s; }
    int pos = atomicAdd(&fill[d], 1);
    sorted[row_start[d] + pos] = s;
}

// ================= conversions =================
__global__ void convert_f32_bf16(const float* __restrict__ in, ushort* __restrict__ out, long n4) {
    long i = (long)blockIdx.x * 256 + threadIdx.x;
    if (i < n4) {
        float4 v = *(const float4*)&in[i * 4];
        ushort4 o;
        o.x = f2bf(v.x); o.y = f2bf(v.y); o.z = f2bf(v.z); o.w = f2bf(v.w);
        *(ushort4*)&out[i * 4] = o;
    }
}
__global__ void transpose_w(const float* __restrict__ W, ushort* __restrict__ Bt, int M, int K) {
    int idx = blockIdx.x * 256 + threadIdx.x;
    if (idx < M * K) {
        int m = idx / K, n = idx % K;
        Bt[n * M + m] = f2bf(W[idx]);
    }
}

// ================= bf16 MFMA GEMM =================
// C[N x K] = A[N x M] @ B[M x K]; A bf16 row-major, Bt bf16 [K][M], C bf16.
__global__ __launch_bounds__(256) void gemm_mfma(
        const ushort* __restrict__ A, const ushort* __restrict__ Bt,
        ushort* __restrict__ C, int M, int K) {
    __shared__ ushort As[64][40];
    __shared__ ushort Bs[64][40];
    int t = threadIdx.x;
    int w = t >> 6;
    int l = t & 63;
    int rowBase = blockIdx.y * 64;
    int colBase = blockIdx.x * 64;
    int srow = t >> 2;
    int sk = (t & 3) * 8;
    int m = l & 15, q = l >> 4;
    f32x4 acc[4] = {};
    for (int k0 = 0; k0 < M; k0 += 32) {
        uint4 av = make_uint4(0u, 0u, 0u, 0u);
        int gr = rowBase + srow;
        if (gr < NN) av = *(const uint4*)&A[(long)gr * M + k0 + sk];
        uint4 bv = *(const uint4*)&Bt[(long)(colBase + srow) * M + k0 + sk];
        *(uint4*)&As[srow][sk] = av;
        *(uint4*)&Bs[srow][sk] = bv;
        __syncthreads();
        short8 af = *(const short8*)&As[w * 16 + m][q * 8];
#pragma unroll
        for (int c = 0; c < 4; ++c) {
            short8 bf = *(const short8*)&Bs[c * 16 + m][q * 8];
            acc[c] = __builtin_amdgcn_mfma_f32_16x16x32_bf16(af, bf, acc[c], 0, 0, 0);
        }
        __syncthreads();
    }
#pragma unroll
    for (int c = 0; c < 4; ++c) {
#pragma unroll
        for (int r = 0; r < 4; ++r) {
            int orow = rowBase + w * 16 + q * 4 + r;
            if (orow < NN) C[(long)orow * K + colBase + c * 16 + m] = f2bf(acc[c][r]);
        }
    }
}

// ================= GCN gather =================
// one wave per node; 16-lane sub-groups each take edges at stride 4;
// ushort4 loads (8B/lane), shfl-xor reduce, f32x4 store.
__global__ __launch_bounds__(256) void gcn_gather(
        const int* __restrict__ row_start, const int* __restrict__ sorted,
        const float* __restrict__ dinv, const ushort* __restrict__ h0,
        float* __restrict__ agg) {
    int node = blockIdx.x * 4 + (threadIdx.x >> 6);
    if (node >= NN) return;
    int l = threadIdx.x & 63;
    int sub = l >> 4;           // edge sub-slot 0..3
    int ch = (l & 15) * 4;      // 4 channels of 64
    int b = row_start[node], e = row_start[node + 1];
    float a0 = 0.f, a1 = 0.f, a2 = 0.f, a3 = 0.f;
    for (int i = b + sub; i < e; i += 4) {
        int s = sorted[i];
        float dv = dinv[s];
        ushort4 v = *(const ushort4*)&h0[(long)s * 64 + ch];
        a0 += dv * bf2f(v.x);
        a1 += dv * bf2f(v.y);
        a2 += dv * bf2f(v.z);
        a3 += dv * bf2f(v.w);
    }
    a0 += __shfl_xor(a0, 16); a1 += __shfl_xor(a1, 16);
    a2 += __shfl_xor(a2, 16); a3 += __shfl_xor(a3, 16);
    a0 += __shfl_xor(a0, 32); a1 += __shfl_xor(a1, 32);
    a2 += __shfl_xor(a2, 32); a3 += __shfl_xor(a3, 32);
    if (sub == 0) {
        float dn = dinv[node];
        f32x4 o;
        o[0] = a0 * dn; o[1] = a1 * dn; o[2] = a2 * dn; o[3] = a3 * dn;
        *(f32x4*)&agg[(long)node * 64 + ch] = o;
    }
}

// ================= BatchNorm =================
// C=64, fp32 input, relu(x+bias) pre-BN. Persistent: 512 blocks.
// Wave layout: sub = l>>4 owns row slot, c=(l&15)*4 channels, f32x4 loads.
__global__ __launch_bounds__(256) void bn_stats64(
        const float* __restrict__ x, const float* __restrict__ bias,
        float* __restrict__ sums, float* __restrict__ sumsq) {
    __shared__ float red[4][16][8];
    int l = threadIdx.x & 63;
    int w = threadIdx.x >> 6;
    int wv = blockIdx.x * 4 + w;
    int nw = gridDim.x * 4;
    int sub = l >> 4;
    int c = (l & 15) * 4;
    f32x4 b4 = *(const f32x4*)&bias[c];
    float s0 = 0.f, s1 = 0.f, s2 = 0.f, s3 = 0.f;
    float q0 = 0.f, q1 = 0.f, q2 = 0.f, q3 = 0.f;
    for (int r = wv * 4 + sub; r < NN; r += nw * 4) {
        f32x4 v = *(const f32x4*)&x[(long)r * 64 + c];
        float v0 = fmaxf(v[0] + b4[0], 0.f);
        float v1 = fmaxf(v[1] + b4[1], 0.f);
        float v2 = fmaxf(v[2] + b4[2], 0.f);
        float v3 = fmaxf(v[3] + b4[3], 0.f);
        s0 += v0; s1 += v1; s2 += v2; s3 += v3;
        q0 += v0 * v0; q1 += v1 * v1; q2 += v2 * v2; q3 += v3 * v3;
    }
    // reduce across the 4 row-slots (lanes differing in bits 4,5)
    s0 += __shfl_xor(s0, 16); s1 += __shfl_xor(s1, 16);
    s2 += __shfl_xor(s2, 16); s3 += __shfl_xor(s3, 16);
    q0 += __shfl_xor(q0, 16); q1 += __shfl_xor(q1, 16);
    q2 += __shfl_xor(q2, 16); q3 += __shfl_xor(q3, 16);
    s0 += __shfl_xor(s0, 32); s1 += __shfl_xor(s1, 32);
    s2 += __shfl_xor(s2, 32); s3 += __shfl_xor(s3, 32);
    q0 += __shfl_xor(q0, 32); q1 += __shfl_xor(q1, 32);
    q2 += __shfl_xor(q2, 32); q3 += __shfl_xor(q3, 32);
    if (sub == 0) {
        int li = l & 15;
        red[w][li][0] = s0; red[w][li][1] = s1; red[w][li][2] = s2; red[w][li][3] = s3;
        red[w][li][4] = q0; red[w][li][5] = q1; red[w][li][6] = q2; red[w][li][7] = q3;
    }
    __syncthreads();
    if (w == 0 && sub == 0) {
        int li = l & 15;
        atomicAdd(&sums[c + 0], red[0][li][0] + red[1][li][0] + red[2][li][0] + red[3][li][0]);
        atomicAdd(&sums[c + 1], red[0][li][1] + red[1][li][1] + red[2][li][1] + red[3][li][1]);
        atomicAdd(&sums[c + 2], red[0][li][2] + red[1][li][2] + red[2][li][2] + red[3][li][2]);
        atomicAdd(&sums[c + 3], red[0][li][3] + red[1][li][3] + red[2][li][3] + red[3][li][3]);
        atomicAdd(&sumsq[c + 0], red[0][li][4] + red[1][li][4] + red[2][li][4] + red[3][li][4]);
        atomicAdd(&sumsq[c + 1], red[0][li][5] + red[1][li][5] + red[2][li][5] + red[3][li][5]);
        atomicAdd(&sumsq[c + 2], red[0][li][6] + red[1][li][6] + red[2][li][6] + red[3][li][6]);
        atomicAdd(&sumsq[c + 3], red[0][li][7] + red[1][li][7] + red[2][li][7] + red[3][li][7]);
    }
}
// C=256, bf16 input, NO bias (shift-invariance: var(y+b)=var(y), and the
// bias cancels exactly in the normalized output). Persistent: 512 blocks.
// One wave covers a full row: lane l owns channels 4l..4l+3 (ushort4).
__global__ __launch_bounds__(256) void bn_stats256(
        const ushort* __restrict__ x,
        float* __restrict__ sums, float* __restrict__ sumsq) {
    __shared__ float red[4][64][8];
    int l = threadIdx.x & 63;
    int w = threadIdx.x >> 6;
    int wv = blockIdx.x * 4 + w;
    int nw = gridDim.x * 4;
    int c = l * 4;
    float s0 = 0.f, s1 = 0.f, s2 = 0.f, s3 = 0.f;
    float q0 = 0.f, q1 = 0.f, q2 = 0.f, q3 = 0.f;
    for (int r = wv; r < NN; r += nw) {
        ushort4 v = *(const ushort4*)&x[(long)r * 256 + c];
        float v0 = bf2f(v.x), v1 = bf2f(v.y), v2 = bf2f(v.z), v3 = bf2f(v.w);
        s0 += v0; s1 += v1; s2 += v2; s3 += v3;
        q0 += v0 * v0; q1 += v1 * v1; q2 += v2 * v2; q3 += v3 * v3;
    }
    red[w][l][0] = s0; red[w][l][1] = s1; red[w][l][2] = s2; red[w][l][3] = s3;
    red[w][l][4] = q0; red[w][l][5] = q1; red[w][l][6] = q2; red[w][l][7] = q3;
    __syncthreads();
    if (w == 0) {
        atomicAdd(&sums[c + 0], red[0][l][0] + red[1][l][0] + red[2][l][0] + red[3][l][0]);
        atomicAdd(&sums[c + 1], red[0][l][1] + red[1][l][1] + red[2][l][1] + red[3][l][1]);
        atomicAdd(&sums[c + 2], red[0][l][2] + red[1][l][2] + red[2][l][2] + red[3][l][2]);
        atomicAdd(&sums[c + 3], red[0][l][3] + red[1][l][3] + red[2][l][3] + red[3][l][3]);
        atomicAdd(&sumsq[c + 0], red[0][l][4] + red[1][l][4] + red[2][l][4] + red[3][l][4]);
        atomicAdd(&sumsq[c + 1], red[0][l][5] + red[1][l][5] + red[2][l][5] + red[3][l][5]);
        atomicAdd(&sumsq[c + 2], red[0][l][6] + red[1][l][6] + red[2][l][6] + red[3][l][6]);
        atomicAdd(&sumsq[c + 3], red[0][l][7] + red[1][l][7] + red[2][l][7] + red[3][l][7]);
    }
}
__global__ void bn_finalize(const float* __restrict__ sums, const float* __restrict__ sumsq,
                            const float* __restrict__ g, const float* __restrict__ beta,
                            float* __restrict__ scale, float* __restrict__ shift, int C) {
    int c = threadIdx.x;
    if (c < C) {
        float mean = sums[c] / (float)NN;
        float var = sumsq[c] / (float)NN - mean * mean;
        float sc = g[c] * rsqrtf(var + BN_EPS);
        scale[c] = sc;
        shift[c] = beta[c] - mean * sc;
    }
}
// GCN BN apply: fp32 in, relu pre-BN, bf16 out.
// 4 rows per wave (16 lanes/row, 4 ch/lane); tables hoisted out of row loop.
__global__ __launch_bounds__(256) void bn_apply_gcn(
        const float* __restrict__ x, const float* __restrict__ bias,
        const float* __restrict__ scale, const float* __restrict__ shift,
        ushort* __restrict__ out) {
    int l = threadIdx.x & 63;
    int wv = blockIdx.x * 4 + (threadIdx.x >> 6);
    int nw = gridDim.x * 4;
    int c = (l & 15) * 4;
    int sub = l >> 4;
    f32x4 b4  = *(const f32x4*)&bias[c];
    f32x4 sc4 = *(const f32x4*)&scale[c];
    f32x4 sh4 = *(const f32x4*)&shift[c];
    for (int r = wv * 4 + sub; r < NN; r += nw * 4) {
        f32x4 v = *(const f32x4*)&x[(long)r * 64 + c];
        ushort4 o;
        o.x = f2bf(sc4[0] * fmaxf(v[0] + b4[0], 0.f) + sh4[0]);
        o.y = f2bf(sc4[1] * fmaxf(v[1] + b4[1], 0.f) + sh4[1]);
        o.z = f2bf(sc4[2] * fmaxf(v[2] + b4[2], 0.f) + sh4[2]);
        o.w = f2bf(sc4[3] * fmaxf(v[3] + b4[3], 0.f) + sh4[3]);
        *(ushort4*)&out[(long)r * 64 + c] = o;
    }
}
// GAT BN apply: bf16 in, ELU post-BN, bf16 or fp32 out. NO bias (cancels:
// shift computed from raw-y mean gives identical normalized output).
// One wave per row; lane l owns channels 4l..4l+3; tables hoisted.
__global__ __launch_bounds__(256) void bn_apply_gat(
        const ushort* __restrict__ x,
        const float* __restrict__ scale, const float* __restrict__ shift,
        void* __restrict__ out, int out_bf16) {
    int l = threadIdx.x & 63;
    int wv = blockIdx.x * 4 + (threadIdx.x >> 6);
    int nw = gridDim.x * 4;
    int c = l * 4;
    f32x4 sc4 = *(const f32x4*)&scale[c];
    f32x4 sh4 = *(const f32x4*)&shift[c];
    if (out_bf16) {
        ushort* ob = (ushort*)out;
        for (int r = wv; r < NN; r += nw) {
            ushort4 v = *(const ushort4*)&x[(long)r * 256 + c];
            float t0 = sc4[0] * bf2f(v.x) + sh4[0];
            float t1 = sc4[1] * bf2f(v.y) + sh4[1];
            float t2 = sc4[2] * bf2f(v.z) + sh4[2];
            float t3 = sc4[3] * bf2f(v.w) + sh4[3];
            t0 = (t0 > 0.f) ? t0 : (__expf(t0) - 1.f);
            t1 = (t1 > 0.f) ? t1 : (__expf(t1) - 1.f);
            t2 = (t2 > 0.f) ? t2 : (__expf(t2) - 1.f);
            t3 = (t3 > 0.f) ? t3 : (__expf(t3) - 1.f);
            ushort4 o;
            o.x = f2bf(t0); o.y = f2bf(t1); o.z = f2bf(t2); o.w = f2bf(t3);
            *(ushort4*)&ob[(long)r * 256 + c] = o;
        }
    } else {
        float* of = (float*)out;
        for (int r = wv; r < NN; r += nw) {
            ushort4 v = *(const ushort4*)&x[(long)r * 256 + c];
            float t0 = sc4[0] * bf2f(v.x) + sh4[0];
            float t1 = sc4[1] * bf2f(v.y) + sh4[1];
            float t2 = sc4[2] * bf2f(v.z) + sh4[2];
            float t3 = sc4[3] * bf2f(v.w) + sh4[3];
            f32x4 o;
            o[0] = (t0 > 0.f) ? t0 : (__expf(t0) - 1.f);
            o[1] = (t1 > 0.f) ? t1 : (__expf(t1) - 1.f);
            o[2] = (t2 > 0.f) ? t2 : (__expf(t2) - 1.f);
            o[3] = (t3 > 0.f) ? t3 : (__expf(t3) - 1.f);
            *(f32x4*)&of[(long)r * 256 + c] = o;
        }
    }
}

// ================= GAT =================
__global__ void gat_alpha(const ushort* __restrict__ h, const float* __restrict__ a_src,
                          const float* __restrict__ a_dst,
                          float* __restrict__ alpha_s, float* __restrict__ alpha_d) {
    int n = blockIdx.x;
    int t = threadIdx.x;
    float hv = bf2f(h[(long)n * 256 + t]);
    float vs = hv * a_src[t];
    float vd = hv * a_dst[t];
    for (int off = 32; off > 0; off >>= 1) {
        vs += __shfl_down(vs, off);
        vd += __shfl_down(vd, off);
    }
    if ((t & 63) == 0) {
        int head = t >> 6;
        alpha_s[n * 4 + head] = vs;
        alpha_d[n * 4 + head] = vd;
    }
}

// one wave per node; lane = edge_k*4 + head; 2 passes; stores UNNORMALIZED w
// plus per-(node,head) 1/sum into inv_ls (normalization applied in gather).
__global__ __launch_bounds__(256) void gat_att(
        const int* __restrict__ row_start, const int* __restrict__ sorted,
        const float* __restrict__ as, const float* __restrict__ ad,
        float* __restrict__ att, float* __restrict__ inv_ls) {
    int node = blockIdx.x * 4 + (threadIdx.x >> 6);
    if (node >= NN) return;
    int l = threadIdx.x & 63;
    int h = l & 3, k = l >> 2;
    int b = row_start[node], e = row_start[node + 1];
    float adn = ad[node * 4 + h];
    // pass 1: per-head max
    float lm = -1e30f;
    for (int i = b + k; i < e; i += 16) {
        int s = sorted[i];
        float ev = as[s * 4 + h] + adn;
        ev = (ev > 0.f) ? ev : NEG_SLOPE * ev;
        lm = fmaxf(lm, ev);
    }
    lm = fmaxf(lm, __shfl_xor(lm, 4));
    lm = fmaxf(lm, __shfl_xor(lm, 8));
    lm = fmaxf(lm, __shfl_xor(lm, 16));
    lm = fmaxf(lm, __shfl_xor(lm, 32));
    // pass 2: exp, store unnormalized, per-head sum
    float ls = 0.f;
    for (int i = b + k; i < e; i += 16) {
        int s = sorted[i];
        float ev = as[s * 4 + h] + adn;
        ev = (ev > 0.f) ? ev : NEG_SLOPE * ev;
        float wv = __expf(ev - lm);
        att[(long)i * 4 + h] = wv;
        ls += wv;
    }
    ls += __shfl_xor(ls, 4);
    ls += __shfl_xor(ls, 8);
    ls += __shfl_xor(ls, 16);
    ls += __shfl_xor(ls, 32);
    if (k == 0) inv_ls[node * 4 + h] = 1.0f / ls;
}

// one WAVE per node: lane l owns channels 4l..4l+3 (ushort4 = full 512B row
// per wave-instruction), 4-edge unroll, inv-sum applied at the end.
__global__ __launch_bounds__(256) void gat_gather(
        const int* __restrict__ row_start, const int* __restrict__ sorted,
        const float* __restrict__ att, const float* __restrict__ inv_ls,
        const ushort* __restrict__ h, ushort* __restrict__ out) {
    int node = blockIdx.x * 4 + (threadIdx.x >> 6);
    if (node >= NN) return;
    int l = threadIdx.x & 63;
    int head = l >> 4;                      // channels 4l..4l+3 share one head
    int b = row_start[node], e = row_start[node + 1];
    float a0 = 0.f, a1 = 0.f, a2 = 0.f, a3 = 0.f;
    int i = b;
    for (; i + 3 < e; i += 4) {
        int s0 = sorted[i], s1 = sorted[i + 1], s2 = sorted[i + 2], s3 = sorted[i + 3];
        float w0 = att[(long)i * 4 + head];
        float w1 = att[(long)(i + 1) * 4 + head];
        float w2 = att[(long)(i + 2) * 4 + head];
        float w3 = att[(long)(i + 3) * 4 + head];
        ushort4 v0 = *(const ushort4*)&h[(long)s0 * 256 + l * 4];
        ushort4 v1 = *(const ushort4*)&h[(long)s1 * 256 + l * 4];
        ushort4 v2 = *(const ushort4*)&h[(long)s2 * 256 + l * 4];
        ushort4 v3 = *(const ushort4*)&h[(long)s3 * 256 + l * 4];
        a0 += w0 * bf2f(v0.x) + w1 * bf2f(v1.x) + w2 * bf2f(v2.x) + w3 * bf2f(v3.x);
        a1 += w0 * bf2f(v0.y) + w1 * bf2f(v1.y) + w2 * bf2f(v2.y) + w3 * bf2f(v3.y);
        a2 += w0 * bf2f(v0.z) + w1 * bf2f(v1.z) + w2 * bf2f(v2.z) + w3 * bf2f(v3.z);
        a3 += w0 * bf2f(v0.w) + w1 * bf2f(v1.w) + w2 * bf2f(v2.w) + w3 * bf2f(v3.w);
    }
    for (; i < e; ++i) {
        int s0 = sorted[i];
        float w0 = att[(long)i * 4 + head];
        ushort4 v0 = *(const ushort4*)&h[(long)s0 * 256 + l * 4];
        a0 += w0 * bf2f(v0.x);
        a1 += w0 * bf2f(v0.y);
        a2 += w0 * bf2f(v0.z);
        a3 += w0 * bf2f(v0.w);
    }
    float inv = inv_ls[node * 4 + head];
    ushort4 o;
    o.x = f2bf(a0 * inv);
    o.y = f2bf(a1 * inv);
    o.z = f2bf(a2 * inv);
    o.w = f2bf(a3 * inv);
    *(ushort4*)&out[(long)node * 256 + l * 4] = o;
}

// ================= launch =================
extern "C" void kernel_launch(void* const* d_in, const int* in_sizes, int n_in,
                              void* d_out, int out_size, void* d_ws, size_t ws_size,
                              hipStream_t stream) {
    const float* x      = (const float*)d_in[0];
    const int*   ei     = (const int*)d_in[1];
    const float* W_gcn  = (const float*)d_in[2];
    const float* b_gcn  = (const float*)d_in[3];
    const float* g0     = (const float*)d_in[4];
    const float* beta0  = (const float*)d_in[5];
    const float* W1     = (const float*)d_in[6];
    const float* a_src1 = (const float*)d_in[7];
    const float* a_dst1 = (const float*)d_in[8];
    const float* b1     = (const float*)d_in[9];
    const float* g1     = (const float*)d_in[10];
    const float* beta1  = (const float*)d_in[11];
    const float* W2     = (const float*)d_in[12];
    const float* a_src2 = (const float*)d_in[13];
    const float* a_dst2 = (const float*)d_in[14];
    const float* b2     = (const float*)d_in[15];
    const float* g2     = (const float*)d_in[16];
    const float* beta2  = (const float*)d_in[17];

    const long N = NN;
    float* ws = (float*)d_ws;

    // ---- layout (~544N floats; ws proven >= 641N floats) ----
    float* dinv    = ws;                        // N
    float* alpha_s = ws + N;                    // 4N
    float* alpha_d = ws + 5 * N;                // 4N
    float* sums    = ws + 9 * N;                // 256
    float* sumsq   = sums + 256;
    float* scale   = sumsq + 256;
    float* shift   = scale + 256;
    int*   row_start = (int*)(shift + 256);     // N+1
    int*   fill      = row_start + NN + 1;      // N
    int*   deg_i     = fill + NN;               // N
    int*   sorted    = deg_i + NN;              // 9N
    int*   bsum      = sorted + EE + NN;        // ~400
    ushort* Wgt  = (ushort*)(ws + 23 * N);      // 64x256
    ushort* W1t  = Wgt + 16384;                 // 256x64
    ushort* W2t  = W1t + 16384;                 // 256x256
    ushort* h0b  = (ushort*)(ws + 24 * N);      // [N,64] bf16 (32N fl); reused as x1b
    ushort* x1b  = h0b;
    float*  agg0 = ws + 56 * N;                 // [N,64] fp32 (64N fl)
    ushort* h1b  = (ushort*)(ws + 120 * N);     // [N,256] bf16 (128N fl); also h2
    ushort* x2b  = (ushort*)(ws + 248 * N);     // [N,256] bf16 (128N fl)
    ushort* xb   = x2b;                         // alias: x bf16, dead before x2b live
    ushort* yb   = (ushort*)(ws + 376 * N);     // [N,256] bf16 gather out (128N fl)
    float*  attb = ws + 504 * N;                // (E+N)*4 floats (36N fl) -> ends 540N
    float*  inv_ls = ws + 540 * N;              // 4N floats -> ends 544N
    float*  outp = (float*)d_out;

    const int BLK = 256;
    dim3 blk(BLK);
    const int NBLK_N = (NN + 255) / 256;        // 391

    // ===== CSR build =====
    hipMemsetAsync(fill, 0, 2L * NN * sizeof(int), stream);
    hist_kernel<<<(EE + 255) / 256, blk, 0, stream>>>(ei, deg_i);
    dinv_kernel<<<NBLK_N, blk, 0, stream>>>(deg_i, dinv);
    scan_k1<<<NBLK_N, blk, 0, stream>>>(deg_i, row_start, bsum);
    scan_k2<<<1, 512, 0, stream>>>(bsum, NBLK_N);
    scan_k3<<<(NN + 1 + 255) / 256, blk, 0, stream>>>(row_start, bsum);
    scatter_kernel<<<(EE + NN + 255) / 256, blk, 0, stream>>>(ei, row_start, fill, sorted);

    // ===== conversions =====
    convert_f32_bf16<<<(int)((N * 256 / 4 + 255) / 256), blk, 0, stream>>>(x, xb, N * 256 / 4);
    transpose_w<<<(FIN * CH + 255) / 256, blk, 0, stream>>>(W_gcn, Wgt, FIN, CH);
    transpose_w<<<(CH * C1 + 255) / 256, blk, 0, stream>>>(W1, W1t, CH, C1);
    transpose_w<<<(C1 * C1 + 255) / 256, blk, 0, stream>>>(W2, W2t, C1, C1);

    // ===== GCN =====
    gemm_mfma<<<dim3(CH / 64, (NN + 63) / 64), blk, 0, stream>>>(xb, Wgt, h0b, FIN, CH);
    gcn_gather<<<(NN + 3) / 4, blk, 0, stream>>>(row_start, sorted, dinv, h0b, agg0);
    hipMemsetAsync(sums, 0, 512 * sizeof(float), stream);
    bn_stats64<<<512, blk, 0, stream>>>(agg0, b_gcn, sums, sumsq);
    bn_finalize<<<1, CH, 0, stream>>>(sums, sumsq, g0, beta0, scale, shift, CH);
    bn_apply_gcn<<<1024, blk, 0, stream>>>(agg0, b_gcn, scale, shift, x1b);

    // ===== GAT layer 1 =====
    gemm_mfma<<<dim3(C1 / 64, (NN + 63) / 64), blk, 0, stream>>>(x1b, W1t, h1b, CH, C1);
    gat_alpha<<<NN, blk, 0, stream>>>(h1b, a_src1, a_dst1, alpha_s, alpha_d);
    gat_att<<<(NN + 3) / 4, blk, 0, stream>>>(row_start, sorted, alpha_s, alpha_d, attb, inv_ls);
    gat_gather<<<(NN + 3) / 4, blk, 0, stream>>>(row_start, sorted, attb, inv_ls, h1b, yb);
    hipMemsetAsync(sums, 0, 512 * sizeof(float), stream);
    bn_stats256<<<512, blk, 0, stream>>>(yb, sums, sumsq);
    bn_finalize<<<1, C1, 0, stream>>>(sums, sumsq, g1, beta1, scale, shift, C1);
    bn_apply_gat<<<2048, blk, 0, stream>>>(yb, scale, shift, x2b, 1);

    // ===== GAT layer 2 =====
    gemm_mfma<<<dim3(C1 / 64, (NN + 63) / 64), blk, 0, stream>>>(x2b, W2t, h1b, C1, C1);
    gat_alpha<<<NN, blk, 0, stream>>>(h1b, a_src2, a_dst2, alpha_s, alpha_d);
    gat_att<<<(NN + 3) / 4, blk, 0, stream>>>(row_start, sorted, alpha_s, alpha_d, attb, inv_ls);
    gat_gather<<<(NN + 3) / 4, blk, 0, stream>>>(row_start, sorted, attb, inv_ls, h1b, yb);
    hipMemsetAsync(sums, 0, 512 * sizeof(float), stream);
    bn_stats256<<<512, blk, 0, stream>>>(yb, sums, sumsq);
    bn_finalize<<<1, C1, 0, stream>>>(sums, sumsq, g2, beta2, scale, shift, C1);
    bn_apply_gat<<<2048, blk, 0, stream>>>(yb, scale, shift, outp, 0);
}

// Round 5
// 929.702 us; speedup vs baseline: 1.2805x; 1.0049x over previous
//
#include <hip/hip_runtime.h>
#include <hip/hip_bf16.h>
#include <math.h>

#define NN 100000
#define EE 800000
#define FIN 256
#define CH 64      // HID
#define C1 256     // H*HID
#define BN_EPS 1e-5f
#define NEG_SLOPE 0.2f

typedef __attribute__((ext_vector_type(8))) short short8;
typedef __attribute__((ext_vector_type(8))) unsigned short u16x8;
typedef __attribute__((ext_vector_type(4))) float f32x4;

__device__ __forceinline__ float bf2f(ushort u) {
    return __uint_as_float(((unsigned)u) << 16);
}
__device__ __forceinline__ ushort f2bf(float f) {
    unsigned u = __float_as_uint(f);
    return (ushort)((u + 0x7FFF + ((u >> 16) & 1)) >> 16);   // RNE
}

// ================= CSR build =================
__global__ void hist_kernel(const int* __restrict__ ei, int* __restrict__ deg) {
    int t = blockIdx.x * 256 + threadIdx.x;
    if (t < EE) atomicAdd(&deg[ei[EE + t]], 1);
}
__global__ void dinv_kernel(const int* __restrict__ deg, float* __restrict__ dinv) {
    int i = blockIdx.x * 256 + threadIdx.x;
    if (i < NN) dinv[i] = rsqrtf((float)(deg[i] + 1));  // +1 self loop
}
__global__ void scan_k1(const int* __restrict__ deg, int* __restrict__ row_start,
                        int* __restrict__ bsum) {
    __shared__ int sh[256];
    int t = threadIdx.x;
    int i = blockIdx.x * 256 + t;
    int v = (i < NN) ? (deg[i] + 1) : 0;
    sh[t] = v;
    __syncthreads();
    for (int off = 1; off < 256; off <<= 1) {
        int add = (t >= off) ? sh[t - off] : 0;
        __syncthreads();
        sh[t] += add;
        __syncthreads();
    }
    if (i < NN) row_start[i] = sh[t] - v;
    if (t == 255) bsum[blockIdx.x] = sh[255];
}
__global__ void scan_k2(int* __restrict__ bsum, int nb) {
    __shared__ int sh[512];
    int t = threadIdx.x;
    int v = (t < nb) ? bsum[t] : 0;
    sh[t] = v;
    __syncthreads();
    for (int off = 1; off < 512; off <<= 1) {
        int add = (t >= off) ? sh[t - off] : 0;
        __syncthreads();
        sh[t] += add;
        __syncthreads();
    }
    if (t < nb) bsum[t] = sh[t] - v;
}
__global__ void scan_k3(int* __restrict__ row_start, const int* __restrict__ bsum) {
    int i = blockIdx.x * 256 + threadIdx.x;
    if (i < NN) row_start[i] += bsum[i >> 8];
    if (i == NN) row_start[NN] = EE + NN;
}
__global__ void scatter_kernel(const int* __restrict__ ei, const int* __restrict__ row_start,
                               int* __restrict__ fill, int* __restrict__ sorted) {
    int t = blockIdx.x * 256 + threadIdx.x;
    if (t >= EE + NN) return;
    int s, d;
    if (t < EE) { s = ei[t]; d = ei[EE + t]; }
    else        { s = t - EE; d = s; }
    int pos = atomicAdd(&fill[d], 1);
    sorted[row_start[d] + pos] = s;
}

// ================= conversions =================
__global__ void convert_f32_bf16(const float* __restrict__ in, ushort* __restrict__ out, long n4) {
    long i = (long)blockIdx.x * 256 + threadIdx.x;
    if (i < n4) {
        float4 v = *(const float4*)&in[i * 4];
        ushort4 o;
        o.x = f2bf(v.x); o.y = f2bf(v.y); o.z = f2bf(v.z); o.w = f2bf(v.w);
        *(ushort4*)&out[i * 4] = o;
    }
}
__global__ void transpose_w(const float* __restrict__ W, ushort* __restrict__ Bt, int M, int K) {
    int idx = blockIdx.x * 256 + threadIdx.x;
    if (idx < M * K) {
        int m = idx / K, n = idx % K;
        Bt[n * M + m] = f2bf(W[idx]);
    }
}

// ================= bf16 MFMA GEMM =================
// C[N x K] = A[N x M] @ B[M x K]; A bf16 row-major, Bt bf16 [K][M], C bf16.
__global__ __launch_bounds__(256) void gemm_mfma(
        const ushort* __restrict__ A, const ushort* __restrict__ Bt,
        ushort* __restrict__ C, int M, int K) {
    __shared__ ushort As[64][40];
    __shared__ ushort Bs[64][40];
    int t = threadIdx.x;
    int w = t >> 6;
    int l = t & 63;
    int rowBase = blockIdx.y * 64;
    int colBase = blockIdx.x * 64;
    int srow = t >> 2;
    int sk = (t & 3) * 8;
    int m = l & 15, q = l >> 4;
    f32x4 acc[4] = {};
    for (int k0 = 0; k0 < M; k0 += 32) {
        uint4 av = make_uint4(0u, 0u, 0u, 0u);
        int gr = rowBase + srow;
        if (gr < NN) av = *(const uint4*)&A[(long)gr * M + k0 + sk];
        uint4 bv = *(const uint4*)&Bt[(long)(colBase + srow) * M + k0 + sk];
        *(uint4*)&As[srow][sk] = av;
        *(uint4*)&Bs[srow][sk] = bv;
        __syncthreads();
        short8 af = *(const short8*)&As[w * 16 + m][q * 8];
#pragma unroll
        for (int c = 0; c < 4; ++c) {
            short8 bf = *(const short8*)&Bs[c * 16 + m][q * 8];
            acc[c] = __builtin_amdgcn_mfma_f32_16x16x32_bf16(af, bf, acc[c], 0, 0, 0);
        }
        __syncthreads();
    }
#pragma unroll
    for (int c = 0; c < 4; ++c) {
#pragma unroll
        for (int r = 0; r < 4; ++r) {
            int orow = rowBase + w * 16 + q * 4 + r;
            if (orow < NN) C[(long)orow * K + colBase + c * 16 + m] = f2bf(acc[c][r]);
        }
    }
}

// ================= GCN gather =================
// one wave per node; 8 edge-slots x 8 lanes x ushort8 (16B) = 8 rows (1KB)
// per wave-instruction; shfl-xor reduce over slots; f32x4 stores.
__global__ __launch_bounds__(256) void gcn_gather(
        const int* __restrict__ row_start, const int* __restrict__ sorted,
        const float* __restrict__ dinv, const ushort* __restrict__ h0,
        float* __restrict__ agg) {
    int node = blockIdx.x * 4 + (threadIdx.x >> 6);
    if (node >= NN) return;
    int l = threadIdx.x & 63;
    int slot = l >> 3;          // edge slot 0..7
    int li = l & 7;             // lane within row
    int c = li * 8;             // 8 channels of 64
    int b = row_start[node], e = row_start[node + 1];
    float a[8] = {};
    for (int i = b + slot; i < e; i += 8) {
        int s = sorted[i];
        float dv = dinv[s];
        u16x8 v = *(const u16x8*)&h0[(long)s * 64 + c];
#pragma unroll
        for (int j = 0; j < 8; ++j) a[j] += dv * bf2f((ushort)v[j]);
    }
#pragma unroll
    for (int j = 0; j < 8; ++j) {
        a[j] += __shfl_xor(a[j], 8);
        a[j] += __shfl_xor(a[j], 16);
        a[j] += __shfl_xor(a[j], 32);
    }
    if (slot == 0) {
        float dn = dinv[node];
        f32x4 o0, o1;
#pragma unroll
        for (int j = 0; j < 4; ++j) { o0[j] = a[j] * dn; o1[j] = a[4 + j] * dn; }
        *(f32x4*)&agg[(long)node * 64 + c] = o0;
        *(f32x4*)&agg[(long)node * 64 + c + 4] = o1;
    }
}

// ================= BatchNorm =================
// C=64, fp32 input, relu(x+bias) pre-BN. Persistent: 512 blocks.
// Wave layout: sub = l>>4 owns row slot, c=(l&15)*4 channels, f32x4 loads.
__global__ __launch_bounds__(256) void bn_stats64(
        const float* __restrict__ x, const float* __restrict__ bias,
        float* __restrict__ sums, float* __restrict__ sumsq) {
    __shared__ float red[4][16][8];
    int l = threadIdx.x & 63;
    int w = threadIdx.x >> 6;
    int wv = blockIdx.x * 4 + w;
    int nw = gridDim.x * 4;
    int sub = l >> 4;
    int c = (l & 15) * 4;
    f32x4 b4 = *(const f32x4*)&bias[c];
    float s0 = 0.f, s1 = 0.f, s2 = 0.f, s3 = 0.f;
    float q0 = 0.f, q1 = 0.f, q2 = 0.f, q3 = 0.f;
    for (int r = wv * 4 + sub; r < NN; r += nw * 4) {
        f32x4 v = *(const f32x4*)&x[(long)r * 64 + c];
        float v0 = fmaxf(v[0] + b4[0], 0.f);
        float v1 = fmaxf(v[1] + b4[1], 0.f);
        float v2 = fmaxf(v[2] + b4[2], 0.f);
        float v3 = fmaxf(v[3] + b4[3], 0.f);
        s0 += v0; s1 += v1; s2 += v2; s3 += v3;
        q0 += v0 * v0; q1 += v1 * v1; q2 += v2 * v2; q3 += v3 * v3;
    }
    // reduce across the 4 row-slots (lanes differing in bits 4,5)
    s0 += __shfl_xor(s0, 16); s1 += __shfl_xor(s1, 16);
    s2 += __shfl_xor(s2, 16); s3 += __shfl_xor(s3, 16);
    q0 += __shfl_xor(q0, 16); q1 += __shfl_xor(q1, 16);
    q2 += __shfl_xor(q2, 16); q3 += __shfl_xor(q3, 16);
    s0 += __shfl_xor(s0, 32); s1 += __shfl_xor(s1, 32);
    s2 += __shfl_xor(s2, 32); s3 += __shfl_xor(s3, 32);
    q0 += __shfl_xor(q0, 32); q1 += __shfl_xor(q1, 32);
    q2 += __shfl_xor(q2, 32); q3 += __shfl_xor(q3, 32);
    if (sub == 0) {
        int li = l & 15;
        red[w][li][0] = s0; red[w][li][1] = s1; red[w][li][2] = s2; red[w][li][3] = s3;
        red[w][li][4] = q0; red[w][li][5] = q1; red[w][li][6] = q2; red[w][li][7] = q3;
    }
    __syncthreads();
    if (w == 0 && sub == 0) {
        int li = l & 15;
        atomicAdd(&sums[c + 0], red[0][li][0] + red[1][li][0] + red[2][li][0] + red[3][li][0]);
        atomicAdd(&sums[c + 1], red[0][li][1] + red[1][li][1] + red[2][li][1] + red[3][li][1]);
        atomicAdd(&sums[c + 2], red[0][li][2] + red[1][li][2] + red[2][li][2] + red[3][li][2]);
        atomicAdd(&sums[c + 3], red[0][li][3] + red[1][li][3] + red[2][li][3] + red[3][li][3]);
        atomicAdd(&sumsq[c + 0], red[0][li][4] + red[1][li][4] + red[2][li][4] + red[3][li][4]);
        atomicAdd(&sumsq[c + 1], red[0][li][5] + red[1][li][5] + red[2][li][5] + red[3][li][5]);
        atomicAdd(&sumsq[c + 2], red[0][li][6] + red[1][li][6] + red[2][li][6] + red[3][li][6]);
        atomicAdd(&sumsq[c + 3], red[0][li][7] + red[1][li][7] + red[2][li][7] + red[3][li][7]);
    }
}
// C=256, bf16 input, NO bias (shift-invariance: var(y+b)=var(y), and the
// bias cancels exactly in the normalized output). Persistent: 512 blocks.
// One wave covers a full row: lane l owns channels 4l..4l+3 (ushort4).
__global__ __launch_bounds__(256) void bn_stats256(
        const ushort* __restrict__ x,
        float* __restrict__ sums, float* __restrict__ sumsq) {
    __shared__ float red[4][64][8];
    int l = threadIdx.x & 63;
    int w = threadIdx.x >> 6;
    int wv = blockIdx.x * 4 + w;
    int nw = gridDim.x * 4;
    int c = l * 4;
    float s0 = 0.f, s1 = 0.f, s2 = 0.f, s3 = 0.f;
    float q0 = 0.f, q1 = 0.f, q2 = 0.f, q3 = 0.f;
    for (int r = wv; r < NN; r += nw) {
        ushort4 v = *(const ushort4*)&x[(long)r * 256 + c];
        float v0 = bf2f(v.x), v1 = bf2f(v.y), v2 = bf2f(v.z), v3 = bf2f(v.w);
        s0 += v0; s1 += v1; s2 += v2; s3 += v3;
        q0 += v0 * v0; q1 += v1 * v1; q2 += v2 * v2; q3 += v3 * v3;
    }
    red[w][l][0] = s0; red[w][l][1] = s1; red[w][l][2] = s2; red[w][l][3] = s3;
    red[w][l][4] = q0; red[w][l][5] = q1; red[w][l][6] = q2; red[w][l][7] = q3;
    __syncthreads();
    if (w == 0) {
        atomicAdd(&sums[c + 0], red[0][l][0] + red[1][l][0] + red[2][l][0] + red[3][l][0]);
        atomicAdd(&sums[c + 1], red[0][l][1] + red[1][l][1] + red[2][l][1] + red[3][l][1]);
        atomicAdd(&sums[c + 2], red[0][l][2] + red[1][l][2] + red[2][l][2] + red[3][l][2]);
        atomicAdd(&sums[c + 3], red[0][l][3] + red[1][l][3] + red[2][l][3] + red[3][l][3]);
        atomicAdd(&sumsq[c + 0], red[0][l][4] + red[1][l][4] + red[2][l][4] + red[3][l][4]);
        atomicAdd(&sumsq[c + 1], red[0][l][5] + red[1][l][5] + red[2][l][5] + red[3][l][5]);
        atomicAdd(&sumsq[c + 2], red[0][l][6] + red[1][l][6] + red[2][l][6] + red[3][l][6]);
        atomicAdd(&sumsq[c + 3], red[0][l][7] + red[1][l][7] + red[2][l][7] + red[3][l][7]);
    }
}
__global__ void bn_finalize(const float* __restrict__ sums, const float* __restrict__ sumsq,
                            const float* __restrict__ g, const float* __restrict__ beta,
                            float* __restrict__ scale, float* __restrict__ shift, int C) {
    int c = threadIdx.x;
    if (c < C) {
        float mean = sums[c] / (float)NN;
        float var = sumsq[c] / (float)NN - mean * mean;
        float sc = g[c] * rsqrtf(var + BN_EPS);
        scale[c] = sc;
        shift[c] = beta[c] - mean * sc;
    }
}
// GCN BN apply: fp32 in, relu pre-BN, bf16 out.
// 4 rows per wave (16 lanes/row, 4 ch/lane); tables hoisted out of row loop.
__global__ __launch_bounds__(256) void bn_apply_gcn(
        const float* __restrict__ x, const float* __restrict__ bias,
        const float* __restrict__ scale, const float* __restrict__ shift,
        ushort* __restrict__ out) {
    int l = threadIdx.x & 63;
    int wv = blockIdx.x * 4 + (threadIdx.x >> 6);
    int nw = gridDim.x * 4;
    int c = (l & 15) * 4;
    int sub = l >> 4;
    f32x4 b4  = *(const f32x4*)&bias[c];
    f32x4 sc4 = *(const f32x4*)&scale[c];
    f32x4 sh4 = *(const f32x4*)&shift[c];
    for (int r = wv * 4 + sub; r < NN; r += nw * 4) {
        f32x4 v = *(const f32x4*)&x[(long)r * 64 + c];
        ushort4 o;
        o.x = f2bf(sc4[0] * fmaxf(v[0] + b4[0], 0.f) + sh4[0]);
        o.y = f2bf(sc4[1] * fmaxf(v[1] + b4[1], 0.f) + sh4[1]);
        o.z = f2bf(sc4[2] * fmaxf(v[2] + b4[2], 0.f) + sh4[2]);
        o.w = f2bf(sc4[3] * fmaxf(v[3] + b4[3], 0.f) + sh4[3]);
        *(ushort4*)&out[(long)r * 64 + c] = o;
    }
}
// GAT BN apply: bf16 in, ELU post-BN, bf16 or fp32 out. NO bias (cancels:
// shift computed from raw-y mean gives identical normalized output).
// One wave per row; lane l owns channels 4l..4l+3; tables hoisted.
__global__ __launch_bounds__(256) void bn_apply_gat(
        const ushort* __restrict__ x,
        const float* __restrict__ scale, const float* __restrict__ shift,
        void* __restrict__ out, int out_bf16) {
    int l = threadIdx.x & 63;
    int wv = blockIdx.x * 4 + (threadIdx.x >> 6);
    int nw = gridDim.x * 4;
    int c = l * 4;
    f32x4 sc4 = *(const f32x4*)&scale[c];
    f32x4 sh4 = *(const f32x4*)&shift[c];
    if (out_bf16) {
        ushort* ob = (ushort*)out;
        for (int r = wv; r < NN; r += nw) {
            ushort4 v = *(const ushort4*)&x[(long)r * 256 + c];
            float t0 = sc4[0] * bf2f(v.x) + sh4[0];
            float t1 = sc4[1] * bf2f(v.y) + sh4[1];
            float t2 = sc4[2] * bf2f(v.z) + sh4[2];
            float t3 = sc4[3] * bf2f(v.w) + sh4[3];
            t0 = (t0 > 0.f) ? t0 : (__expf(t0) - 1.f);
            t1 = (t1 > 0.f) ? t1 : (__expf(t1) - 1.f);
            t2 = (t2 > 0.f) ? t2 : (__expf(t2) - 1.f);
            t3 = (t3 > 0.f) ? t3 : (__expf(t3) - 1.f);
            ushort4 o;
            o.x = f2bf(t0); o.y = f2bf(t1); o.z = f2bf(t2); o.w = f2bf(t3);
            *(ushort4*)&ob[(long)r * 256 + c] = o;
        }
    } else {
        float* of = (float*)out;
        for (int r = wv; r < NN; r += nw) {
            ushort4 v = *(const ushort4*)&x[(long)r * 256 + c];
            float t0 = sc4[0] * bf2f(v.x) + sh4[0];
            float t1 = sc4[1] * bf2f(v.y) + sh4[1];
            float t2 = sc4[2] * bf2f(v.z) + sh4[2];
            float t3 = sc4[3] * bf2f(v.w) + sh4[3];
            f32x4 o;
            o[0] = (t0 > 0.f) ? t0 : (__expf(t0) - 1.f);
            o[1] = (t1 > 0.f) ? t1 : (__expf(t1) - 1.f);
            o[2] = (t2 > 0.f) ? t2 : (__expf(t2) - 1.f);
            o[3] = (t3 > 0.f) ? t3 : (__expf(t3) - 1.f);
            *(f32x4*)&of[(long)r * 256 + c] = o;
        }
    }
}

// ================= GAT =================
__global__ void gat_alpha(const ushort* __restrict__ h, const float* __restrict__ a_src,
                          const float* __restrict__ a_dst,
                          float* __restrict__ alpha_s, float* __restrict__ alpha_d) {
    int n = blockIdx.x;
    int t = threadIdx.x;
    float hv = bf2f(h[(long)n * 256 + t]);
    float vs = hv * a_src[t];
    float vd = hv * a_dst[t];
    for (int off = 32; off > 0; off >>= 1) {
        vs += __shfl_down(vs, off);
        vd += __shfl_down(vd, off);
    }
    if ((t & 63) == 0) {
        int head = t >> 6;
        alpha_s[n * 4 + head] = vs;
        alpha_d[n * 4 + head] = vd;
    }
}

// one wave per node; lane = edge_k*4 + head; 2 passes; stores UNNORMALIZED w
// plus per-(node,head) 1/sum into inv_ls (normalization applied in gather).
__global__ __launch_bounds__(256) void gat_att(
        const int* __restrict__ row_start, const int* __restrict__ sorted,
        const float* __restrict__ as, const float* __restrict__ ad,
        float* __restrict__ att, float* __restrict__ inv_ls) {
    int node = blockIdx.x * 4 + (threadIdx.x >> 6);
    if (node >= NN) return;
    int l = threadIdx.x & 63;
    int h = l & 3, k = l >> 2;
    int b = row_start[node], e = row_start[node + 1];
    float adn = ad[node * 4 + h];
    // pass 1: per-head max
    float lm = -1e30f;
    for (int i = b + k; i < e; i += 16) {
        int s = sorted[i];
        float ev = as[s * 4 + h] + adn;
        ev = (ev > 0.f) ? ev : NEG_SLOPE * ev;
        lm = fmaxf(lm, ev);
    }
    lm = fmaxf(lm, __shfl_xor(lm, 4));
    lm = fmaxf(lm, __shfl_xor(lm, 8));
    lm = fmaxf(lm, __shfl_xor(lm, 16));
    lm = fmaxf(lm, __shfl_xor(lm, 32));
    // pass 2: exp, store unnormalized, per-head sum
    float ls = 0.f;
    for (int i = b + k; i < e; i += 16) {
        int s = sorted[i];
        float ev = as[s * 4 + h] + adn;
        ev = (ev > 0.f) ? ev : NEG_SLOPE * ev;
        float wv = __expf(ev - lm);
        att[(long)i * 4 + h] = wv;
        ls += wv;
    }
    ls += __shfl_xor(ls, 4);
    ls += __shfl_xor(ls, 8);
    ls += __shfl_xor(ls, 16);
    ls += __shfl_xor(ls, 32);
    if (k == 0) inv_ls[node * 4 + h] = 1.0f / ls;
}

// one WAVE per node; 2 edge-slots (lanes 0-31 / 32-63), lane li owns
// channels 8li..8li+7 via ushort8 (16B) -> one wave-inst moves 1KB (2 rows).
// 2-deep unroll = 4 edges in flight; slot-combine via shfl_xor(32).
__global__ __launch_bounds__(256) void gat_gather(
        const int* __restrict__ row_start, const int* __restrict__ sorted,
        const float* __restrict__ att, const float* __restrict__ inv_ls,
        const ushort* __restrict__ h, ushort* __restrict__ out) {
    int node = blockIdx.x * 4 + (threadIdx.x >> 6);
    if (node >= NN) return;
    int l = threadIdx.x & 63;
    int slot = l >> 5;                 // edge slot 0/1
    int li = l & 31;                   // lane within row
    int c = li * 8;                    // 8 channels of 256
    int head = li >> 3;                // channels 8li..8li+7 share one head
    int b = row_start[node], e = row_start[node + 1];
    float a[8] = {};
    int i = b + slot;
    for (; i + 2 < e; i += 4) {        // this slot handles edges i and i+2
        int s0 = sorted[i], s1 = sorted[i + 2];
        float w0 = att[(long)i * 4 + head];
        float w1 = att[(long)(i + 2) * 4 + head];
        u16x8 v0 = *(const u16x8*)&h[(long)s0 * 256 + c];
        u16x8 v1 = *(const u16x8*)&h[(long)s1 * 256 + c];
#pragma unroll
        for (int j = 0; j < 8; ++j)
            a[j] += w0 * bf2f((ushort)v0[j]) + w1 * bf2f((ushort)v1[j]);
    }
    for (; i < e; i += 2) {
        int s0 = sorted[i];
        float w0 = att[(long)i * 4 + head];
        u16x8 v0 = *(const u16x8*)&h[(long)s0 * 256 + c];
#pragma unroll
        for (int j = 0; j < 8; ++j) a[j] += w0 * bf2f((ushort)v0[j]);
    }
#pragma unroll
    for (int j = 0; j < 8; ++j) a[j] += __shfl_xor(a[j], 32);
    if (slot == 0) {
        float inv = inv_ls[node * 4 + head];
        u16x8 o;
#pragma unroll
        for (int j = 0; j < 8; ++j) o[j] = f2bf(a[j] * inv);
        *(u16x8*)&out[(long)node * 256 + c] = o;
    }
}

// ================= launch =================
extern "C" void kernel_launch(void* const* d_in, const int* in_sizes, int n_in,
                              void* d_out, int out_size, void* d_ws, size_t ws_size,
                              hipStream_t stream) {
    const float* x      = (const float*)d_in[0];
    const int*   ei     = (const int*)d_in[1];
    const float* W_gcn  = (const float*)d_in[2];
    const float* b_gcn  = (const float*)d_in[3];
    const float* g0     = (const float*)d_in[4];
    const float* beta0  = (const float*)d_in[5];
    const float* W1     = (const float*)d_in[6];
    const float* a_src1 = (const float*)d_in[7];
    const float* a_dst1 = (const float*)d_in[8];
    const float* b1     = (const float*)d_in[9];
    const float* g1     = (const float*)d_in[10];
    const float* beta1  = (const float*)d_in[11];
    const float* W2     = (const float*)d_in[12];
    const float* a_src2 = (const float*)d_in[13];
    const float* a_dst2 = (const float*)d_in[14];
    const float* b2     = (const float*)d_in[15];
    const float* g2     = (const float*)d_in[16];
    const float* beta2  = (const float*)d_in[17];

    const long N = NN;
    float* ws = (float*)d_ws;

    // ---- layout (~544N floats; ws proven >= 641N floats) ----
    float* dinv    = ws;                        // N
    float* alpha_s = ws + N;                    // 4N
    float* alpha_d = ws + 5 * N;                // 4N
    float* sums    = ws + 9 * N;                // 256
    float* sumsq   = sums + 256;
    float* scale   = sumsq + 256;
    float* shift   = scale + 256;
    int*   row_start = (int*)(shift + 256);     // N+1
    int*   fill      = row_start + NN + 1;      // N
    int*   deg_i     = fill + NN;               // N
    int*   sorted    = deg_i + NN;              // 9N
    int*   bsum      = sorted + EE + NN;        // ~400
    ushort* Wgt  = (ushort*)(ws + 23 * N);      // 64x256
    ushort* W1t  = Wgt + 16384;                 // 256x64
    ushort* W2t  = W1t + 16384;                 // 256x256
    ushort* h0b  = (ushort*)(ws + 24 * N);      // [N,64] bf16 (32N fl); reused as x1b
    ushort* x1b  = h0b;
    float*  agg0 = ws + 56 * N;                 // [N,64] fp32 (64N fl)
    ushort* h1b  = (ushort*)(ws + 120 * N);     // [N,256] bf16 (128N fl); also h2
    ushort* x2b  = (ushort*)(ws + 248 * N);     // [N,256] bf16 (128N fl)
    ushort* xb   = x2b;                         // alias: x bf16, dead before x2b live
    ushort* yb   = (ushort*)(ws + 376 * N);     // [N,256] bf16 gather out (128N fl)
    float*  attb = ws + 504 * N;                // (E+N)*4 floats (36N fl) -> ends 540N
    float*  inv_ls = ws + 540 * N;              // 4N floats -> ends 544N
    float*  outp = (float*)d_out;

    const int BLK = 256;
    dim3 blk(BLK);
    const int NBLK_N = (NN + 255) / 256;        // 391

    // ===== CSR build =====
    hipMemsetAsync(fill, 0, 2L * NN * sizeof(int), stream);
    hist_kernel<<<(EE + 255) / 256, blk, 0, stream>>>(ei, deg_i);
    dinv_kernel<<<NBLK_N, blk, 0, stream>>>(deg_i, dinv);
    scan_k1<<<NBLK_N, blk, 0, stream>>>(deg_i, row_start, bsum);
    scan_k2<<<1, 512, 0, stream>>>(bsum, NBLK_N);
    scan_k3<<<(NN + 1 + 255) / 256, blk, 0, stream>>>(row_start, bsum);
    scatter_kernel<<<(EE + NN + 255) / 256, blk, 0, stream>>>(ei, row_start, fill, sorted);

    // ===== conversions =====
    convert_f32_bf16<<<(int)((N * 256 / 4 + 255) / 256), blk, 0, stream>>>(x, xb, N * 256 / 4);
    transpose_w<<<(FIN * CH + 255) / 256, blk, 0, stream>>>(W_gcn, Wgt, FIN, CH);
    transpose_w<<<(CH * C1 + 255) / 256, blk, 0, stream>>>(W1, W1t, CH, C1);
    transpose_w<<<(C1 * C1 + 255) / 256, blk, 0, stream>>>(W2, W2t, C1, C1);

    // ===== GCN =====
    gemm_mfma<<<dim3(CH / 64, (NN + 63) / 64), blk, 0, stream>>>(xb, Wgt, h0b, FIN, CH);
    gcn_gather<<<(NN + 3) / 4, blk, 0, stream>>>(row_start, sorted, dinv, h0b, agg0);
    hipMemsetAsync(sums, 0, 512 * sizeof(float), stream);
    bn_stats64<<<512, blk, 0, stream>>>(agg0, b_gcn, sums, sumsq);
    bn_finalize<<<1, CH, 0, stream>>>(sums, sumsq, g0, beta0, scale, shift, CH);
    bn_apply_gcn<<<1024, blk, 0, stream>>>(agg0, b_gcn, scale, shift, x1b);

    // ===== GAT layer 1 =====
    gemm_mfma<<<dim3(C1 / 64, (NN + 63) / 64), blk, 0, stream>>>(x1b, W1t, h1b, CH, C1);
    gat_alpha<<<NN, blk, 0, stream>>>(h1b, a_src1, a_dst1, alpha_s, alpha_d);
    gat_att<<<(NN + 3) / 4, blk, 0, stream>>>(row_start, sorted, alpha_s, alpha_d, attb, inv_ls);
    gat_gather<<<(NN + 3) / 4, blk, 0, stream>>>(row_start, sorted, attb, inv_ls, h1b, yb);
    hipMemsetAsync(sums, 0, 512 * sizeof(float), stream);
    bn_stats256<<<512, blk, 0, stream>>>(yb, sums, sumsq);
    bn_finalize<<<1, C1, 0, stream>>>(sums, sumsq, g1, beta1, scale, shift, C1);
    bn_apply_gat<<<2048, blk, 0, stream>>>(yb, scale, shift, x2b, 1);

    // ===== GAT layer 2 =====
    gemm_mfma<<<dim3(C1 / 64, (NN + 63) / 64), blk, 0, stream>>>(x2b, W2t, h1b, C1, C1);
    gat_alpha<<<NN, blk, 0, stream>>>(h1b, a_src2, a_dst2, alpha_s, alpha_d);
    gat_att<<<(NN + 3) / 4, blk, 0, stream>>>(row_start, sorted, alpha_s, alpha_d, attb, inv_ls);
    gat_gather<<<(NN + 3) / 4, blk, 0, stream>>>(row_start, sorted, attb, inv_ls, h1b, yb);
    hipMemsetAsync(sums, 0, 512 * sizeof(float), stream);
    bn_stats256<<<512, blk, 0, stream>>>(yb, sums, sumsq);
    bn_finalize<<<1, C1, 0, stream>>>(sums, sumsq, g2, beta2, scale, shift, C1);
    bn_apply_gat<<<2048, blk, 0, stream>>>(yb, scale, shift, outp, 0);
}

// Round 6
// 845.347 us; speedup vs baseline: 1.4083x; 1.0998x over previous
//
#include <hip/hip_runtime.h>
#include <hip/hip_bf16.h>
#include <math.h>

#define NN 100000
#define EE 800000
#define FIN 256
#define CH 64      // HID
#define C1 256     // H*HID
#define BN_EPS 1e-5f
#define NEG_SLOPE 0.2f

typedef __attribute__((ext_vector_type(8))) short short8;
typedef __attribute__((ext_vector_type(8))) unsigned short u16x8;
typedef __attribute__((ext_vector_type(4))) float f32x4;

__device__ __forceinline__ float bf2f(ushort u) {
    return __uint_as_float(((unsigned)u) << 16);
}
__device__ __forceinline__ ushort f2bf(float f) {
    unsigned u = __float_as_uint(f);
    return (ushort)((u + 0x7FFF + ((u >> 16) & 1)) >> 16);   // RNE
}

// ================= CSR build =================
__global__ void hist_kernel(const int* __restrict__ ei, int* __restrict__ deg) {
    int t = blockIdx.x * 256 + threadIdx.x;
    if (t < EE) atomicAdd(&deg[ei[EE + t]], 1);
}
__global__ void dinv_kernel(const int* __restrict__ deg, float* __restrict__ dinv) {
    int i = blockIdx.x * 256 + threadIdx.x;
    if (i < NN) dinv[i] = rsqrtf((float)(deg[i] + 1));  // +1 self loop
}
__global__ void scan_k1(const int* __restrict__ deg, int* __restrict__ row_start,
                        int* __restrict__ bsum) {
    __shared__ int sh[256];
    int t = threadIdx.x;
    int i = blockIdx.x * 256 + t;
    int v = (i < NN) ? (deg[i] + 1) : 0;
    sh[t] = v;
    __syncthreads();
    for (int off = 1; off < 256; off <<= 1) {
        int add = (t >= off) ? sh[t - off] : 0;
        __syncthreads();
        sh[t] += add;
        __syncthreads();
    }
    if (i < NN) row_start[i] = sh[t] - v;
    if (t == 255) bsum[blockIdx.x] = sh[255];
}
__global__ void scan_k2(int* __restrict__ bsum, int nb) {
    __shared__ int sh[512];
    int t = threadIdx.x;
    int v = (t < nb) ? bsum[t] : 0;
    sh[t] = v;
    __syncthreads();
    for (int off = 1; off < 512; off <<= 1) {
        int add = (t >= off) ? sh[t - off] : 0;
        __syncthreads();
        sh[t] += add;
        __syncthreads();
    }
    if (t < nb) bsum[t] = sh[t] - v;
}
__global__ void scan_k3(int* __restrict__ row_start, const int* __restrict__ bsum) {
    int i = blockIdx.x * 256 + threadIdx.x;
    if (i < NN) row_start[i] += bsum[i >> 8];
    if (i == NN) row_start[NN] = EE + NN;
}
__global__ void scatter_kernel(const int* __restrict__ ei, const int* __restrict__ row_start,
                               int* __restrict__ fill, int* __restrict__ sorted) {
    int t = blockIdx.x * 256 + threadIdx.x;
    if (t >= EE + NN) return;
    int s, d;
    if (t < EE) { s = ei[t]; d = ei[EE + t]; }
    else        { s = t - EE; d = s; }
    int pos = atomicAdd(&fill[d], 1);
    sorted[row_start[d] + pos] = s;
}

// ================= conversions =================
__global__ void convert_f32_bf16(const float* __restrict__ in, ushort* __restrict__ out, long n4) {
    long i = (long)blockIdx.x * 256 + threadIdx.x;
    if (i < n4) {
        float4 v = *(const float4*)&in[i * 4];
        ushort4 o;
        o.x = f2bf(v.x); o.y = f2bf(v.y); o.z = f2bf(v.z); o.w = f2bf(v.w);
        *(ushort4*)&out[i * 4] = o;
    }
}
__global__ void transpose_w(const float* __restrict__ W, ushort* __restrict__ Bt, int M, int K) {
    int idx = blockIdx.x * 256 + threadIdx.x;
    if (idx < M * K) {
        int m = idx / K, n = idx % K;
        Bt[n * M + m] = f2bf(W[idx]);
    }
}

// ================= bf16 MFMA GEMM =================
// C[N x K] = A[N x M] @ B[M x K]; A bf16 row-major, Bt bf16 [K][M], C bf16.
__global__ __launch_bounds__(256) void gemm_mfma(
        const ushort* __restrict__ A, const ushort* __restrict__ Bt,
        ushort* __restrict__ C, int M, int K) {
    __shared__ ushort As[64][40];
    __shared__ ushort Bs[64][40];
    int t = threadIdx.x;
    int w = t >> 6;
    int l = t & 63;
    int rowBase = blockIdx.y * 64;
    int colBase = blockIdx.x * 64;
    int srow = t >> 2;
    int sk = (t & 3) * 8;
    int m = l & 15, q = l >> 4;
    f32x4 acc[4] = {};
    for (int k0 = 0; k0 < M; k0 += 32) {
        uint4 av = make_uint4(0u, 0u, 0u, 0u);
        int gr = rowBase + srow;
        if (gr < NN) av = *(const uint4*)&A[(long)gr * M + k0 + sk];
        uint4 bv = *(const uint4*)&Bt[(long)(colBase + srow) * M + k0 + sk];
        *(uint4*)&As[srow][sk] = av;
        *(uint4*)&Bs[srow][sk] = bv;
        __syncthreads();
        short8 af = *(const short8*)&As[w * 16 + m][q * 8];
#pragma unroll
        for (int c = 0; c < 4; ++c) {
            short8 bf = *(const short8*)&Bs[c * 16 + m][q * 8];
            acc[c] = __builtin_amdgcn_mfma_f32_16x16x32_bf16(af, bf, acc[c], 0, 0, 0);
        }
        __syncthreads();
    }
#pragma unroll
    for (int c = 0; c < 4; ++c) {
#pragma unroll
        for (int r = 0; r < 4; ++r) {
            int orow = rowBase + w * 16 + q * 4 + r;
            if (orow < NN) C[(long)orow * K + colBase + c * 16 + m] = f2bf(acc[c][r]);
        }
    }
}

// ================= GCN gather =================
// one wave per node; 8 edge-slots x 8 lanes x ushort8 (16B) = 8 rows (1KB)
// per wave-instruction; shfl-xor reduce over slots; f32x4 stores.
__global__ __launch_bounds__(256) void gcn_gather(
        const int* __restrict__ row_start, const int* __restrict__ sorted,
        const float* __restrict__ dinv, const ushort* __restrict__ h0,
        float* __restrict__ agg) {
    int node = blockIdx.x * 4 + (threadIdx.x >> 6);
    if (node >= NN) return;
    int l = threadIdx.x & 63;
    int slot = l >> 3;          // edge slot 0..7
    int li = l & 7;             // lane within row
    int c = li * 8;             // 8 channels of 64
    int b = row_start[node], e = row_start[node + 1];
    float a[8] = {};
    for (int i = b + slot; i < e; i += 8) {
        int s = sorted[i];
        float dv = dinv[s];
        u16x8 v = *(const u16x8*)&h0[(long)s * 64 + c];
#pragma unroll
        for (int j = 0; j < 8; ++j) a[j] += dv * bf2f((ushort)v[j]);
    }
#pragma unroll
    for (int j = 0; j < 8; ++j) {
        a[j] += __shfl_xor(a[j], 8);
        a[j] += __shfl_xor(a[j], 16);
        a[j] += __shfl_xor(a[j], 32);
    }
    if (slot == 0) {
        float dn = dinv[node];
        f32x4 o0, o1;
#pragma unroll
        for (int j = 0; j < 4; ++j) { o0[j] = a[j] * dn; o1[j] = a[4 + j] * dn; }
        *(f32x4*)&agg[(long)node * 64 + c] = o0;
        *(f32x4*)&agg[(long)node * 64 + c + 4] = o1;
    }
}

// ================= BatchNorm =================
// C=64, fp32 input, relu(x+bias) pre-BN. Persistent: 512 blocks.
// Wave layout: sub = l>>4 owns row slot, c=(l&15)*4 channels, f32x4 loads.
__global__ __launch_bounds__(256) void bn_stats64(
        const float* __restrict__ x, const float* __restrict__ bias,
        float* __restrict__ sums, float* __restrict__ sumsq) {
    __shared__ float red[4][16][8];
    int l = threadIdx.x & 63;
    int w = threadIdx.x >> 6;
    int wv = blockIdx.x * 4 + w;
    int nw = gridDim.x * 4;
    int sub = l >> 4;
    int c = (l & 15) * 4;
    f32x4 b4 = *(const f32x4*)&bias[c];
    float s0 = 0.f, s1 = 0.f, s2 = 0.f, s3 = 0.f;
    float q0 = 0.f, q1 = 0.f, q2 = 0.f, q3 = 0.f;
    for (int r = wv * 4 + sub; r < NN; r += nw * 4) {
        f32x4 v = *(const f32x4*)&x[(long)r * 64 + c];
        float v0 = fmaxf(v[0] + b4[0], 0.f);
        float v1 = fmaxf(v[1] + b4[1], 0.f);
        float v2 = fmaxf(v[2] + b4[2], 0.f);
        float v3 = fmaxf(v[3] + b4[3], 0.f);
        s0 += v0; s1 += v1; s2 += v2; s3 += v3;
        q0 += v0 * v0; q1 += v1 * v1; q2 += v2 * v2; q3 += v3 * v3;
    }
    // reduce across the 4 row-slots (lanes differing in bits 4,5)
    s0 += __shfl_xor(s0, 16); s1 += __shfl_xor(s1, 16);
    s2 += __shfl_xor(s2, 16); s3 += __shfl_xor(s3, 16);
    q0 += __shfl_xor(q0, 16); q1 += __shfl_xor(q1, 16);
    q2 += __shfl_xor(q2, 16); q3 += __shfl_xor(q3, 16);
    s0 += __shfl_xor(s0, 32); s1 += __shfl_xor(s1, 32);
    s2 += __shfl_xor(s2, 32); s3 += __shfl_xor(s3, 32);
    q0 += __shfl_xor(q0, 32); q1 += __shfl_xor(q1, 32);
    q2 += __shfl_xor(q2, 32); q3 += __shfl_xor(q3, 32);
    if (sub == 0) {
        int li = l & 15;
        red[w][li][0] = s0; red[w][li][1] = s1; red[w][li][2] = s2; red[w][li][3] = s3;
        red[w][li][4] = q0; red[w][li][5] = q1; red[w][li][6] = q2; red[w][li][7] = q3;
    }
    __syncthreads();
    if (w == 0 && sub == 0) {
        int li = l & 15;
        atomicAdd(&sums[c + 0], red[0][li][0] + red[1][li][0] + red[2][li][0] + red[3][li][0]);
        atomicAdd(&sums[c + 1], red[0][li][1] + red[1][li][1] + red[2][li][1] + red[3][li][1]);
        atomicAdd(&sums[c + 2], red[0][li][2] + red[1][li][2] + red[2][li][2] + red[3][li][2]);
        atomicAdd(&sums[c + 3], red[0][li][3] + red[1][li][3] + red[2][li][3] + red[3][li][3]);
        atomicAdd(&sumsq[c + 0], red[0][li][4] + red[1][li][4] + red[2][li][4] + red[3][li][4]);
        atomicAdd(&sumsq[c + 1], red[0][li][5] + red[1][li][5] + red[2][li][5] + red[3][li][5]);
        atomicAdd(&sumsq[c + 2], red[0][li][6] + red[1][li][6] + red[2][li][6] + red[3][li][6]);
        atomicAdd(&sumsq[c + 3], red[0][li][7] + red[1][li][7] + red[2][li][7] + red[3][li][7]);
    }
}
// C=256, bf16 input, NO bias (shift-invariance: var(y+b)=var(y), and the
// bias cancels exactly in the normalized output). Persistent: 512 blocks.
// One wave covers a full row: lane l owns channels 4l..4l+3 (ushort4).
__global__ __launch_bounds__(256) void bn_stats256(
        const ushort* __restrict__ x,
        float* __restrict__ sums, float* __restrict__ sumsq) {
    __shared__ float red[4][64][8];
    int l = threadIdx.x & 63;
    int w = threadIdx.x >> 6;
    int wv = blockIdx.x * 4 + w;
    int nw = gridDim.x * 4;
    int c = l * 4;
    float s0 = 0.f, s1 = 0.f, s2 = 0.f, s3 = 0.f;
    float q0 = 0.f, q1 = 0.f, q2 = 0.f, q3 = 0.f;
    for (int r = wv; r < NN; r += nw) {
        ushort4 v = *(const ushort4*)&x[(long)r * 256 + c];
        float v0 = bf2f(v.x), v1 = bf2f(v.y), v2 = bf2f(v.z), v3 = bf2f(v.w);
        s0 += v0; s1 += v1; s2 += v2; s3 += v3;
        q0 += v0 * v0; q1 += v1 * v1; q2 += v2 * v2; q3 += v3 * v3;
    }
    red[w][l][0] = s0; red[w][l][1] = s1; red[w][l][2] = s2; red[w][l][3] = s3;
    red[w][l][4] = q0; red[w][l][5] = q1; red[w][l][6] = q2; red[w][l][7] = q3;
    __syncthreads();
    if (w == 0) {
        atomicAdd(&sums[c + 0], red[0][l][0] + red[1][l][0] + red[2][l][0] + red[3][l][0]);
        atomicAdd(&sums[c + 1], red[0][l][1] + red[1][l][1] + red[2][l][1] + red[3][l][1]);
        atomicAdd(&sums[c + 2], red[0][l][2] + red[1][l][2] + red[2][l][2] + red[3][l][2]);
        atomicAdd(&sums[c + 3], red[0][l][3] + red[1][l][3] + red[2][l][3] + red[3][l][3]);
        atomicAdd(&sumsq[c + 0], red[0][l][4] + red[1][l][4] + red[2][l][4] + red[3][l][4]);
        atomicAdd(&sumsq[c + 1], red[0][l][5] + red[1][l][5] + red[2][l][5] + red[3][l][5]);
        atomicAdd(&sumsq[c + 2], red[0][l][6] + red[1][l][6] + red[2][l][6] + red[3][l][6]);
        atomicAdd(&sumsq[c + 3], red[0][l][7] + red[1][l][7] + red[2][l][7] + red[3][l][7]);
    }
}
__global__ void bn_finalize(const float* __restrict__ sums, const float* __restrict__ sumsq,
                            const float* __restrict__ g, const float* __restrict__ beta,
                            float* __restrict__ scale, float* __restrict__ shift, int C) {
    int c = threadIdx.x;
    if (c < C) {
        float mean = sums[c] / (float)NN;
        float var = sumsq[c] / (float)NN - mean * mean;
        float sc = g[c] * rsqrtf(var + BN_EPS);
        scale[c] = sc;
        shift[c] = beta[c] - mean * sc;
    }
}
// GCN BN apply: fp32 in, relu pre-BN, bf16 out.
// 4 rows per wave (16 lanes/row, 4 ch/lane); tables hoisted out of row loop.
__global__ __launch_bounds__(256) void bn_apply_gcn(
        const float* __restrict__ x, const float* __restrict__ bias,
        const float* __restrict__ scale, const float* __restrict__ shift,
        ushort* __restrict__ out) {
    int l = threadIdx.x & 63;
    int wv = blockIdx.x * 4 + (threadIdx.x >> 6);
    int nw = gridDim.x * 4;
    int c = (l & 15) * 4;
    int sub = l >> 4;
    f32x4 b4  = *(const f32x4*)&bias[c];
    f32x4 sc4 = *(const f32x4*)&scale[c];
    f32x4 sh4 = *(const f32x4*)&shift[c];
    for (int r = wv * 4 + sub; r < NN; r += nw * 4) {
        f32x4 v = *(const f32x4*)&x[(long)r * 64 + c];
        ushort4 o;
        o.x = f2bf(sc4[0] * fmaxf(v[0] + b4[0], 0.f) + sh4[0]);
        o.y = f2bf(sc4[1] * fmaxf(v[1] + b4[1], 0.f) + sh4[1]);
        o.z = f2bf(sc4[2] * fmaxf(v[2] + b4[2], 0.f) + sh4[2]);
        o.w = f2bf(sc4[3] * fmaxf(v[3] + b4[3], 0.f) + sh4[3]);
        *(ushort4*)&out[(long)r * 64 + c] = o;
    }
}
// GAT BN apply: bf16 in, ELU post-BN, bf16 or fp32 out. NO bias (cancels:
// shift computed from raw-y mean gives identical normalized output).
// One wave per row; lane l owns channels 4l..4l+3; tables hoisted.
__global__ __launch_bounds__(256) void bn_apply_gat(
        const ushort* __restrict__ x,
        const float* __restrict__ scale, const float* __restrict__ shift,
        void* __restrict__ out, int out_bf16) {
    int l = threadIdx.x & 63;
    int wv = blockIdx.x * 4 + (threadIdx.x >> 6);
    int nw = gridDim.x * 4;
    int c = l * 4;
    f32x4 sc4 = *(const f32x4*)&scale[c];
    f32x4 sh4 = *(const f32x4*)&shift[c];
    if (out_bf16) {
        ushort* ob = (ushort*)out;
        for (int r = wv; r < NN; r += nw) {
            ushort4 v = *(const ushort4*)&x[(long)r * 256 + c];
            float t0 = sc4[0] * bf2f(v.x) + sh4[0];
            float t1 = sc4[1] * bf2f(v.y) + sh4[1];
            float t2 = sc4[2] * bf2f(v.z) + sh4[2];
            float t3 = sc4[3] * bf2f(v.w) + sh4[3];
            t0 = (t0 > 0.f) ? t0 : (__expf(t0) - 1.f);
            t1 = (t1 > 0.f) ? t1 : (__expf(t1) - 1.f);
            t2 = (t2 > 0.f) ? t2 : (__expf(t2) - 1.f);
            t3 = (t3 > 0.f) ? t3 : (__expf(t3) - 1.f);
            ushort4 o;
            o.x = f2bf(t0); o.y = f2bf(t1); o.z = f2bf(t2); o.w = f2bf(t3);
            *(ushort4*)&ob[(long)r * 256 + c] = o;
        }
    } else {
        float* of = (float*)out;
        for (int r = wv; r < NN; r += nw) {
            ushort4 v = *(const ushort4*)&x[(long)r * 256 + c];
            float t0 = sc4[0] * bf2f(v.x) + sh4[0];
            float t1 = sc4[1] * bf2f(v.y) + sh4[1];
            float t2 = sc4[2] * bf2f(v.z) + sh4[2];
            float t3 = sc4[3] * bf2f(v.w) + sh4[3];
            f32x4 o;
            o[0] = (t0 > 0.f) ? t0 : (__expf(t0) - 1.f);
            o[1] = (t1 > 0.f) ? t1 : (__expf(t1) - 1.f);
            o[2] = (t2 > 0.f) ? t2 : (__expf(t2) - 1.f);
            o[3] = (t3 > 0.f) ? t3 : (__expf(t3) - 1.f);
            *(f32x4*)&of[(long)r * 256 + c] = o;
        }
    }
}

// ================= GAT =================
// one wave per node (4/block); lane l owns channels 4l..4l+3 (ushort4);
// per-head (16-lane group) shfl_xor reduce.
__global__ __launch_bounds__(256) void gat_alpha(
        const ushort* __restrict__ h, const float* __restrict__ a_src,
        const float* __restrict__ a_dst,
        float* __restrict__ alpha_s, float* __restrict__ alpha_d) {
    int node = blockIdx.x * 4 + (threadIdx.x >> 6);
    if (node >= NN) return;
    int l = threadIdx.x & 63;
    int c = l * 4;
    f32x4 asv = *(const f32x4*)&a_src[c];   // [H][64] flat == channel order
    f32x4 adv = *(const f32x4*)&a_dst[c];
    ushort4 v = *(const ushort4*)&h[(long)node * 256 + c];
    float h0 = bf2f(v.x), h1 = bf2f(v.y), h2 = bf2f(v.z), h3 = bf2f(v.w);
    float vs = h0 * asv[0] + h1 * asv[1] + h2 * asv[2] + h3 * asv[3];
    float vd = h0 * adv[0] + h1 * adv[1] + h2 * adv[2] + h3 * adv[3];
    vs += __shfl_xor(vs, 1); vd += __shfl_xor(vd, 1);
    vs += __shfl_xor(vs, 2); vd += __shfl_xor(vd, 2);
    vs += __shfl_xor(vs, 4); vd += __shfl_xor(vd, 4);
    vs += __shfl_xor(vs, 8); vd += __shfl_xor(vd, 8);
    if ((l & 15) == 0) {
        int head = l >> 4;
        alpha_s[node * 4 + head] = vs;
        alpha_d[node * 4 + head] = vd;
    }
}

// one wave per node; lane = edge_k*4 + head; SINGLE pass (no max-subtract:
// softmax is shift-invariant and |e| is far below exp overflow here);
// stores UNNORMALIZED w + per-(node,head) 1/sum into inv_ls.
__global__ __launch_bounds__(256) void gat_att(
        const int* __restrict__ row_start, const int* __restrict__ sorted,
        const float* __restrict__ as, const float* __restrict__ ad,
        float* __restrict__ att, float* __restrict__ inv_ls) {
    int node = blockIdx.x * 4 + (threadIdx.x >> 6);
    if (node >= NN) return;
    int l = threadIdx.x & 63;
    int h = l & 3, k = l >> 2;
    int b = row_start[node], e = row_start[node + 1];
    float adn = ad[node * 4 + h];
    float ls = 0.f;
    for (int i = b + k; i < e; i += 16) {
        int s = sorted[i];
        float ev = as[s * 4 + h] + adn;
        ev = (ev > 0.f) ? ev : NEG_SLOPE * ev;
        ev = fminf(ev, 80.f);          // overflow guard (never hit in practice)
        float wv = __expf(ev);
        att[(long)i * 4 + h] = wv;
        ls += wv;
    }
    ls += __shfl_xor(ls, 4);
    ls += __shfl_xor(ls, 8);
    ls += __shfl_xor(ls, 16);
    ls += __shfl_xor(ls, 32);
    if (k == 0) inv_ls[node * 4 + h] = 1.0f / ls;
}

// one WAVE per node: lane l owns channels 4l..4l+3 (ushort4); 8 edges
// batch-issued per iteration (8 row-loads in flight before first FMA).
__global__ __launch_bounds__(256) void gat_gather(
        const int* __restrict__ row_start, const int* __restrict__ sorted,
        const float* __restrict__ att, const float* __restrict__ inv_ls,
        const ushort* __restrict__ h, ushort* __restrict__ out) {
    int node = blockIdx.x * 4 + (threadIdx.x >> 6);
    if (node >= NN) return;
    int l = threadIdx.x & 63;
    int head = l >> 4;                      // channels 4l..4l+3 share one head
    int b = row_start[node], e = row_start[node + 1];
    float a0 = 0.f, a1 = 0.f, a2 = 0.f, a3 = 0.f;
    int i = b;
    for (; i + 7 < e; i += 8) {
        int s[8]; float w[8]; ushort4 v[8];
#pragma unroll
        for (int j = 0; j < 8; ++j) s[j] = sorted[i + j];
#pragma unroll
        for (int j = 0; j < 8; ++j) w[j] = att[(long)(i + j) * 4 + head];
#pragma unroll
        for (int j = 0; j < 8; ++j) v[j] = *(const ushort4*)&h[(long)s[j] * 256 + l * 4];
#pragma unroll
        for (int j = 0; j < 8; ++j) {
            a0 += w[j] * bf2f(v[j].x);
            a1 += w[j] * bf2f(v[j].y);
            a2 += w[j] * bf2f(v[j].z);
            a3 += w[j] * bf2f(v[j].w);
        }
    }
    if (i + 3 < e) {
        int s[4]; float w[4]; ushort4 v[4];
#pragma unroll
        for (int j = 0; j < 4; ++j) s[j] = sorted[i + j];
#pragma unroll
        for (int j = 0; j < 4; ++j) w[j] = att[(long)(i + j) * 4 + head];
#pragma unroll
        for (int j = 0; j < 4; ++j) v[j] = *(const ushort4*)&h[(long)s[j] * 256 + l * 4];
#pragma unroll
        for (int j = 0; j < 4; ++j) {
            a0 += w[j] * bf2f(v[j].x);
            a1 += w[j] * bf2f(v[j].y);
            a2 += w[j] * bf2f(v[j].z);
            a3 += w[j] * bf2f(v[j].w);
        }
        i += 4;
    }
    for (; i < e; ++i) {
        int s0 = sorted[i];
        float w0 = att[(long)i * 4 + head];
        ushort4 v0 = *(const ushort4*)&h[(long)s0 * 256 + l * 4];
        a0 += w0 * bf2f(v0.x);
        a1 += w0 * bf2f(v0.y);
        a2 += w0 * bf2f(v0.z);
        a3 += w0 * bf2f(v0.w);
    }
    float inv = inv_ls[node * 4 + head];
    ushort4 o;
    o.x = f2bf(a0 * inv);
    o.y = f2bf(a1 * inv);
    o.z = f2bf(a2 * inv);
    o.w = f2bf(a3 * inv);
    *(ushort4*)&out[(long)node * 256 + l * 4] = o;
}

// ================= launch =================
extern "C" void kernel_launch(void* const* d_in, const int* in_sizes, int n_in,
                              void* d_out, int out_size, void* d_ws, size_t ws_size,
                              hipStream_t stream) {
    const float* x      = (const float*)d_in[0];
    const int*   ei     = (const int*)d_in[1];
    const float* W_gcn  = (const float*)d_in[2];
    const float* b_gcn  = (const float*)d_in[3];
    const float* g0     = (const float*)d_in[4];
    const float* beta0  = (const float*)d_in[5];
    const float* W1     = (const float*)d_in[6];
    const float* a_src1 = (const float*)d_in[7];
    const float* a_dst1 = (const float*)d_in[8];
    const float* b1     = (const float*)d_in[9];
    const float* g1     = (const float*)d_in[10];
    const float* beta1  = (const float*)d_in[11];
    const float* W2     = (const float*)d_in[12];
    const float* a_src2 = (const float*)d_in[13];
    const float* a_dst2 = (const float*)d_in[14];
    const float* b2     = (const float*)d_in[15];
    const float* g2     = (const float*)d_in[16];
    const float* beta2  = (const float*)d_in[17];

    const long N = NN;
    float* ws = (float*)d_ws;

    // ---- layout (~544N floats; ws proven >= 641N floats) ----
    float* dinv    = ws;                        // N
    float* alpha_s = ws + N;                    // 4N
    float* alpha_d = ws + 5 * N;                // 4N
    float* sums    = ws + 9 * N;                // 256
    float* sumsq   = sums + 256;
    float* scale   = sumsq + 256;
    float* shift   = scale + 256;
    int*   row_start = (int*)(shift + 256);     // N+1
    int*   fill      = row_start + NN + 1;      // N
    int*   deg_i     = fill + NN;               // N
    int*   sorted    = deg_i + NN;              // 9N
    int*   bsum      = sorted + EE + NN;        // ~400
    ushort* Wgt  = (ushort*)(ws + 23 * N);      // 64x256
    ushort* W1t  = Wgt + 16384;                 // 256x64
    ushort* W2t  = W1t + 16384;                 // 256x256
    ushort* h0b  = (ushort*)(ws + 24 * N);      // [N,64] bf16 (32N fl); reused as x1b
    ushort* x1b  = h0b;
    float*  agg0 = ws + 56 * N;                 // [N,64] fp32 (64N fl)
    ushort* h1b  = (ushort*)(ws + 120 * N);     // [N,256] bf16 (128N fl); also h2
    ushort* x2b  = (ushort*)(ws + 248 * N);     // [N,256] bf16 (128N fl)
    ushort* xb   = x2b;                         // alias: x bf16, dead before x2b live
    ushort* yb   = (ushort*)(ws + 376 * N);     // [N,256] bf16 gather out (128N fl)
    float*  attb = ws + 504 * N;                // (E+N)*4 floats (36N fl) -> ends 540N
    float*  inv_ls = ws + 540 * N;              // 4N floats -> ends 544N
    float*  outp = (float*)d_out;

    const int BLK = 256;
    dim3 blk(BLK);
    const int NBLK_N = (NN + 255) / 256;        // 391

    // ===== CSR build =====
    hipMemsetAsync(fill, 0, 2L * NN * sizeof(int), stream);
    hist_kernel<<<(EE + 255) / 256, blk, 0, stream>>>(ei, deg_i);
    dinv_kernel<<<NBLK_N, blk, 0, stream>>>(deg_i, dinv);
    scan_k1<<<NBLK_N, blk, 0, stream>>>(deg_i, row_start, bsum);
    scan_k2<<<1, 512, 0, stream>>>(bsum, NBLK_N);
    scan_k3<<<(NN + 1 + 255) / 256, blk, 0, stream>>>(row_start, bsum);
    scatter_kernel<<<(EE + NN + 255) / 256, blk, 0, stream>>>(ei, row_start, fill, sorted);

    // ===== conversions =====
    convert_f32_bf16<<<(int)((N * 256 / 4 + 255) / 256), blk, 0, stream>>>(x, xb, N * 256 / 4);
    transpose_w<<<(FIN * CH + 255) / 256, blk, 0, stream>>>(W_gcn, Wgt, FIN, CH);
    transpose_w<<<(CH * C1 + 255) / 256, blk, 0, stream>>>(W1, W1t, CH, C1);
    transpose_w<<<(C1 * C1 + 255) / 256, blk, 0, stream>>>(W2, W2t, C1, C1);

    // ===== GCN =====
    gemm_mfma<<<dim3(CH / 64, (NN + 63) / 64), blk, 0, stream>>>(xb, Wgt, h0b, FIN, CH);
    gcn_gather<<<(NN + 3) / 4, blk, 0, stream>>>(row_start, sorted, dinv, h0b, agg0);
    hipMemsetAsync(sums, 0, 512 * sizeof(float), stream);
    bn_stats64<<<512, blk, 0, stream>>>(agg0, b_gcn, sums, sumsq);
    bn_finalize<<<1, CH, 0, stream>>>(sums, sumsq, g0, beta0, scale, shift, CH);
    bn_apply_gcn<<<1024, blk, 0, stream>>>(agg0, b_gcn, scale, shift, x1b);

    // ===== GAT layer 1 =====
    gemm_mfma<<<dim3(C1 / 64, (NN + 63) / 64), blk, 0, stream>>>(x1b, W1t, h1b, CH, C1);
    gat_alpha<<<(NN + 3) / 4, blk, 0, stream>>>(h1b, a_src1, a_dst1, alpha_s, alpha_d);
    gat_att<<<(NN + 3) / 4, blk, 0, stream>>>(row_start, sorted, alpha_s, alpha_d, attb, inv_ls);
    gat_gather<<<(NN + 3) / 4, blk, 0, stream>>>(row_start, sorted, attb, inv_ls, h1b, yb);
    hipMemsetAsync(sums, 0, 512 * sizeof(float), stream);
    bn_stats256<<<512, blk, 0, stream>>>(yb, sums, sumsq);
    bn_finalize<<<1, C1, 0, stream>>>(sums, sumsq, g1, beta1, scale, shift, C1);
    bn_apply_gat<<<2048, blk, 0, stream>>>(yb, scale, shift, x2b, 1);

    // ===== GAT layer 2 =====
    gemm_mfma<<<dim3(C1 / 64, (NN + 63) / 64), blk, 0, stream>>>(x2b, W2t, h1b, C1, C1);
    gat_alpha<<<(NN + 3) / 4, blk, 0, stream>>>(h1b, a_src2, a_dst2, alpha_s, alpha_d);
    gat_att<<<(NN + 3) / 4, blk, 0, stream>>>(row_start, sorted, alpha_s, alpha_d, attb, inv_ls);
    gat_gather<<<(NN + 3) / 4, blk, 0, stream>>>(row_start, sorted, attb, inv_ls, h1b, yb);
    hipMemsetAsync(sums, 0, 512 * sizeof(float), stream);
    bn_stats256<<<512, blk, 0, stream>>>(yb, sums, sumsq);
    bn_finalize<<<1, C1, 0, stream>>>(sums, sumsq, g2, beta2, scale, shift, C1);
    bn_apply_gat<<<2048, blk, 0, stream>>>(yb, scale, shift, outp, 0);
}

// Round 7
// 810.929 us; speedup vs baseline: 1.4681x; 1.0424x over previous
//
#include <hip/hip_runtime.h>
#include <hip/hip_bf16.h>
#include <math.h>

#define NN 100000
#define EE 800000
#define FIN 256
#define CH 64      // HID
#define C1 256     // H*HID
#define BN_EPS 1e-5f
#define NEG_SLOPE 0.2f

typedef __attribute__((ext_vector_type(8))) short short8;
typedef __attribute__((ext_vector_type(8))) unsigned short u16x8;
typedef __attribute__((ext_vector_type(4))) float f32x4;

__device__ __forceinline__ float bf2f(ushort u) {
    return __uint_as_float(((unsigned)u) << 16);
}
__device__ __forceinline__ ushort f2bf(float f) {
    unsigned u = __float_as_uint(f);
    return (ushort)((u + 0x7FFF + ((u >> 16) & 1)) >> 16);   // RNE
}

// ================= CSR build =================
__global__ void hist_kernel(const int* __restrict__ ei, int* __restrict__ deg) {
    int t = blockIdx.x * 256 + threadIdx.x;
    if (t < EE) atomicAdd(&deg[ei[EE + t]], 1);
}
__global__ void dinv_kernel(const int* __restrict__ deg, float* __restrict__ dinv) {
    int i = blockIdx.x * 256 + threadIdx.x;
    if (i < NN) dinv[i] = rsqrtf((float)(deg[i] + 1));  // +1 self loop
}
__global__ void scan_k1(const int* __restrict__ deg, int* __restrict__ row_start,
                        int* __restrict__ bsum) {
    __shared__ int sh[256];
    int t = threadIdx.x;
    int i = blockIdx.x * 256 + t;
    int v = (i < NN) ? (deg[i] + 1) : 0;
    sh[t] = v;
    __syncthreads();
    for (int off = 1; off < 256; off <<= 1) {
        int add = (t >= off) ? sh[t - off] : 0;
        __syncthreads();
        sh[t] += add;
        __syncthreads();
    }
    if (i < NN) row_start[i] = sh[t] - v;
    if (t == 255) bsum[blockIdx.x] = sh[255];
}
__global__ void scan_k2(int* __restrict__ bsum, int nb) {
    __shared__ int sh[512];
    int t = threadIdx.x;
    int v = (t < nb) ? bsum[t] : 0;
    sh[t] = v;
    __syncthreads();
    for (int off = 1; off < 512; off <<= 1) {
        int add = (t >= off) ? sh[t - off] : 0;
        __syncthreads();
        sh[t] += add;
        __syncthreads();
    }
    if (t < nb) bsum[t] = sh[t] - v;
}
__global__ void scan_k3(int* __restrict__ row_start, const int* __restrict__ bsum) {
    int i = blockIdx.x * 256 + threadIdx.x;
    if (i < NN) row_start[i] += bsum[i >> 8];
    if (i == NN) row_start[NN] = EE + NN;
}
__global__ void scatter_kernel(const int* __restrict__ ei, const int* __restrict__ row_start,
                               int* __restrict__ fill, int* __restrict__ sorted) {
    int t = blockIdx.x * 256 + threadIdx.x;
    if (t >= EE + NN) return;
    int s, d;
    if (t < EE) { s = ei[t]; d = ei[EE + t]; }
    else        { s = t - EE; d = s; }
    int pos = atomicAdd(&fill[d], 1);
    sorted[row_start[d] + pos] = s;
}

// ================= conversions =================
__global__ void convert_f32_bf16(const float* __restrict__ in, ushort* __restrict__ out, long n4) {
    long i = (long)blockIdx.x * 256 + threadIdx.x;
    if (i < n4) {
        float4 v = *(const float4*)&in[i * 4];
        ushort4 o;
        o.x = f2bf(v.x); o.y = f2bf(v.y); o.z = f2bf(v.z); o.w = f2bf(v.w);
        *(ushort4*)&out[i * 4] = o;
    }
}
__global__ void transpose_w(const float* __restrict__ W, ushort* __restrict__ Bt, int M, int K) {
    int idx = blockIdx.x * 256 + threadIdx.x;
    if (idx < M * K) {
        int m = idx / K, n = idx % K;
        Bt[n * M + m] = f2bf(W[idx]);
    }
}

// ================= bf16 MFMA GEMM =================
// C[N x K] = A[N x M] @ B[M x K]; A bf16 row-major, Bt bf16 [K][M], C bf16.
__global__ __launch_bounds__(256) void gemm_mfma(
        const ushort* __restrict__ A, const ushort* __restrict__ Bt,
        ushort* __restrict__ C, int M, int K) {
    __shared__ ushort As[64][40];
    __shared__ ushort Bs[64][40];
    int t = threadIdx.x;
    int w = t >> 6;
    int l = t & 63;
    int rowBase = blockIdx.y * 64;
    int colBase = blockIdx.x * 64;
    int srow = t >> 2;
    int sk = (t & 3) * 8;
    int m = l & 15, q = l >> 4;
    f32x4 acc[4] = {};
    for (int k0 = 0; k0 < M; k0 += 32) {
        uint4 av = make_uint4(0u, 0u, 0u, 0u);
        int gr = rowBase + srow;
        if (gr < NN) av = *(const uint4*)&A[(long)gr * M + k0 + sk];
        uint4 bv = *(const uint4*)&Bt[(long)(colBase + srow) * M + k0 + sk];
        *(uint4*)&As[srow][sk] = av;
        *(uint4*)&Bs[srow][sk] = bv;
        __syncthreads();
        short8 af = *(const short8*)&As[w * 16 + m][q * 8];
#pragma unroll
        for (int c = 0; c < 4; ++c) {
            short8 bf = *(const short8*)&Bs[c * 16 + m][q * 8];
            acc[c] = __builtin_amdgcn_mfma_f32_16x16x32_bf16(af, bf, acc[c], 0, 0, 0);
        }
        __syncthreads();
    }
#pragma unroll
    for (int c = 0; c < 4; ++c) {
#pragma unroll
        for (int r = 0; r < 4; ++r) {
            int orow = rowBase + w * 16 + q * 4 + r;
            if (orow < NN) C[(long)orow * K + colBase + c * 16 + m] = f2bf(acc[c][r]);
        }
    }
}

// ================= GCN gather =================
// one wave per node; 8 edge-slots x 8 lanes x ushort8 (16B) = 8 rows (1KB)
// per wave-instruction; shfl-xor reduce over slots; f32x4 stores.
__global__ __launch_bounds__(256) void gcn_gather(
        const int* __restrict__ row_start, const int* __restrict__ sorted,
        const float* __restrict__ dinv, const ushort* __restrict__ h0,
        float* __restrict__ agg) {
    int node = blockIdx.x * 4 + (threadIdx.x >> 6);
    if (node >= NN) return;
    int l = threadIdx.x & 63;
    int slot = l >> 3;          // edge slot 0..7
    int li = l & 7;             // lane within row
    int c = li * 8;             // 8 channels of 64
    int b = row_start[node], e = row_start[node + 1];
    float a[8] = {};
    for (int i = b + slot; i < e; i += 8) {
        int s = sorted[i];
        float dv = dinv[s];
        u16x8 v = *(const u16x8*)&h0[(long)s * 64 + c];
#pragma unroll
        for (int j = 0; j < 8; ++j) a[j] += dv * bf2f((ushort)v[j]);
    }
#pragma unroll
    for (int j = 0; j < 8; ++j) {
        a[j] += __shfl_xor(a[j], 8);
        a[j] += __shfl_xor(a[j], 16);
        a[j] += __shfl_xor(a[j], 32);
    }
    if (slot == 0) {
        float dn = dinv[node];
        f32x4 o0, o1;
#pragma unroll
        for (int j = 0; j < 4; ++j) { o0[j] = a[j] * dn; o1[j] = a[4 + j] * dn; }
        *(f32x4*)&agg[(long)node * 64 + c] = o0;
        *(f32x4*)&agg[(long)node * 64 + c + 4] = o1;
    }
}

// ================= BatchNorm =================
// C=64, fp32 input, relu(x+bias) pre-BN. Persistent: 512 blocks.
// Wave layout: sub = l>>4 owns row slot, c=(l&15)*4 channels, f32x4 loads.
__global__ __launch_bounds__(256) void bn_stats64(
        const float* __restrict__ x, const float* __restrict__ bias,
        float* __restrict__ sums, float* __restrict__ sumsq) {
    __shared__ float red[4][16][8];
    int l = threadIdx.x & 63;
    int w = threadIdx.x >> 6;
    int wv = blockIdx.x * 4 + w;
    int nw = gridDim.x * 4;
    int sub = l >> 4;
    int c = (l & 15) * 4;
    f32x4 b4 = *(const f32x4*)&bias[c];
    float s0 = 0.f, s1 = 0.f, s2 = 0.f, s3 = 0.f;
    float q0 = 0.f, q1 = 0.f, q2 = 0.f, q3 = 0.f;
    for (int r = wv * 4 + sub; r < NN; r += nw * 4) {
        f32x4 v = *(const f32x4*)&x[(long)r * 64 + c];
        float v0 = fmaxf(v[0] + b4[0], 0.f);
        float v1 = fmaxf(v[1] + b4[1], 0.f);
        float v2 = fmaxf(v[2] + b4[2], 0.f);
        float v3 = fmaxf(v[3] + b4[3], 0.f);
        s0 += v0; s1 += v1; s2 += v2; s3 += v3;
        q0 += v0 * v0; q1 += v1 * v1; q2 += v2 * v2; q3 += v3 * v3;
    }
    // reduce across the 4 row-slots (lanes differing in bits 4,5)
    s0 += __shfl_xor(s0, 16); s1 += __shfl_xor(s1, 16);
    s2 += __shfl_xor(s2, 16); s3 += __shfl_xor(s3, 16);
    q0 += __shfl_xor(q0, 16); q1 += __shfl_xor(q1, 16);
    q2 += __shfl_xor(q2, 16); q3 += __shfl_xor(q3, 16);
    s0 += __shfl_xor(s0, 32); s1 += __shfl_xor(s1, 32);
    s2 += __shfl_xor(s2, 32); s3 += __shfl_xor(s3, 32);
    q0 += __shfl_xor(q0, 32); q1 += __shfl_xor(q1, 32);
    q2 += __shfl_xor(q2, 32); q3 += __shfl_xor(q3, 32);
    if (sub == 0) {
        int li = l & 15;
        red[w][li][0] = s0; red[w][li][1] = s1; red[w][li][2] = s2; red[w][li][3] = s3;
        red[w][li][4] = q0; red[w][li][5] = q1; red[w][li][6] = q2; red[w][li][7] = q3;
    }
    __syncthreads();
    if (w == 0 && sub == 0) {
        int li = l & 15;
        atomicAdd(&sums[c + 0], red[0][li][0] + red[1][li][0] + red[2][li][0] + red[3][li][0]);
        atomicAdd(&sums[c + 1], red[0][li][1] + red[1][li][1] + red[2][li][1] + red[3][li][1]);
        atomicAdd(&sums[c + 2], red[0][li][2] + red[1][li][2] + red[2][li][2] + red[3][li][2]);
        atomicAdd(&sums[c + 3], red[0][li][3] + red[1][li][3] + red[2][li][3] + red[3][li][3]);
        atomicAdd(&sumsq[c + 0], red[0][li][4] + red[1][li][4] + red[2][li][4] + red[3][li][4]);
        atomicAdd(&sumsq[c + 1], red[0][li][5] + red[1][li][5] + red[2][li][5] + red[3][li][5]);
        atomicAdd(&sumsq[c + 2], red[0][li][6] + red[1][li][6] + red[2][li][6] + red[3][li][6]);
        atomicAdd(&sumsq[c + 3], red[0][li][7] + red[1][li][7] + red[2][li][7] + red[3][li][7]);
    }
}
// C=256, bf16 input, NO bias (shift-invariance: var(y+b)=var(y), and the
// bias cancels exactly in the normalized output). Persistent: 512 blocks.
// One wave covers a full row: lane l owns channels 4l..4l+3 (ushort4).
__global__ __launch_bounds__(256) void bn_stats256(
        const ushort* __restrict__ x,
        float* __restrict__ sums, float* __restrict__ sumsq) {
    __shared__ float red[4][64][8];
    int l = threadIdx.x & 63;
    int w = threadIdx.x >> 6;
    int wv = blockIdx.x * 4 + w;
    int nw = gridDim.x * 4;
    int c = l * 4;
    float s0 = 0.f, s1 = 0.f, s2 = 0.f, s3 = 0.f;
    float q0 = 0.f, q1 = 0.f, q2 = 0.f, q3 = 0.f;
    for (int r = wv; r < NN; r += nw) {
        ushort4 v = *(const ushort4*)&x[(long)r * 256 + c];
        float v0 = bf2f(v.x), v1 = bf2f(v.y), v2 = bf2f(v.z), v3 = bf2f(v.w);
        s0 += v0; s1 += v1; s2 += v2; s3 += v3;
        q0 += v0 * v0; q1 += v1 * v1; q2 += v2 * v2; q3 += v3 * v3;
    }
    red[w][l][0] = s0; red[w][l][1] = s1; red[w][l][2] = s2; red[w][l][3] = s3;
    red[w][l][4] = q0; red[w][l][5] = q1; red[w][l][6] = q2; red[w][l][7] = q3;
    __syncthreads();
    if (w == 0) {
        atomicAdd(&sums[c + 0], red[0][l][0] + red[1][l][0] + red[2][l][0] + red[3][l][0]);
        atomicAdd(&sums[c + 1], red[0][l][1] + red[1][l][1] + red[2][l][1] + red[3][l][1]);
        atomicAdd(&sums[c + 2], red[0][l][2] + red[1][l][2] + red[2][l][2] + red[3][l][2]);
        atomicAdd(&sums[c + 3], red[0][l][3] + red[1][l][3] + red[2][l][3] + red[3][l][3]);
        atomicAdd(&sumsq[c + 0], red[0][l][4] + red[1][l][4] + red[2][l][4] + red[3][l][4]);
        atomicAdd(&sumsq[c + 1], red[0][l][5] + red[1][l][5] + red[2][l][5] + red[3][l][5]);
        atomicAdd(&sumsq[c + 2], red[0][l][6] + red[1][l][6] + red[2][l][6] + red[3][l][6]);
        atomicAdd(&sumsq[c + 3], red[0][l][7] + red[1][l][7] + red[2][l][7] + red[3][l][7]);
    }
}
__global__ void bn_finalize(const float* __restrict__ sums, const float* __restrict__ sumsq,
                            const float* __restrict__ g, const float* __restrict__ beta,
                            float* __restrict__ scale, float* __restrict__ shift, int C) {
    int c = threadIdx.x;
    if (c < C) {
        float mean = sums[c] / (float)NN;
        float var = sumsq[c] / (float)NN - mean * mean;
        float sc = g[c] * rsqrtf(var + BN_EPS);
        scale[c] = sc;
        shift[c] = beta[c] - mean * sc;
    }
}
// GCN BN apply: fp32 in, relu pre-BN, bf16 out.
// 4 rows per wave (16 lanes/row, 4 ch/lane); tables hoisted out of row loop.
__global__ __launch_bounds__(256) void bn_apply_gcn(
        const float* __restrict__ x, const float* __restrict__ bias,
        const float* __restrict__ scale, const float* __restrict__ shift,
        ushort* __restrict__ out) {
    int l = threadIdx.x & 63;
    int wv = blockIdx.x * 4 + (threadIdx.x >> 6);
    int nw = gridDim.x * 4;
    int c = (l & 15) * 4;
    int sub = l >> 4;
    f32x4 b4  = *(const f32x4*)&bias[c];
    f32x4 sc4 = *(const f32x4*)&scale[c];
    f32x4 sh4 = *(const f32x4*)&shift[c];
    for (int r = wv * 4 + sub; r < NN; r += nw * 4) {
        f32x4 v = *(const f32x4*)&x[(long)r * 64 + c];
        ushort4 o;
        o.x = f2bf(sc4[0] * fmaxf(v[0] + b4[0], 0.f) + sh4[0]);
        o.y = f2bf(sc4[1] * fmaxf(v[1] + b4[1], 0.f) + sh4[1]);
        o.z = f2bf(sc4[2] * fmaxf(v[2] + b4[2], 0.f) + sh4[2]);
        o.w = f2bf(sc4[3] * fmaxf(v[3] + b4[3], 0.f) + sh4[3]);
        *(ushort4*)&out[(long)r * 64 + c] = o;
    }
}
// GAT BN apply: bf16 in, ELU post-BN, bf16 or fp32 out. NO bias (cancels:
// shift computed from raw-y mean gives identical normalized output).
// One wave per row; lane l owns channels 4l..4l+3; tables hoisted.
__global__ __launch_bounds__(256) void bn_apply_gat(
        const ushort* __restrict__ x,
        const float* __restrict__ scale, const float* __restrict__ shift,
        void* __restrict__ out, int out_bf16) {
    int l = threadIdx.x & 63;
    int wv = blockIdx.x * 4 + (threadIdx.x >> 6);
    int nw = gridDim.x * 4;
    int c = l * 4;
    f32x4 sc4 = *(const f32x4*)&scale[c];
    f32x4 sh4 = *(const f32x4*)&shift[c];
    if (out_bf16) {
        ushort* ob = (ushort*)out;
        for (int r = wv; r < NN; r += nw) {
            ushort4 v = *(const ushort4*)&x[(long)r * 256 + c];
            float t0 = sc4[0] * bf2f(v.x) + sh4[0];
            float t1 = sc4[1] * bf2f(v.y) + sh4[1];
            float t2 = sc4[2] * bf2f(v.z) + sh4[2];
            float t3 = sc4[3] * bf2f(v.w) + sh4[3];
            t0 = (t0 > 0.f) ? t0 : (__expf(t0) - 1.f);
            t1 = (t1 > 0.f) ? t1 : (__expf(t1) - 1.f);
            t2 = (t2 > 0.f) ? t2 : (__expf(t2) - 1.f);
            t3 = (t3 > 0.f) ? t3 : (__expf(t3) - 1.f);
            ushort4 o;
            o.x = f2bf(t0); o.y = f2bf(t1); o.z = f2bf(t2); o.w = f2bf(t3);
            *(ushort4*)&ob[(long)r * 256 + c] = o;
        }
    } else {
        float* of = (float*)out;
        for (int r = wv; r < NN; r += nw) {
            ushort4 v = *(const ushort4*)&x[(long)r * 256 + c];
            float t0 = sc4[0] * bf2f(v.x) + sh4[0];
            float t1 = sc4[1] * bf2f(v.y) + sh4[1];
            float t2 = sc4[2] * bf2f(v.z) + sh4[2];
            float t3 = sc4[3] * bf2f(v.w) + sh4[3];
            f32x4 o;
            o[0] = (t0 > 0.f) ? t0 : (__expf(t0) - 1.f);
            o[1] = (t1 > 0.f) ? t1 : (__expf(t1) - 1.f);
            o[2] = (t2 > 0.f) ? t2 : (__expf(t2) - 1.f);
            o[3] = (t3 > 0.f) ? t3 : (__expf(t3) - 1.f);
            *(f32x4*)&of[(long)r * 256 + c] = o;
        }
    }
}

// ================= GAT =================
// one wave per node (4/block); lane l owns channels 4l..4l+3 (ushort4);
// per-head (16-lane group) shfl_xor reduce.
__global__ __launch_bounds__(256) void gat_alpha(
        const ushort* __restrict__ h, const float* __restrict__ a_src,
        const float* __restrict__ a_dst,
        float* __restrict__ alpha_s, float* __restrict__ alpha_d) {
    int node = blockIdx.x * 4 + (threadIdx.x >> 6);
    if (node >= NN) return;
    int l = threadIdx.x & 63;
    int c = l * 4;
    f32x4 asv = *(const f32x4*)&a_src[c];   // [H][64] flat == channel order
    f32x4 adv = *(const f32x4*)&a_dst[c];
    ushort4 v = *(const ushort4*)&h[(long)node * 256 + c];
    float h0 = bf2f(v.x), h1 = bf2f(v.y), h2 = bf2f(v.z), h3 = bf2f(v.w);
    float vs = h0 * asv[0] + h1 * asv[1] + h2 * asv[2] + h3 * asv[3];
    float vd = h0 * adv[0] + h1 * adv[1] + h2 * adv[2] + h3 * adv[3];
    vs += __shfl_xor(vs, 1); vd += __shfl_xor(vd, 1);
    vs += __shfl_xor(vs, 2); vd += __shfl_xor(vd, 2);
    vs += __shfl_xor(vs, 4); vd += __shfl_xor(vd, 4);
    vs += __shfl_xor(vs, 8); vd += __shfl_xor(vd, 8);
    if ((l & 15) == 0) {
        int head = l >> 4;
        alpha_s[node * 4 + head] = vs;
        alpha_d[node * 4 + head] = vd;
    }
}

// FUSED attention+gather: one WAVE per node; lane l owns channels 4l..4l+3;
// w = exp(lrelu(as[s]+ad[n])) recomputed inline from the L2-resident alpha
// tables (replaces the 14.4MB att stream + separate gat_att kernel); each
// lane accumulates the softmax denominator ls alongside (identical within a
// head group); normalize at the end. 4-edge batch (VGPR-friendly, occ ~72%).
__global__ __launch_bounds__(256) void gat_gather(
        const int* __restrict__ row_start, const int* __restrict__ sorted,
        const float* __restrict__ as, const float* __restrict__ ad,
        const ushort* __restrict__ h, ushort* __restrict__ out) {
    int node = blockIdx.x * 4 + (threadIdx.x >> 6);
    if (node >= NN) return;
    int l = threadIdx.x & 63;
    int head = l >> 4;                      // channels 4l..4l+3 share one head
    int b = row_start[node], e = row_start[node + 1];
    float adn = ad[node * 4 + head];
    float a0 = 0.f, a1 = 0.f, a2 = 0.f, a3 = 0.f;
    float ls = 0.f;
    int i = b;
    for (; i + 3 < e; i += 4) {
        int s[4]; float ev[4]; ushort4 v[4];
#pragma unroll
        for (int j = 0; j < 4; ++j) s[j] = sorted[i + j];
#pragma unroll
        for (int j = 0; j < 4; ++j) ev[j] = as[s[j] * 4 + head];
#pragma unroll
        for (int j = 0; j < 4; ++j) v[j] = *(const ushort4*)&h[(long)s[j] * 256 + l * 4];
#pragma unroll
        for (int j = 0; j < 4; ++j) {
            float t = ev[j] + adn;
            t = (t > 0.f) ? t : NEG_SLOPE * t;
            float w = __expf(fminf(t, 80.f));
            ls += w;
            a0 += w * bf2f(v[j].x);
            a1 += w * bf2f(v[j].y);
            a2 += w * bf2f(v[j].z);
            a3 += w * bf2f(v[j].w);
        }
    }
    for (; i < e; ++i) {
        int s0 = sorted[i];
        float t = as[s0 * 4 + head] + adn;
        t = (t > 0.f) ? t : NEG_SLOPE * t;
        float w = __expf(fminf(t, 80.f));
        ushort4 v0 = *(const ushort4*)&h[(long)s0 * 256 + l * 4];
        ls += w;
        a0 += w * bf2f(v0.x);
        a1 += w * bf2f(v0.y);
        a2 += w * bf2f(v0.z);
        a3 += w * bf2f(v0.w);
    }
    float inv = 1.0f / ls;
    ushort4 o;
    o.x = f2bf(a0 * inv);
    o.y = f2bf(a1 * inv);
    o.z = f2bf(a2 * inv);
    o.w = f2bf(a3 * inv);
    *(ushort4*)&out[(long)node * 256 + l * 4] = o;
}

// ================= launch =================
extern "C" void kernel_launch(void* const* d_in, const int* in_sizes, int n_in,
                              void* d_out, int out_size, void* d_ws, size_t ws_size,
                              hipStream_t stream) {
    const float* x      = (const float*)d_in[0];
    const int*   ei     = (const int*)d_in[1];
    const float* W_gcn  = (const float*)d_in[2];
    const float* b_gcn  = (const float*)d_in[3];
    const float* g0     = (const float*)d_in[4];
    const float* beta0  = (const float*)d_in[5];
    const float* W1     = (const float*)d_in[6];
    const float* a_src1 = (const float*)d_in[7];
    const float* a_dst1 = (const float*)d_in[8];
    const float* b1     = (const float*)d_in[9];
    const float* g1     = (const float*)d_in[10];
    const float* beta1  = (const float*)d_in[11];
    const float* W2     = (const float*)d_in[12];
    const float* a_src2 = (const float*)d_in[13];
    const float* a_dst2 = (const float*)d_in[14];
    const float* b2     = (const float*)d_in[15];
    const float* g2     = (const float*)d_in[16];
    const float* beta2  = (const float*)d_in[17];

    const long N = NN;
    float* ws = (float*)d_ws;

    // ---- layout (~544N floats; ws proven >= 641N floats) ----
    float* dinv    = ws;                        // N
    float* alpha_s = ws + N;                    // 4N
    float* alpha_d = ws + 5 * N;                // 4N
    float* sums    = ws + 9 * N;                // 256
    float* sumsq   = sums + 256;
    float* scale   = sumsq + 256;
    float* shift   = scale + 256;
    int*   row_start = (int*)(shift + 256);     // N+1
    int*   fill      = row_start + NN + 1;      // N
    int*   deg_i     = fill + NN;               // N
    int*   sorted    = deg_i + NN;              // 9N
    int*   bsum      = sorted + EE + NN;        // ~400
    ushort* Wgt  = (ushort*)(ws + 23 * N);      // 64x256
    ushort* W1t  = Wgt + 16384;                 // 256x64
    ushort* W2t  = W1t + 16384;                 // 256x256
    ushort* h0b  = (ushort*)(ws + 24 * N);      // [N,64] bf16 (32N fl); reused as x1b
    ushort* x1b  = h0b;
    float*  agg0 = ws + 56 * N;                 // [N,64] fp32 (64N fl)
    ushort* h1b  = (ushort*)(ws + 120 * N);     // [N,256] bf16 (128N fl); also h2
    ushort* x2b  = (ushort*)(ws + 248 * N);     // [N,256] bf16 (128N fl)
    ushort* xb   = x2b;                         // alias: x bf16, dead before x2b live
    ushort* yb   = (ushort*)(ws + 376 * N);     // [N,256] bf16 gather out (128N fl)
    float*  outp = (float*)d_out;

    const int BLK = 256;
    dim3 blk(BLK);
    const int NBLK_N = (NN + 255) / 256;        // 391

    // ===== CSR build =====
    hipMemsetAsync(fill, 0, 2L * NN * sizeof(int), stream);
    hist_kernel<<<(EE + 255) / 256, blk, 0, stream>>>(ei, deg_i);
    dinv_kernel<<<NBLK_N, blk, 0, stream>>>(deg_i, dinv);
    scan_k1<<<NBLK_N, blk, 0, stream>>>(deg_i, row_start, bsum);
    scan_k2<<<1, 512, 0, stream>>>(bsum, NBLK_N);
    scan_k3<<<(NN + 1 + 255) / 256, blk, 0, stream>>>(row_start, bsum);
    scatter_kernel<<<(EE + NN + 255) / 256, blk, 0, stream>>>(ei, row_start, fill, sorted);

    // ===== conversions =====
    convert_f32_bf16<<<(int)((N * 256 / 4 + 255) / 256), blk, 0, stream>>>(x, xb, N * 256 / 4);
    transpose_w<<<(FIN * CH + 255) / 256, blk, 0, stream>>>(W_gcn, Wgt, FIN, CH);
    transpose_w<<<(CH * C1 + 255) / 256, blk, 0, stream>>>(W1, W1t, CH, C1);
    transpose_w<<<(C1 * C1 + 255) / 256, blk, 0, stream>>>(W2, W2t, C1, C1);

    // ===== GCN =====
    gemm_mfma<<<dim3(CH / 64, (NN + 63) / 64), blk, 0, stream>>>(xb, Wgt, h0b, FIN, CH);
    gcn_gather<<<(NN + 3) / 4, blk, 0, stream>>>(row_start, sorted, dinv, h0b, agg0);
    hipMemsetAsync(sums, 0, 512 * sizeof(float), stream);
    bn_stats64<<<512, blk, 0, stream>>>(agg0, b_gcn, sums, sumsq);
    bn_finalize<<<1, CH, 0, stream>>>(sums, sumsq, g0, beta0, scale, shift, CH);
    bn_apply_gcn<<<1024, blk, 0, stream>>>(agg0, b_gcn, scale, shift, x1b);

    // ===== GAT layer 1 =====
    gemm_mfma<<<dim3(C1 / 64, (NN + 63) / 64), blk, 0, stream>>>(x1b, W1t, h1b, CH, C1);
    gat_alpha<<<(NN + 3) / 4, blk, 0, stream>>>(h1b, a_src1, a_dst1, alpha_s, alpha_d);
    gat_gather<<<(NN + 3) / 4, blk, 0, stream>>>(row_start, sorted, alpha_s, alpha_d, h1b, yb);
    hipMemsetAsync(sums, 0, 512 * sizeof(float), stream);
    bn_stats256<<<512, blk, 0, stream>>>(yb, sums, sumsq);
    bn_finalize<<<1, C1, 0, stream>>>(sums, sumsq, g1, beta1, scale, shift, C1);
    bn_apply_gat<<<2048, blk, 0, stream>>>(yb, scale, shift, x2b, 1);

    // ===== GAT layer 2 =====
    gemm_mfma<<<dim3(C1 / 64, (NN + 63) / 64), blk, 0, stream>>>(x2b, W2t, h1b, C1, C1);
    gat_alpha<<<(NN + 3) / 4, blk, 0, stream>>>(h1b, a_src2, a_dst2, alpha_s, alpha_d);
    gat_gather<<<(NN + 3) / 4, blk, 0, stream>>>(row_start, sorted, alpha_s, alpha_d, h1b, yb);
    hipMemsetAsync(sums, 0, 512 * sizeof(float), stream);
    bn_stats256<<<512, blk, 0, stream>>>(yb, sums, sumsq);
    bn_finalize<<<1, C1, 0, stream>>>(sums, sumsq, g2, beta2, scale, shift, C1);
    bn_apply_gat<<<2048, blk, 0, stream>>>(yb, scale, shift, outp, 0);
}

// Round 8
// 766.768 us; speedup vs baseline: 1.5526x; 1.0576x over previous
//
#include <hip/hip_runtime.h>
#include <hip/hip_bf16.h>
#include <math.h>

#define NN 100000
#define EE 800000
#define FIN 256
#define CH 64      // HID
#define C1 256     // H*HID
#define BN_EPS 1e-5f
#define NEG_SLOPE 0.2f
#define NREP 16    // BN stats atomic replicas

typedef __attribute__((ext_vector_type(8))) short short8;
typedef __attribute__((ext_vector_type(8))) unsigned short u16x8;
typedef __attribute__((ext_vector_type(4))) float f32x4;

__device__ __forceinline__ float bf2f(ushort u) {
    return __uint_as_float(((unsigned)u) << 16);
}
__device__ __forceinline__ ushort f2bf(float f) {
    unsigned u = __float_as_uint(f);
    return (ushort)((u + 0x7FFF + ((u >> 16) & 1)) >> 16);   // RNE
}

// ================= CSR build =================
__global__ void hist_kernel(const int* __restrict__ ei, int* __restrict__ deg) {
    int t = blockIdx.x * 256 + threadIdx.x;
    if (t < EE) atomicAdd(&deg[ei[EE + t]], 1);
}
__global__ void dinv_kernel(const int* __restrict__ deg, float* __restrict__ dinv) {
    int i = blockIdx.x * 256 + threadIdx.x;
    if (i < NN) dinv[i] = rsqrtf((float)(deg[i] + 1));  // +1 self loop
}
__global__ void scan_k1(const int* __restrict__ deg, int* __restrict__ row_start,
                        int* __restrict__ bsum) {
    __shared__ int sh[256];
    int t = threadIdx.x;
    int i = blockIdx.x * 256 + t;
    int v = (i < NN) ? (deg[i] + 1) : 0;
    sh[t] = v;
    __syncthreads();
    for (int off = 1; off < 256; off <<= 1) {
        int add = (t >= off) ? sh[t - off] : 0;
        __syncthreads();
        sh[t] += add;
        __syncthreads();
    }
    if (i < NN) row_start[i] = sh[t] - v;
    if (t == 255) bsum[blockIdx.x] = sh[255];
}
__global__ void scan_k2(int* __restrict__ bsum, int nb) {
    __shared__ int sh[512];
    int t = threadIdx.x;
    int v = (t < nb) ? bsum[t] : 0;
    sh[t] = v;
    __syncthreads();
    for (int off = 1; off < 512; off <<= 1) {
        int add = (t >= off) ? sh[t - off] : 0;
        __syncthreads();
        sh[t] += add;
        __syncthreads();
    }
    if (t < nb) bsum[t] = sh[t] - v;
}
__global__ void scan_k3(int* __restrict__ row_start, const int* __restrict__ bsum) {
    int i = blockIdx.x * 256 + threadIdx.x;
    if (i < NN) row_start[i] += bsum[i >> 8];
    if (i == NN) row_start[NN] = EE + NN;
}
__global__ void scatter_kernel(const int* __restrict__ ei, const int* __restrict__ row_start,
                               int* __restrict__ fill, int* __restrict__ sorted) {
    int t = blockIdx.x * 256 + threadIdx.x;
    if (t >= EE + NN) return;
    int s, d;
    if (t < EE) { s = ei[t]; d = ei[EE + t]; }
    else        { s = t - EE; d = s; }
    int pos = atomicAdd(&fill[d], 1);
    sorted[row_start[d] + pos] = s;
}

// ================= conversions =================
__global__ void transpose_w(const float* __restrict__ W, ushort* __restrict__ Bt, int M, int K) {
    int idx = blockIdx.x * 256 + threadIdx.x;
    if (idx < M * K) {
        int m = idx / K, n = idx % K;
        Bt[n * M + m] = f2bf(W[idx]);
    }
}

// ================= bf16 MFMA GEMM (+optional fp32-A, +fused GAT alpha) ====
// C[N x K] = A[N x M] @ B[M x K]; A bf16 or fp32 row-major, Bt bf16 [K][M].
// If alpha_s != null: K==256, each col-block (64 cols) is one head; compute
// per-row dots with a_src/a_dst over this block's cols and store directly.
__global__ __launch_bounds__(256) void gemm_mfma(
        const void* __restrict__ Ap, const ushort* __restrict__ Bt,
        ushort* __restrict__ C, int M, int K, int a_fp32,
        const float* __restrict__ a_src, const float* __restrict__ a_dst,
        float* __restrict__ alpha_s, float* __restrict__ alpha_d) {
    __shared__ ushort As[64][40];
    __shared__ ushort Bs[64][40];
    int t = threadIdx.x;
    int w = t >> 6;
    int l = t & 63;
    int rowBase = blockIdx.y * 64;
    int colBase = blockIdx.x * 64;
    int srow = t >> 2;
    int sk = (t & 3) * 8;
    int m = l & 15, q = l >> 4;
    f32x4 acc[4] = {};
    for (int k0 = 0; k0 < M; k0 += 32) {
        int gr = rowBase + srow;
        if (a_fp32) {
            ushort4 u0 = {0, 0, 0, 0}, u1 = {0, 0, 0, 0};
            if (gr < NN) {
                const float* Af = (const float*)Ap;
                float4 f0 = *(const float4*)&Af[(long)gr * M + k0 + sk];
                float4 f1 = *(const float4*)&Af[(long)gr * M + k0 + sk + 4];
                u0.x = f2bf(f0.x); u0.y = f2bf(f0.y); u0.z = f2bf(f0.z); u0.w = f2bf(f0.w);
                u1.x = f2bf(f1.x); u1.y = f2bf(f1.y); u1.z = f2bf(f1.z); u1.w = f2bf(f1.w);
            }
            *(ushort4*)&As[srow][sk] = u0;
            *(ushort4*)&As[srow][sk + 4] = u1;
        } else {
            uint4 av = make_uint4(0u, 0u, 0u, 0u);
            if (gr < NN) av = *(const uint4*)&((const ushort*)Ap)[(long)gr * M + k0 + sk];
            *(uint4*)&As[srow][sk] = av;
        }
        uint4 bv = *(const uint4*)&Bt[(long)(colBase + srow) * M + k0 + sk];
        *(uint4*)&Bs[srow][sk] = bv;
        __syncthreads();
        short8 af = *(const short8*)&As[w * 16 + m][q * 8];
#pragma unroll
        for (int c = 0; c < 4; ++c) {
            short8 bf = *(const short8*)&Bs[c * 16 + m][q * 8];
            acc[c] = __builtin_amdgcn_mfma_f32_16x16x32_bf16(af, bf, acc[c], 0, 0, 0);
        }
        __syncthreads();
    }
    if (alpha_s) {
        int head = colBase >> 6;
        float ps[4] = {}, pd[4] = {};
#pragma unroll
        for (int c = 0; c < 4; ++c) {
            float av = a_src[colBase + c * 16 + m];
            float dv = a_dst[colBase + c * 16 + m];
#pragma unroll
            for (int r = 0; r < 4; ++r) {
                ps[r] += acc[c][r] * av;
                pd[r] += acc[c][r] * dv;
            }
        }
#pragma unroll
        for (int r = 0; r < 4; ++r) {
            ps[r] += __shfl_xor(ps[r], 1); pd[r] += __shfl_xor(pd[r], 1);
            ps[r] += __shfl_xor(ps[r], 2); pd[r] += __shfl_xor(pd[r], 2);
            ps[r] += __shfl_xor(ps[r], 4); pd[r] += __shfl_xor(pd[r], 4);
            ps[r] += __shfl_xor(ps[r], 8); pd[r] += __shfl_xor(pd[r], 8);
        }
        if (m == 0) {
#pragma unroll
            for (int r = 0; r < 4; ++r) {
                int row = rowBase + w * 16 + q * 4 + r;
                if (row < NN) {
                    alpha_s[row * 4 + head] = ps[r];
                    alpha_d[row * 4 + head] = pd[r];
                }
            }
        }
    }
#pragma unroll
    for (int c = 0; c < 4; ++c) {
#pragma unroll
        for (int r = 0; r < 4; ++r) {
            int orow = rowBase + w * 16 + q * 4 + r;
            if (orow < NN) C[(long)orow * K + colBase + c * 16 + m] = f2bf(acc[c][r]);
        }
    }
}

// ================= GCN gather (persistent, + fused bn_stats64) ============
// one wave per node iter; 8 edge-slots x 8 lanes x ushort8 = 8 rows (1KB)
// per wave-instruction; stats of relu(agg+bias) accumulated in registers,
// block-reduced in LDS, atomics into NREP replicated slots.
__global__ __launch_bounds__(256) void gcn_gather(
        const int* __restrict__ row_start, const int* __restrict__ sorted,
        const float* __restrict__ dinv, const ushort* __restrict__ h0,
        const float* __restrict__ bias, float* __restrict__ agg,
        float* __restrict__ sums, float* __restrict__ sumsq) {
    __shared__ float red[4][8][16];
    int l = threadIdx.x & 63;
    int w = threadIdx.x >> 6;
    int wv = blockIdx.x * 4 + w;
    int nw = gridDim.x * 4;
    int slot = l >> 3;          // edge slot 0..7
    int li = l & 7;             // lane within row
    int c = li * 8;             // 8 channels of 64
    float bb[8];
#pragma unroll
    for (int j = 0; j < 8; ++j) bb[j] = bias[c + j];
    float st[8] = {}, qt[8] = {};
    for (int node = wv; node < NN; node += nw) {
        int b = row_start[node], e = row_start[node + 1];
        float a[8] = {};
        for (int i = b + slot; i < e; i += 8) {
            int s = sorted[i];
            float dv = dinv[s];
            u16x8 v = *(const u16x8*)&h0[(long)s * 64 + c];
#pragma unroll
            for (int j = 0; j < 8; ++j) a[j] += dv * bf2f((ushort)v[j]);
        }
#pragma unroll
        for (int j = 0; j < 8; ++j) {
            a[j] += __shfl_xor(a[j], 8);
            a[j] += __shfl_xor(a[j], 16);
            a[j] += __shfl_xor(a[j], 32);
        }
        if (slot == 0) {
            float dn = dinv[node];
            f32x4 o0, o1;
#pragma unroll
            for (int j = 0; j < 4; ++j) { o0[j] = a[j] * dn; o1[j] = a[4 + j] * dn; }
            *(f32x4*)&agg[(long)node * 64 + c] = o0;
            *(f32x4*)&agg[(long)node * 64 + c + 4] = o1;
#pragma unroll
            for (int j = 0; j < 8; ++j) {
                float v = fmaxf((j < 4 ? o0[j] : o1[j - 4]) + bb[j], 0.f);
                st[j] += v; qt[j] += v * v;
            }
        }
    }
    if (slot == 0) {
#pragma unroll
        for (int j = 0; j < 8; ++j) { red[w][li][j] = st[j]; red[w][li][8 + j] = qt[j]; }
    }
    __syncthreads();
    if (w == 0 && slot == 0) {
        float* S = sums + (blockIdx.x & (NREP - 1)) * 64;
        float* Q = sumsq + (blockIdx.x & (NREP - 1)) * 64;
#pragma unroll
        for (int j = 0; j < 8; ++j) {
            atomicAdd(&S[c + j], red[0][li][j] + red[1][li][j] + red[2][li][j] + red[3][li][j]);
            atomicAdd(&Q[c + j], red[0][li][8 + j] + red[1][li][8 + j] + red[2][li][8 + j] + red[3][li][8 + j]);
        }
    }
}

// ================= BatchNorm =================
// finalize over NREP replicated partial slots
__global__ void bn_finalize(const float* __restrict__ sums, const float* __restrict__ sumsq,
                            const float* __restrict__ g, const float* __restrict__ beta,
                            float* __restrict__ scale, float* __restrict__ shift, int C) {
    int c = threadIdx.x;
    if (c < C) {
        float sm = 0.f, sq = 0.f;
        for (int r = 0; r < NREP; ++r) { sm += sums[r * C + c]; sq += sumsq[r * C + c]; }
        float mean = sm / (float)NN;
        float var = sq / (float)NN - mean * mean;
        float sc = g[c] * rsqrtf(var + BN_EPS);
        scale[c] = sc;
        shift[c] = beta[c] - mean * sc;
    }
}
// GCN BN apply: fp32 in, relu pre-BN, bf16 out.
__global__ __launch_bounds__(256) void bn_apply_gcn(
        const float* __restrict__ x, const float* __restrict__ bias,
        const float* __restrict__ scale, const float* __restrict__ shift,
        ushort* __restrict__ out) {
    int l = threadIdx.x & 63;
    int wv = blockIdx.x * 4 + (threadIdx.x >> 6);
    int nw = gridDim.x * 4;
    int c = (l & 15) * 4;
    int sub = l >> 4;
    f32x4 b4  = *(const f32x4*)&bias[c];
    f32x4 sc4 = *(const f32x4*)&scale[c];
    f32x4 sh4 = *(const f32x4*)&shift[c];
    for (int r = wv * 4 + sub; r < NN; r += nw * 4) {
        f32x4 v = *(const f32x4*)&x[(long)r * 64 + c];
        ushort4 o;
        o.x = f2bf(sc4[0] * fmaxf(v[0] + b4[0], 0.f) + sh4[0]);
        o.y = f2bf(sc4[1] * fmaxf(v[1] + b4[1], 0.f) + sh4[1]);
        o.z = f2bf(sc4[2] * fmaxf(v[2] + b4[2], 0.f) + sh4[2]);
        o.w = f2bf(sc4[3] * fmaxf(v[3] + b4[3], 0.f) + sh4[3]);
        *(ushort4*)&out[(long)r * 64 + c] = o;
    }
}
// GAT BN apply: bf16 in, ELU post-BN, bf16 or fp32 out (bias cancels).
__global__ __launch_bounds__(256) void bn_apply_gat(
        const ushort* __restrict__ x,
        const float* __restrict__ scale, const float* __restrict__ shift,
        void* __restrict__ out, int out_bf16) {
    int l = threadIdx.x & 63;
    int wv = blockIdx.x * 4 + (threadIdx.x >> 6);
    int nw = gridDim.x * 4;
    int c = l * 4;
    f32x4 sc4 = *(const f32x4*)&scale[c];
    f32x4 sh4 = *(const f32x4*)&shift[c];
    if (out_bf16) {
        ushort* ob = (ushort*)out;
        for (int r = wv; r < NN; r += nw) {
            ushort4 v = *(const ushort4*)&x[(long)r * 256 + c];
            float t0 = sc4[0] * bf2f(v.x) + sh4[0];
            float t1 = sc4[1] * bf2f(v.y) + sh4[1];
            float t2 = sc4[2] * bf2f(v.z) + sh4[2];
            float t3 = sc4[3] * bf2f(v.w) + sh4[3];
            t0 = (t0 > 0.f) ? t0 : (__expf(t0) - 1.f);
            t1 = (t1 > 0.f) ? t1 : (__expf(t1) - 1.f);
            t2 = (t2 > 0.f) ? t2 : (__expf(t2) - 1.f);
            t3 = (t3 > 0.f) ? t3 : (__expf(t3) - 1.f);
            ushort4 o;
            o.x = f2bf(t0); o.y = f2bf(t1); o.z = f2bf(t2); o.w = f2bf(t3);
            *(ushort4*)&ob[(long)r * 256 + c] = o;
        }
    } else {
        float* of = (float*)out;
        for (int r = wv; r < NN; r += nw) {
            ushort4 v = *(const ushort4*)&x[(long)r * 256 + c];
            float t0 = sc4[0] * bf2f(v.x) + sh4[0];
            float t1 = sc4[1] * bf2f(v.y) + sh4[1];
            float t2 = sc4[2] * bf2f(v.z) + sh4[2];
            float t3 = sc4[3] * bf2f(v.w) + sh4[3];
            f32x4 o;
            o[0] = (t0 > 0.f) ? t0 : (__expf(t0) - 1.f);
            o[1] = (t1 > 0.f) ? t1 : (__expf(t1) - 1.f);
            o[2] = (t2 > 0.f) ? t2 : (__expf(t2) - 1.f);
            o[3] = (t3 > 0.f) ? t3 : (__expf(t3) - 1.f);
            *(f32x4*)&of[(long)r * 256 + c] = o;
        }
    }
}

// ========== FUSED GAT attention+gather (persistent, + fused bn_stats256) ==
// one wave per node iter; lane l owns channels 4l..4l+3; w recomputed
// inline from alpha tables; softmax denominator on the fly; output stats
// accumulated in registers -> LDS -> NREP-replicated atomics.
__global__ __launch_bounds__(256) void gat_gather(
        const int* __restrict__ row_start, const int* __restrict__ sorted,
        const float* __restrict__ as, const float* __restrict__ ad,
        const ushort* __restrict__ h, ushort* __restrict__ out,
        float* __restrict__ sums, float* __restrict__ sumsq) {
    __shared__ float red[4][64][8];
    int l = threadIdx.x & 63;
    int w = threadIdx.x >> 6;
    int wv = blockIdx.x * 4 + w;
    int nw = gridDim.x * 4;
    int head = l >> 4;                      // channels 4l..4l+3 share one head
    float s0 = 0.f, s1 = 0.f, s2 = 0.f, s3 = 0.f;
    float z0 = 0.f, z1 = 0.f, z2 = 0.f, z3 = 0.f;
    for (int node = wv; node < NN; node += nw) {
        int b = row_start[node], e = row_start[node + 1];
        float adn = ad[node * 4 + head];
        float a0 = 0.f, a1 = 0.f, a2 = 0.f, a3 = 0.f;
        float ls = 0.f;
        int i = b;
        for (; i + 3 < e; i += 4) {
            int s[4]; float ev[4]; ushort4 v[4];
#pragma unroll
            for (int j = 0; j < 4; ++j) s[j] = sorted[i + j];
#pragma unroll
            for (int j = 0; j < 4; ++j) ev[j] = as[s[j] * 4 + head];
#pragma unroll
            for (int j = 0; j < 4; ++j) v[j] = *(const ushort4*)&h[(long)s[j] * 256 + l * 4];
#pragma unroll
            for (int j = 0; j < 4; ++j) {
                float t = ev[j] + adn;
                t = (t > 0.f) ? t : NEG_SLOPE * t;
                float wt = __expf(t);
                ls += wt;
                a0 += wt * bf2f(v[j].x);
                a1 += wt * bf2f(v[j].y);
                a2 += wt * bf2f(v[j].z);
                a3 += wt * bf2f(v[j].w);
            }
        }
        for (; i < e; ++i) {
            int sv = sorted[i];
            float t = as[sv * 4 + head] + adn;
            t = (t > 0.f) ? t : NEG_SLOPE * t;
            float wt = __expf(t);
            ushort4 v0 = *(const ushort4*)&h[(long)sv * 256 + l * 4];
            ls += wt;
            a0 += wt * bf2f(v0.x);
            a1 += wt * bf2f(v0.y);
            a2 += wt * bf2f(v0.z);
            a3 += wt * bf2f(v0.w);
        }
        float inv = 1.0f / ls;
        float o0 = a0 * inv, o1 = a1 * inv, o2 = a2 * inv, o3 = a3 * inv;
        ushort4 o;
        o.x = f2bf(o0); o.y = f2bf(o1); o.z = f2bf(o2); o.w = f2bf(o3);
        *(ushort4*)&out[(long)node * 256 + l * 4] = o;
        s0 += o0; s1 += o1; s2 += o2; s3 += o3;
        z0 += o0 * o0; z1 += o1 * o1; z2 += o2 * o2; z3 += o3 * o3;
    }
    red[w][l][0] = s0; red[w][l][1] = s1; red[w][l][2] = s2; red[w][l][3] = s3;
    red[w][l][4] = z0; red[w][l][5] = z1; red[w][l][6] = z2; red[w][l][7] = z3;
    __syncthreads();
    if (w == 0) {
        int c = l * 4;
        float* S = sums + (blockIdx.x & (NREP - 1)) * 256;
        float* Q = sumsq + (blockIdx.x & (NREP - 1)) * 256;
        atomicAdd(&S[c + 0], red[0][l][0] + red[1][l][0] + red[2][l][0] + red[3][l][0]);
        atomicAdd(&S[c + 1], red[0][l][1] + red[1][l][1] + red[2][l][1] + red[3][l][1]);
        atomicAdd(&S[c + 2], red[0][l][2] + red[1][l][2] + red[2][l][2] + red[3][l][2]);
        atomicAdd(&S[c + 3], red[0][l][3] + red[1][l][3] + red[2][l][3] + red[3][l][3]);
        atomicAdd(&Q[c + 0], red[0][l][4] + red[1][l][4] + red[2][l][4] + red[3][l][4]);
        atomicAdd(&Q[c + 1], red[0][l][5] + red[1][l][5] + red[2][l][5] + red[3][l][5]);
        atomicAdd(&Q[c + 2], red[0][l][6] + red[1][l][6] + red[2][l][6] + red[3][l][6]);
        atomicAdd(&Q[c + 3], red[0][l][7] + red[1][l][7] + red[2][l][7] + red[3][l][7]);
    }
}

// ================= launch =================
extern "C" void kernel_launch(void* const* d_in, const int* in_sizes, int n_in,
                              void* d_out, int out_size, void* d_ws, size_t ws_size,
                              hipStream_t stream) {
    const float* x      = (const float*)d_in[0];
    const int*   ei     = (const int*)d_in[1];
    const float* W_gcn  = (const float*)d_in[2];
    const float* b_gcn  = (const float*)d_in[3];
    const float* g0     = (const float*)d_in[4];
    const float* beta0  = (const float*)d_in[5];
    const float* W1     = (const float*)d_in[6];
    const float* a_src1 = (const float*)d_in[7];
    const float* a_dst1 = (const float*)d_in[8];
    const float* b1     = (const float*)d_in[9];
    const float* g1     = (const float*)d_in[10];
    const float* beta1  = (const float*)d_in[11];
    const float* W2     = (const float*)d_in[12];
    const float* a_src2 = (const float*)d_in[13];
    const float* a_dst2 = (const float*)d_in[14];
    const float* b2     = (const float*)d_in[15];
    const float* g2     = (const float*)d_in[16];
    const float* beta2  = (const float*)d_in[17];

    const long N = NN;
    float* ws = (float*)d_ws;

    // ---- layout ----
    float* dinv    = ws;                        // N
    float* alpha_s = ws + N;                    // 4N
    float* alpha_d = ws + 5 * N;                // 4N
    float* sums    = ws + 9 * N;                // NREP*256 = 4096
    float* sumsq   = sums + 4096;               // 4096
    float* scale   = sumsq + 4096;              // 256
    float* shift   = scale + 256;               // 256
    int*   row_start = (int*)(shift + 256);     // N+1
    int*   fill      = row_start + NN + 1;      // N
    int*   deg_i     = fill + NN;               // N
    int*   sorted    = deg_i + NN;              // 9N
    int*   bsum      = sorted + EE + NN;        // ~400  (ends ~21N+9.1K < 23N)
    ushort* Wgt  = (ushort*)(ws + 23 * N);      // 64x256
    ushort* W1t  = Wgt + 16384;                 // 256x64
    ushort* W2t  = W1t + 16384;                 // 256x256
    ushort* h0b  = (ushort*)(ws + 24 * N);      // [N,64] bf16; reused as x1b
    ushort* x1b  = h0b;
    float*  agg0 = ws + 56 * N;                 // [N,64] fp32
    ushort* h1b  = (ushort*)(ws + 120 * N);     // [N,256] bf16; also h2
    ushort* x2b  = (ushort*)(ws + 248 * N);     // [N,256] bf16
    ushort* yb   = (ushort*)(ws + 376 * N);     // [N,256] bf16 gather out
    float*  outp = (float*)d_out;

    const int BLK = 256;
    dim3 blk(BLK);
    const int NBLK_N = (NN + 255) / 256;        // 391

    // ===== CSR build =====
    hipMemsetAsync(fill, 0, 2L * NN * sizeof(int), stream);
    hist_kernel<<<(EE + 255) / 256, blk, 0, stream>>>(ei, deg_i);
    dinv_kernel<<<NBLK_N, blk, 0, stream>>>(deg_i, dinv);
    scan_k1<<<NBLK_N, blk, 0, stream>>>(deg_i, row_start, bsum);
    scan_k2<<<1, 512, 0, stream>>>(bsum, NBLK_N);
    scan_k3<<<(NN + 1 + 255) / 256, blk, 0, stream>>>(row_start, bsum);
    scatter_kernel<<<(EE + NN + 255) / 256, blk, 0, stream>>>(ei, row_start, fill, sorted);

    // ===== weight conversions =====
    transpose_w<<<(FIN * CH + 255) / 256, blk, 0, stream>>>(W_gcn, Wgt, FIN, CH);
    transpose_w<<<(CH * C1 + 255) / 256, blk, 0, stream>>>(W1, W1t, CH, C1);
    transpose_w<<<(C1 * C1 + 255) / 256, blk, 0, stream>>>(W2, W2t, C1, C1);

    // ===== GCN =====
    gemm_mfma<<<dim3(CH / 64, (NN + 63) / 64), blk, 0, stream>>>(
        x, Wgt, h0b, FIN, CH, 1, nullptr, nullptr, nullptr, nullptr);
    hipMemsetAsync(sums, 0, 8192 * sizeof(float), stream);
    gcn_gather<<<4096, blk, 0, stream>>>(row_start, sorted, dinv, h0b, b_gcn, agg0, sums, sumsq);
    bn_finalize<<<1, CH, 0, stream>>>(sums, sumsq, g0, beta0, scale, shift, CH);
    bn_apply_gcn<<<1024, blk, 0, stream>>>(agg0, b_gcn, scale, shift, x1b);

    // ===== GAT layer 1 =====
    gemm_mfma<<<dim3(C1 / 64, (NN + 63) / 64), blk, 0, stream>>>(
        x1b, W1t, h1b, CH, C1, 0, a_src1, a_dst1, alpha_s, alpha_d);
    hipMemsetAsync(sums, 0, 8192 * sizeof(float), stream);
    gat_gather<<<8192, blk, 0, stream>>>(row_start, sorted, alpha_s, alpha_d, h1b, yb, sums, sumsq);
    bn_finalize<<<1, C1, 0, stream>>>(sums, sumsq, g1, beta1, scale, shift, C1);
    bn_apply_gat<<<2048, blk, 0, stream>>>(yb, scale, shift, x2b, 1);

    // ===== GAT layer 2 =====
    gemm_mfma<<<dim3(C1 / 64, (NN + 63) / 64), blk, 0, stream>>>(
        x2b, W2t, h1b, C1, C1, 0, a_src2, a_dst2, alpha_s, alpha_d);
    hipMemsetAsync(sums, 0, 8192 * sizeof(float), stream);
    gat_gather<<<8192, blk, 0, stream>>>(row_start, sorted, alpha_s, alpha_d, h1b, yb, sums, sumsq);
    bn_finalize<<<1, C1, 0, stream>>>(sums, sumsq, g2, beta2, scale, shift, C1);
    bn_apply_gat<<<2048, blk, 0, stream>>>(yb, scale, shift, outp, 0);
}